// Round 1
// baseline (460.620 us; speedup 1.0000x reference)
//
#include <hip/hip_runtime.h>
#include <cstdint>

#define DEV __device__ __forceinline__

typedef __attribute__((ext_vector_type(8))) short bf16x8;
typedef __attribute__((ext_vector_type(4))) float f32x4;
typedef __attribute__((ext_vector_type(2))) __fp16 h2t;
typedef __attribute__((ext_vector_type(4))) unsigned int u32x4;
typedef unsigned long long u64;

DEV unsigned short f2bf(float f) {
    unsigned u = __float_as_uint(f);
    unsigned r = u + 0x7fffu + ((u >> 16) & 1u);
    return (unsigned short)(r >> 16);
}
DEV uint32_t pkbf2(float a, float b) {
    return (uint32_t)f2bf(a) | ((uint32_t)f2bf(b) << 16);
}
DEV uint32_t pkh2(float a, float b) {
    h2t p = __builtin_amdgcn_cvt_pkrtz(a, b);
    union { h2t h; uint32_t u; } c;
    c.h = p;
    return c.u;
}
DEV float dot2(uint32_t w, uint32_t x, float acc) {
    union { uint32_t u; h2t h; } a, b;
    a.u = w; b.u = x;
    return __builtin_amdgcn_fdot2(a.h, b.h, acc, false);
}
DEV float sigm(float x) { return __builtin_amdgcn_rcpf(1.f + __expf(-x)); }
DEV float tanh_(float x) { return fmaf(2.f, sigm(2.f * x), -1.f); }
DEV uint32_t packpair(float h) {
    float hs = __int_as_float(__builtin_amdgcn_ds_swizzle(__float_as_int(h), 0x041F));
    return pkh2(h, hs);
}
DEV uint32_t comp4(uint4 v, int e) {
    return (e == 0) ? v.x : (e == 1) ? v.y : (e == 2) ? v.z : v.w;
}
DEV uint32_t comp4v(u32x4 v, int e) {
    return (e == 0) ? v[0] : (e == 1) ? v[1] : (e == 2) ? v[2] : v[3];
}
DEV u64 pack4bf(float a, float b, float c, float d) {
    unsigned lo = (unsigned)f2bf(a) | ((unsigned)f2bf(b) << 16);
    unsigned hi = (unsigned)f2bf(c) | ((unsigned)f2bf(d) << 16);
    return (u64)lo | ((u64)hi << 32);
}

// ---------------- weight prep (bf16, K-chunk order)
// conv1: w1t[oc][k], k = cc*8 + u*4 + c; chunk cc<15: taps (r=cc/3, kx=2*(cc%3)+u);
//        kx=5 / cc=15 / c=3 are phantom slots with ZERO weight.
// w2t[64][288]: k = tap*32 + c; w3t[64][576]: k = tap*64 + c
__global__ __launch_bounds__(256) void k_wprep(const float* __restrict__ w1,
                                               const float* __restrict__ w2,
                                               const float* __restrict__ w3,
                                               unsigned short* __restrict__ w1t,
                                               unsigned short* __restrict__ w2t,
                                               unsigned short* __restrict__ w3t) {
    int i = blockIdx.x * 256 + threadIdx.x;
    if (i < 32 * 128) {
        int oc = i >> 7, k = i & 127;
        int cc = k >> 3, u = (k >> 2) & 1, c = k & 3;
        int r = cc / 3, kx = 2 * (cc - 3 * r) + u;
        w1t[i] = (cc < 15 && kx < 5 && c < 3) ? f2bf(w1[oc * 75 + c * 25 + r * 5 + kx])
                                              : (unsigned short)0;
    } else if (i < 32 * 128 + 64 * 288) {
        int j = i - 32 * 128;
        int oc = j / 288, k = j - oc * 288;
        int pos = k >> 5, c = k & 31;
        w2t[j] = f2bf(w2[oc * 288 + c * 9 + pos]);
    } else if (i < 32 * 128 + 64 * 288 + 64 * 576) {
        int j = i - 32 * 128 - 64 * 288;
        int oc = j / 576, k = j - oc * 576;
        int pos = k >> 6, c = k & 63;
        w3t[j] = f2bf(w3[oc * 576 + c * 9 + pos]);
    }
}

// ---------------- LSTM weight prep: f16 pairs (see k_lstm)
__global__ __launch_bounds__(256) void k_wprep_lstm(const float* __restrict__ Wih0,
                                                    const float* __restrict__ Wih,
                                                    const float* __restrict__ Whh,
                                                    uint32_t* __restrict__ wpk) {
    int idx = blockIdx.x * 256 + threadIdx.x;  // 0..32767
    int lane = idx & 63;
    int j = (idx >> 6) & 63;
    int l = idx >> 12;
    int g = j >> 4, q = j & 15;
    int r = g * 64 + lane;
    uint32_t ov[4];
#pragma unroll
    for (int e = 0; e < 4; ++e) {
        int p = q * 4 + e;
        float w0, w1;
        if (p < 32) {
            int k0 = 2 * p;
            if (l == 0) {
                w0 = (k0 < 16) ? Wih0[r * 16 + k0] : 0.f;
                w1 = (k0 + 1 < 16) ? Wih0[r * 16 + k0 + 1] : 0.f;
            } else {
                const float* base = Wih + ((size_t)(l - 1) * 256 + r) * 64;
                w0 = base[k0];
                w1 = base[k0 + 1];
            }
        } else {
            int k0 = 2 * (p - 32);
            const float* base = Whh + ((size_t)l * 256 + r) * 64;
            w0 = base[k0];
            w1 = base[k0 + 1];
        }
        ov[e] = pkh2(w0, w1);
    }
    uint4 v;
    v.x = ov[0]; v.y = ov[1]; v.z = ov[2]; v.w = ov[3];
    ((uint4*)wpk)[idx] = v;
}

// ---------------- conv1: 4 output rows/block, wave=row, b128 frags, 2 MFMA per frag.
__global__ __launch_bounds__(256) void k_conv1m(const float* __restrict__ img,
                                                const unsigned short* __restrict__ w1t,
                                                const float* __restrict__ bias,
                                                unsigned short* __restrict__ out) {
    int b = blockIdx.x, y0 = blockIdx.y * 4;
    int tid = threadIdx.x;
    __shared__ __align__(16) unsigned short lds[12 * 1040];
    char* lb = (char*)lds;
    const float* ib = img + (size_t)b * 3 * 192 * 256;
#pragma unroll
    for (int r = 0; r < 12; ++r) {
        if (r < 11) {
            int row = 2 * y0 + r;
            if (row > 191) row = 191;
            const float* ip = ib + row * 256 + tid;
            float f0 = ip[0], f1 = ip[192 * 256], f2 = ip[2 * 192 * 256];
            uint32_t lo = (uint32_t)f2bf(f0) | ((uint32_t)f2bf(f1) << 16);
            *(u64*)(lb + r * 2080 + tid * 8) = (u64)lo | ((u64)f2bf(f2) << 32);
        } else {
            *(u64*)(lb + 11 * 2080 + tid * 8) = 0ull;
        }
    }
    __syncthreads();
    int wave = tid >> 6, lane = tid & 63;
    int quad = lane >> 4, nl = lane & 15;
    int ly = wave;
    float4 bv0 = *(const float4*)(bias + quad * 4);
    float4 bv1 = *(const float4*)(bias + 16 + quad * 4);
    f32x4 acc[8][2];
#pragma unroll
    for (int nt = 0; nt < 8; ++nt) {
        acc[nt][0][0] = bv0.x; acc[nt][0][1] = bv0.y; acc[nt][0][2] = bv0.z; acc[nt][0][3] = bv0.w;
        acc[nt][1][0] = bv1.x; acc[nt][1][1] = bv1.y; acc[nt][1][2] = bv1.z; acc[nt][1][3] = bv1.w;
    }
#pragma unroll
    for (int ks = 0; ks < 4; ++ks) {
        int cc = ks * 4 + quad;
        int r = cc / 3, kxp = cc - 3 * r;
        int rb = (2 * ly + r) * 2080 + kxp * 16 + nl * 16;
        bf16x8 af0 = *(const bf16x8*)(w1t + (nl) * 128 + ks * 32 + quad * 8);
        bf16x8 af1 = *(const bf16x8*)(w1t + (16 + nl) * 128 + ks * 32 + quad * 8);
#pragma unroll
        for (int nt = 0; nt < 8; ++nt) {
            bf16x8 bv = *(const bf16x8*)(lb + rb + nt * 256);
            acc[nt][0] = __builtin_amdgcn_mfma_f32_16x16x32_bf16(af0, bv, acc[nt][0], 0, 0, 0);
            acc[nt][1] = __builtin_amdgcn_mfma_f32_16x16x32_bf16(af1, bv, acc[nt][1], 0, 0, 0);
        }
    }
    int y = y0 + ly;
    if (y < 94) {
#pragma unroll
        for (int nt = 0; nt < 8; ++nt) {
            int x = nt * 16 + nl;
            if (x < 126) {
#pragma unroll
                for (int mi = 0; mi < 2; ++mi) {
                    f32x4 a = acc[nt][mi];
                    u64 pk = pack4bf(fmaxf(a[0], 0.f), fmaxf(a[1], 0.f),
                                     fmaxf(a[2], 0.f), fmaxf(a[3], 0.f));
                    *(u64*)(out + (((size_t)b * 94 + y) * 126 + x) * 32 + mi * 16 + quad * 4) = pk;
                }
            }
        }
    }
}

// ---------------- conv2: NHWC in -> NHWC out [128][46][62][64]. 3x3 s2 ReLU.
__global__ __launch_bounds__(256) void k_conv2m(const unsigned short* __restrict__ in,
                                                const unsigned short* __restrict__ w2t,
                                                const float* __restrict__ bias,
                                                unsigned short* __restrict__ out) {
    int b = blockIdx.x, y = blockIdx.y;
    int tid = threadIdx.x;
    __shared__ __align__(16) unsigned short lds[3 * 130 * 36];
    char* lb = (char*)lds;
    const u64* in64 = (const u64*)in;
    size_t gbase = ((size_t)b * 94 + 2 * y) * 126 * 8;
    for (int u = tid; u < 3024; u += 256) {
        int r = u / 1008, rem = u - r * 1008;
        int p = rem >> 3, h = rem & 7;
        u64 v = in64[gbase + (size_t)r * 126 * 8 + p * 8 + h];
        *(u64*)(lb + r * 9360 + p * 72 + h * 8) = v;
    }
    __syncthreads();
    int wave = tid >> 6, lane = tid & 63;
    int quad = lane >> 4, nl = lane & 15;
    int mtg = wave & 1, ntg = wave >> 1;
    f32x4 acc[4];
#pragma unroll
    for (int mi = 0; mi < 2; ++mi) {
        float4 bv = *(const float4*)(bias + (mtg * 2 + mi) * 16 + quad * 4);
#pragma unroll
        for (int ni = 0; ni < 2; ++ni) {
            acc[mi * 2 + ni][0] = bv.x; acc[mi * 2 + ni][1] = bv.y;
            acc[mi * 2 + ni][2] = bv.z; acc[mi * 2 + ni][3] = bv.w;
        }
    }
#pragma unroll
    for (int ks = 0; ks < 9; ++ks) {
        const int r = ks / 3, kx = ks - r * 3;
        bf16x8 af0 = *(const bf16x8*)(w2t + ((mtg * 2 + 0) * 16 + nl) * 288 + ks * 32 + quad * 8);
        bf16x8 af1 = *(const bf16x8*)(w2t + ((mtg * 2 + 1) * 16 + nl) * 288 + ks * 32 + quad * 8);
        int ro = r * 9360 + 72 * kx + quad * 16;
#pragma unroll
        for (int ni = 0; ni < 2; ++ni) {
            int x = (ntg * 2 + ni) * 16 + nl;
            union { u64 d[2]; bf16x8 v; } bb;
            bb.d[0] = *(const u64*)(lb + ro + 144 * x);
            bb.d[1] = *(const u64*)(lb + ro + 144 * x + 8);
            acc[0 * 2 + ni] = __builtin_amdgcn_mfma_f32_16x16x32_bf16(af0, bb.v, acc[0 * 2 + ni], 0, 0, 0);
            acc[1 * 2 + ni] = __builtin_amdgcn_mfma_f32_16x16x32_bf16(af1, bb.v, acc[1 * 2 + ni], 0, 0, 0);
        }
    }
#pragma unroll
    for (int ni = 0; ni < 2; ++ni) {
        int x = (ntg * 2 + ni) * 16 + nl;
        if (x < 62) {
#pragma unroll
            for (int mi = 0; mi < 2; ++mi) {
                int oc0 = (mtg * 2 + mi) * 16 + quad * 4;
                f32x4 a = acc[mi * 2 + ni];
                u64 pk = pack4bf(fmaxf(a[0], 0.f), fmaxf(a[1], 0.f), fmaxf(a[2], 0.f), fmaxf(a[3], 0.f));
                *(u64*)(out + (((size_t)b * 46 + y) * 62 + x) * 64 + oc0) = pk;
            }
        }
    }
}

// ---------------- conv3: NHWC in -> NCHW-flatten bf16 [b][64*660]. 3x3 s2.
__global__ __launch_bounds__(256) void k_conv3m(const unsigned short* __restrict__ in,
                                                const unsigned short* __restrict__ w3t,
                                                const float* __restrict__ bias,
                                                unsigned short* __restrict__ out) {
    int b = blockIdx.x, y = blockIdx.y;
    int tid = threadIdx.x;
    __shared__ __align__(16) unsigned short lds[3 * 65 * 68];
    char* lb = (char*)lds;
    const u64* in64 = (const u64*)in;
    size_t gbase = ((size_t)b * 46 + 2 * y) * 62 * 16;
    for (int u = tid; u < 2976; u += 256) {
        int r = u / 992, rem = u - r * 992;
        int p = rem >> 4, h = rem & 15;
        u64 v = in64[gbase + (size_t)r * 62 * 16 + p * 16 + h];
        *(u64*)(lb + r * 8840 + p * 136 + h * 8) = v;
    }
    __syncthreads();
    int wave = tid >> 6, lane = tid & 63;
    int quad = lane >> 4, nl = lane & 15;
    int mtg = wave & 1, nt = wave >> 1;
    f32x4 acc[2];
#pragma unroll
    for (int mi = 0; mi < 2; ++mi) {
        float4 bv = *(const float4*)(bias + (mtg * 2 + mi) * 16 + quad * 4);
        acc[mi][0] = bv.x; acc[mi][1] = bv.y; acc[mi][2] = bv.z; acc[mi][3] = bv.w;
    }
    int x = nt * 16 + nl;
#pragma unroll
    for (int ks = 0; ks < 18; ++ks) {
        const int pos = ks >> 1, half = ks & 1;
        const int r = pos / 3, kx = pos - r * 3;
        bf16x8 af0 = *(const bf16x8*)(w3t + ((mtg * 2 + 0) * 16 + nl) * 576 + ks * 32 + quad * 8);
        bf16x8 af1 = *(const bf16x8*)(w3t + ((mtg * 2 + 1) * 16 + nl) * 576 + ks * 32 + quad * 8);
        int ro = r * 8840 + 136 * kx + half * 64 + quad * 16;
        union { u64 d[2]; bf16x8 v; } bb;
        bb.d[0] = *(const u64*)(lb + ro + 272 * x);
        bb.d[1] = *(const u64*)(lb + ro + 272 * x + 8);
        acc[0] = __builtin_amdgcn_mfma_f32_16x16x32_bf16(af0, bb.v, acc[0], 0, 0, 0);
        acc[1] = __builtin_amdgcn_mfma_f32_16x16x32_bf16(af1, bb.v, acc[1], 0, 0, 0);
    }
    if (x < 30) {
#pragma unroll
        for (int mi = 0; mi < 2; ++mi) {
            int oc0 = (mtg * 2 + mi) * 16 + quad * 4;
#pragma unroll
            for (int r2 = 0; r2 < 4; ++r2)
                out[(size_t)b * 42240 + (oc0 + r2) * 660 + y * 30 + x] = f2bf(acc[mi][r2]);
        }
    }
}

// ---------------- fc1 v2: LDS-staged double-buffered bf16 MFMA GEMM.
__global__ __launch_bounds__(256) void k_fc1_mfma(const unsigned short* __restrict__ A,
                                                  const float* __restrict__ W,
                                                  float* __restrict__ part) {
    int kc = blockIdx.x;  // 0..59, 704 K each
    int nb = blockIdx.y;  // 0..3
    int tid = threadIdx.x;
    int wave = tid >> 6, lane = tid & 63;
    int m16 = lane & 15, quad = lane >> 4;
    __shared__ __align__(16) char lw[2][64 * 80];    // W: 64 rows x 32 bf16, stride 80
    __shared__ __align__(16) char la[2][128 * 80];   // A: 128 rows x 32 bf16, stride 80
    int k0 = kc * 704;
    int wrow = tid >> 2, wseg = tid & 3;   // 4 thr/row x 8 fp32
    const float* wsrc = W + (size_t)(nb * 64 + wrow) * 42240 + k0 + wseg * 8;
    int arow = tid >> 1, aseg = tid & 1;   // 2 thr/row x 16 bf16
    const uint4* asrc = (const uint4*)(A + (size_t)arow * 42240 + k0) + aseg * 2;
    float4 wr0 = ((const float4*)wsrc)[0];
    float4 wr1 = ((const float4*)wsrc)[1];
    uint4 ar0 = asrc[0];
    uint4 ar1 = asrc[1];
    f32x4 acc[8] = {};
    char* lwf = nullptr;
    for (int ks = 0; ks < 22; ++ks) {
        int buf = ks & 1;
        uint4 wp;
        wp.x = pkbf2(wr0.x, wr0.y); wp.y = pkbf2(wr0.z, wr0.w);
        wp.z = pkbf2(wr1.x, wr1.y); wp.w = pkbf2(wr1.z, wr1.w);
        *(uint4*)(lw[buf] + wrow * 80 + wseg * 16) = wp;
        *(uint4*)(la[buf] + arow * 80 + aseg * 32) = ar0;
        *(uint4*)(la[buf] + arow * 80 + aseg * 32 + 16) = ar1;
        if (ks < 21) {
            wsrc += 32;
            asrc += 4;
            wr0 = ((const float4*)wsrc)[0];
            wr1 = ((const float4*)wsrc)[1];
            ar0 = asrc[0];
            ar1 = asrc[1];
        }
        __syncthreads();
        bf16x8 wf = *(const bf16x8*)(lw[buf] + (wave * 16 + m16) * 80 + quad * 16);
        const char* lab = la[buf] + m16 * 80 + quad * 16;
#pragma unroll
        for (int tm = 0; tm < 8; ++tm) {
            bf16x8 af = *(const bf16x8*)(lab + tm * 16 * 80);
            acc[tm] = __builtin_amdgcn_mfma_f32_16x16x32_bf16(af, wf, acc[tm], 0, 0, 0);
        }
        (void)lwf;
    }
    int n = nb * 64 + wave * 16 + m16;
    float* pb = part + ((size_t)kc * 128) * 256 + n;
#pragma unroll
    for (int tm = 0; tm < 8; ++tm) {
        int row = tm * 16 + quad * 4;
#pragma unroll
        for (int r = 0; r < 4; ++r) pb[(size_t)(row + r) * 256] = acc[tm][r];
    }
}

// ---------------- fc1-combine + fc2 + lowd1 + lowd2 fused -> cnn_out2
__global__ __launch_bounds__(128) void k_head(const float* __restrict__ part,
                                              const float* __restrict__ f1b,
                                              const float* __restrict__ w2, const float* __restrict__ b2,
                                              const float* __restrict__ lw1, const float* __restrict__ lb1,
                                              const float* __restrict__ lw2, const float* __restrict__ lb2,
                                              float* __restrict__ cnn2) {
    int b = blockIdx.x, n = threadIdx.x;
    __shared__ float xa[256];
    __shared__ float xb[128];
    __shared__ float xc[128];
#pragma unroll
    for (int h = 0; h < 2; ++h) {
        int col = n + h * 128;
        float s = f1b[col];
        for (int kc = 0; kc < 60; ++kc) s += part[((size_t)kc * 128 + b) * 256 + col];
        xa[col] = fmaxf(s, 0.f);
    }
    __syncthreads();
    float acc = b2[n];
    for (int k = 0; k < 256; ++k) acc = fmaf(xa[k], w2[n * 256 + k], acc);
    xb[n] = acc;
    __syncthreads();
    acc = lb1[n];
    for (int k = 0; k < 128; ++k) acc = fmaf(xb[k], lw1[n * 128 + k], acc);
    xc[n] = fmaxf(acc, 0.f);
    __syncthreads();
    acc = lb2[n];
    for (int k = 0; k < 128; ++k) acc = fmaf(xc[k], lw2[n * 128 + k], acc);
    cnn2[b * 128 + n] = acc;
}

// ---------------- action MLP
__global__ __launch_bounds__(256) void k_act(const float* __restrict__ ain,
                                             const float* __restrict__ w1, const float* __restrict__ b1,
                                             const float* __restrict__ w2, const float* __restrict__ b2,
                                             float* __restrict__ abuf) {
    int idx = blockIdx.x * 256 + threadIdx.x;
    float x0 = ain[idx * 2], x1 = ain[idx * 2 + 1];
    float h1[16];
#pragma unroll
    for (int i = 0; i < 16; ++i)
        h1[i] = fmaxf(fmaf(x0, w1[i * 2], fmaf(x1, w1[i * 2 + 1], b1[i])), 0.f);
#pragma unroll
    for (int i = 0; i < 16; ++i) {
        float a = b2[i];
#pragma unroll
        for (int j = 0; j < 16; ++j) a = fmaf(h1[j], w2[i * 16 + j], a);
        abuf[idx * 16 + i] = a;
    }
}

// ---------------- LSTM v2: layer-pipelined systolic waves.
// 128 blocks (1 sample) x 4 waves. Phase P: wave w = layer P*4+w.
// 11 pipelined steps per phase (t = s - w). h handoff wave->wave via LDS packed
// f16 pairs (pair m = (h[2m],h[2m+1]) at word m). Layer-3 h parked in h3pk for
// phase 1. Weights: 64 uint4/lane loaded VOLATILE (blocks rematerialization ->
// stays VGPR-resident; launch_bounds(256,1) gives the 512-VGPR budget).
__global__ __launch_bounds__(256, 1) void k_lstm(const float* __restrict__ abuf,
                                                 const float* __restrict__ cnn2,
                                                 const uint32_t* __restrict__ wpk,
                                                 const float* __restrict__ bih,
                                                 const float* __restrict__ bhh,
                                                 float* __restrict__ lout) {
    int b = blockIdx.x;
    int tid = threadIdx.x;
    int w = tid >> 6, lane = tid & 63;
    __shared__ uint32_t hbuf[2][3][32];   // [step parity][producer wave][pair]
    __shared__ uint32_t h3pk[8][32];      // layer-3 h pairs for all t (phase 0 -> 1)

    // layer-0 x pairs: lane p (p<8) holds (a[2p], a[2p+1]); others zero.
    uint32_t xq[8];
#pragma unroll
    for (int t = 0; t < 8; ++t) {
        float x0 = 0.f, x1 = 0.f;
        if (lane < 8) {
            const float* ap = abuf + (b * 8 + t) * 16 + 2 * lane;
            x0 = ap[0];
            x1 = ap[1];
        }
        xq[t] = pkh2(x0, x1);
    }
    float h0 = cnn2[b * 128 + 64 + lane];
    float c0 = cnn2[b * 128 + lane];
    const u32x4* wbase = (const u32x4*)wpk;

#pragma unroll
    for (int P = 0; P < 2; ++P) {
        const int L = P * 4 + w;
        const volatile u32x4* wp = (const volatile u32x4*)(wbase + (size_t)L * 4096 + lane);
        u32x4 wreg[64];
#pragma unroll
        for (int j = 0; j < 64; ++j) wreg[j] = wp[j * 64];
        float bias0 = bih[L * 256 + lane] + bhh[L * 256 + lane];
        float bias1 = bih[L * 256 + 64 + lane] + bhh[L * 256 + 64 + lane];
        float bias2 = bih[L * 256 + 128 + lane] + bhh[L * 256 + 128 + lane];
        float bias3 = bih[L * 256 + 192 + lane] + bhh[L * 256 + 192 + lane];
        float h = h0, c = c0;
        uint32_t hpk = packpair(h);

        for (int s = 0; s < 11; ++s) {
            if (s >= w && s < w + 8) {  // wave-uniform
                uint32_t xcur;
                if (w == 0)
                    xcur = (P == 0) ? xq[0] : h3pk[s][lane & 31];
                else
                    xcur = hbuf[(s & 1) ^ 1][w - 1][lane & 31];
                float a0 = bias0, a1 = bias1, a2 = bias2, a3 = bias3;
#pragma unroll
                for (int p = 0; p < 32; ++p) {
                    uint32_t bx = (uint32_t)__builtin_amdgcn_readlane((int)xcur, p);
                    int q = p >> 2, e = p & 3;
                    a0 = dot2(comp4v(wreg[q], e), bx, a0);
                    a1 = dot2(comp4v(wreg[16 + q], e), bx, a1);
                    a2 = dot2(comp4v(wreg[32 + q], e), bx, a2);
                    a3 = dot2(comp4v(wreg[48 + q], e), bx, a3);
                }
#pragma unroll
                for (int m = 0; m < 32; ++m) {
                    uint32_t bh = (uint32_t)__builtin_amdgcn_readlane((int)hpk, 2 * m);
                    int q = 8 + (m >> 2), e = m & 3;
                    a0 = dot2(comp4v(wreg[q], e), bh, a0);
                    a1 = dot2(comp4v(wreg[16 + q], e), bh, a1);
                    a2 = dot2(comp4v(wreg[32 + q], e), bh, a2);
                    a3 = dot2(comp4v(wreg[48 + q], e), bh, a3);
                }
                float gi = sigm(a0), gf = sigm(a1), gv = tanh_(a2), go = sigm(a3);
                c = gf * c + gi * gv;
                h = go * tanh_(c);
                hpk = packpair(h);
                if (w < 3) {
                    if (!(lane & 1)) hbuf[s & 1][w][lane >> 1] = hpk;
                } else if (P == 0) {
                    if (!(lane & 1)) h3pk[s - 3][lane >> 1] = hpk;
                } else {
                    lout[((size_t)b * 8 + (s - 3)) * 64 + lane] = h;
                }
            }
            if (P == 0 && w == 0) {  // shift x queue (static indices only)
#pragma unroll
                for (int k = 0; k < 7; ++k) xq[k] = xq[k + 1];
            }
            __syncthreads();
        }
    }
}

// ---------------- out MLP + rotation -> d_out (128,8,4)
__global__ __launch_bounds__(256) void k_out(const float* __restrict__ lout,
                                             const float* __restrict__ w1, const float* __restrict__ b1,
                                             const float* __restrict__ w2, const float* __restrict__ b2,
                                             const float* __restrict__ gt, float* __restrict__ out) {
    int idx = blockIdx.x * 256 + threadIdx.x;
    int b = idx >> 3;
    float x[64];
#pragma unroll
    for (int j = 0; j < 64; ++j) x[j] = lout[idx * 64 + j];
    float h[32];
#pragma unroll 8
    for (int i = 0; i < 32; ++i) {
        float a = b1[i];
#pragma unroll
        for (int j = 0; j < 64; ++j) a = fmaf(x[j], w1[i * 64 + j], a);
        h[i] = fmaxf(a, 0.f);
    }
    float mo[4];
#pragma unroll
    for (int i = 0; i < 4; ++i) {
        float a = b2[i];
#pragma unroll
        for (int j = 0; j < 32; ++j) a = fmaf(h[j], w2[i * 32 + j], a);
        mo[i] = a;
    }
    float yaw = gt[b * 48 + 5];
    float cy = cosf(yaw), sy = sinf(yaw);
    out[idx * 4 + 0] = fmaf(mo[0], cy, fmaf(mo[1], sy, gt[b * 48 + 1]));
    out[idx * 4 + 1] = fmaf(mo[0], -sy, fmaf(mo[1], cy, gt[b * 48 + 2]));
    out[idx * 4 + 2] = mo[2] + gt[b * 48 + 3];
    out[idx * 4 + 3] = mo[3];
}

extern "C" void kernel_launch(void* const* d_in, const int* in_sizes, int n_in,
                              void* d_out, int out_size, void* d_ws, size_t ws_size,
                              hipStream_t stream) {
    const float* img = (const float*)d_in[0];
    const float* ain = (const float*)d_in[1];
    const float* gt = (const float*)d_in[2];
    const float* c1w = (const float*)d_in[3];
    const float* c1b = (const float*)d_in[4];
    const float* c2w = (const float*)d_in[5];
    const float* c2b = (const float*)d_in[6];
    const float* c3w = (const float*)d_in[7];
    const float* c3b = (const float*)d_in[8];
    const float* f1w = (const float*)d_in[9];
    const float* f1b = (const float*)d_in[10];
    const float* f2w = (const float*)d_in[11];
    const float* f2b = (const float*)d_in[12];
    const float* l1w = (const float*)d_in[13];
    const float* l1b = (const float*)d_in[14];
    const float* l2w = (const float*)d_in[15];
    const float* l2b = (const float*)d_in[16];
    const float* a1w = (const float*)d_in[17];
    const float* a1b = (const float*)d_in[18];
    const float* a2w = (const float*)d_in[19];
    const float* a2b = (const float*)d_in[20];
    const float* wih0 = (const float*)d_in[21];
    const float* wih = (const float*)d_in[22];
    const float* whh = (const float*)d_in[23];
    const float* bihp = (const float*)d_in[24];
    const float* bhhp = (const float*)d_in[25];
    const float* o1w = (const float*)d_in[26];
    const float* o1b = (const float*)d_in[27];
    const float* o2w = (const float*)d_in[28];
    const float* o2b = (const float*)d_in[29];
    float* out = (float*)d_out;

    char* ws = (char*)d_ws;
    unsigned short* c1o = (unsigned short*)(ws);                 // 97,026,048 B
    unsigned short* c2o = (unsigned short*)(ws + 97026048);      // 46,727,168 B
    unsigned short* c3o = (unsigned short*)(ws + 143753216);     // 10,813,440 B
    float* f1p = (float*)(ws + 154566656);                       // 60*128*256*4 = 7,864,320 B
    float* cnn2 = (float*)(ws + 163348480);
    float* abuf = (float*)(ws + 163414016);
    float* lo = (float*)(ws + 163479552);
    unsigned short* w1t = (unsigned short*)(ws + 163741696);     // 8,192 B
    unsigned short* w2t = (unsigned short*)(ws + 163749888);     // 36,864 B
    unsigned short* w3t = (unsigned short*)(ws + 163786752);     // 73,728 B
    uint32_t* wpk = (uint32_t*)(ws + 163860480);                 // 524,288 B

    k_wprep<<<232, 256, 0, stream>>>(c1w, c2w, c3w, w1t, w2t, w3t);
    k_wprep_lstm<<<128, 256, 0, stream>>>(wih0, wih, whh, wpk);
    k_conv1m<<<dim3(128, 24), 256, 0, stream>>>(img, w1t, c1b, c1o);
    k_conv2m<<<dim3(128, 46), 256, 0, stream>>>(c1o, w2t, c2b, c2o);
    k_conv3m<<<dim3(128, 22), 256, 0, stream>>>(c2o, w3t, c3b, c3o);
    k_fc1_mfma<<<dim3(60, 4), 256, 0, stream>>>(c3o, f1w, f1p);
    k_head<<<128, 128, 0, stream>>>(f1p, f1b, f2w, f2b, l1w, l1b, l2w, l2b, cnn2);
    k_act<<<4, 256, 0, stream>>>(ain, a1w, a1b, a2w, a2b, abuf);
    k_lstm<<<128, 256, 0, stream>>>(abuf, cnn2, wpk, bihp, bhhp, lo);
    k_out<<<4, 256, 0, stream>>>(lo, o1w, o1b, o2w, o2b, gt, out);
}

// Round 2
// 458.167 us; speedup vs baseline: 1.0054x; 1.0054x over previous
//
#include <hip/hip_runtime.h>
#include <cstdint>

#define DEV __device__ __forceinline__

typedef __attribute__((ext_vector_type(8))) short bf16x8;
typedef __attribute__((ext_vector_type(4))) float f32x4;
typedef __attribute__((ext_vector_type(2))) __fp16 h2t;
typedef __attribute__((ext_vector_type(4))) unsigned int u32x4;
typedef unsigned long long u64;

DEV unsigned short f2bf(float f) {
    unsigned u = __float_as_uint(f);
    unsigned r = u + 0x7fffu + ((u >> 16) & 1u);
    return (unsigned short)(r >> 16);
}
DEV uint32_t pkbf2(float a, float b) {
    return (uint32_t)f2bf(a) | ((uint32_t)f2bf(b) << 16);
}
DEV uint32_t pkh2(float a, float b) {
    h2t p = __builtin_amdgcn_cvt_pkrtz(a, b);
    union { h2t h; uint32_t u; } c;
    c.h = p;
    return c.u;
}
DEV float dot2(uint32_t w, uint32_t x, float acc) {
    union { uint32_t u; h2t h; } a, b;
    a.u = w; b.u = x;
    return __builtin_amdgcn_fdot2(a.h, b.h, acc, false);
}
DEV float sigm(float x) { return __builtin_amdgcn_rcpf(1.f + __expf(-x)); }
DEV float tanh_(float x) { return fmaf(2.f, sigm(2.f * x), -1.f); }
DEV uint32_t packpair(float h) {
    float hs = __int_as_float(__builtin_amdgcn_ds_swizzle(__float_as_int(h), 0x041F));
    return pkh2(h, hs);
}
DEV uint32_t comp4v(u32x4 v, int e) {
    return (e == 0) ? v[0] : (e == 1) ? v[1] : (e == 2) ? v[2] : v[3];
}
DEV u64 pack4bf(float a, float b, float c, float d) {
    unsigned lo = (unsigned)f2bf(a) | ((unsigned)f2bf(b) << 16);
    unsigned hi = (unsigned)f2bf(c) | ((unsigned)f2bf(d) << 16);
    return (u64)lo | ((u64)hi << 32);
}

// ---------------- weight prep (bf16, K-chunk order)
__global__ __launch_bounds__(256) void k_wprep(const float* __restrict__ w1,
                                               const float* __restrict__ w2,
                                               const float* __restrict__ w3,
                                               unsigned short* __restrict__ w1t,
                                               unsigned short* __restrict__ w2t,
                                               unsigned short* __restrict__ w3t) {
    int i = blockIdx.x * 256 + threadIdx.x;
    if (i < 32 * 128) {
        int oc = i >> 7, k = i & 127;
        int cc = k >> 3, u = (k >> 2) & 1, c = k & 3;
        int r = cc / 3, kx = 2 * (cc - 3 * r) + u;
        w1t[i] = (cc < 15 && kx < 5 && c < 3) ? f2bf(w1[oc * 75 + c * 25 + r * 5 + kx])
                                              : (unsigned short)0;
    } else if (i < 32 * 128 + 64 * 288) {
        int j = i - 32 * 128;
        int oc = j / 288, k = j - oc * 288;
        int pos = k >> 5, c = k & 31;
        w2t[j] = f2bf(w2[oc * 288 + c * 9 + pos]);
    } else if (i < 32 * 128 + 64 * 288 + 64 * 576) {
        int j = i - 32 * 128 - 64 * 288;
        int oc = j / 576, k = j - oc * 576;
        int pos = k >> 6, c = k & 63;
        w3t[j] = f2bf(w3[oc * 576 + c * 9 + pos]);
    }
}

// ---------------- LSTM weight prep: f16 pairs (see k_lstm)
__global__ __launch_bounds__(256) void k_wprep_lstm(const float* __restrict__ Wih0,
                                                    const float* __restrict__ Wih,
                                                    const float* __restrict__ Whh,
                                                    uint32_t* __restrict__ wpk) {
    int idx = blockIdx.x * 256 + threadIdx.x;  // 0..32767
    int lane = idx & 63;
    int j = (idx >> 6) & 63;
    int l = idx >> 12;
    int g = j >> 4, q = j & 15;
    int r = g * 64 + lane;
    uint32_t ov[4];
#pragma unroll
    for (int e = 0; e < 4; ++e) {
        int p = q * 4 + e;
        float w0, w1;
        if (p < 32) {
            int k0 = 2 * p;
            if (l == 0) {
                w0 = (k0 < 16) ? Wih0[r * 16 + k0] : 0.f;
                w1 = (k0 + 1 < 16) ? Wih0[r * 16 + k0 + 1] : 0.f;
            } else {
                const float* base = Wih + ((size_t)(l - 1) * 256 + r) * 64;
                w0 = base[k0];
                w1 = base[k0 + 1];
            }
        } else {
            int k0 = 2 * (p - 32);
            const float* base = Whh + ((size_t)l * 256 + r) * 64;
            w0 = base[k0];
            w1 = base[k0 + 1];
        }
        ov[e] = pkh2(w0, w1);
    }
    uint4 v;
    v.x = ov[0]; v.y = ov[1]; v.z = ov[2]; v.w = ov[3];
    ((uint4*)wpk)[idx] = v;
}

// ---------------- conv1: 4 output rows/block, wave=row. Weights hoisted to regs.
__global__ __launch_bounds__(256) void k_conv1m(const float* __restrict__ img,
                                                const unsigned short* __restrict__ w1t,
                                                const float* __restrict__ bias,
                                                unsigned short* __restrict__ out) {
    int b = blockIdx.x, y0 = blockIdx.y * 4;
    int tid = threadIdx.x;
    int wave = tid >> 6, lane = tid & 63;
    int quad = lane >> 4, nl = lane & 15;
    __shared__ __align__(16) unsigned short lds[12 * 1040];
    char* lb = (char*)lds;
    // hoist weights: pinned into regs by the pre-compute __syncthreads (vmcnt drain)
    bf16x8 wfa[4], wfb[4];
#pragma unroll
    for (int ks = 0; ks < 4; ++ks) {
        wfa[ks] = *(const bf16x8*)(w1t + nl * 128 + ks * 32 + quad * 8);
        wfb[ks] = *(const bf16x8*)(w1t + (16 + nl) * 128 + ks * 32 + quad * 8);
    }
    const float* ib = img + (size_t)b * 3 * 192 * 256;
#pragma unroll
    for (int r = 0; r < 12; ++r) {
        if (r < 11) {
            int row = 2 * y0 + r;
            if (row > 191) row = 191;
            const float* ip = ib + row * 256 + tid;
            float f0 = ip[0], f1 = ip[192 * 256], f2 = ip[2 * 192 * 256];
            uint32_t lo = (uint32_t)f2bf(f0) | ((uint32_t)f2bf(f1) << 16);
            *(u64*)(lb + r * 2080 + tid * 8) = (u64)lo | ((u64)f2bf(f2) << 32);
        } else {
            *(u64*)(lb + 11 * 2080 + tid * 8) = 0ull;
        }
    }
    __syncthreads();
    int ly = wave;
    float4 bv0 = *(const float4*)(bias + quad * 4);
    float4 bv1 = *(const float4*)(bias + 16 + quad * 4);
    f32x4 acc[8][2];
#pragma unroll
    for (int nt = 0; nt < 8; ++nt) {
        acc[nt][0][0] = bv0.x; acc[nt][0][1] = bv0.y; acc[nt][0][2] = bv0.z; acc[nt][0][3] = bv0.w;
        acc[nt][1][0] = bv1.x; acc[nt][1][1] = bv1.y; acc[nt][1][2] = bv1.z; acc[nt][1][3] = bv1.w;
    }
#pragma unroll
    for (int ks = 0; ks < 4; ++ks) {
        int cc = ks * 4 + quad;
        int r = cc / 3, kxp = cc - 3 * r;
        int rb = (2 * ly + r) * 2080 + kxp * 16 + nl * 16;
#pragma unroll
        for (int nt = 0; nt < 8; ++nt) {
            bf16x8 bv = *(const bf16x8*)(lb + rb + nt * 256);
            acc[nt][0] = __builtin_amdgcn_mfma_f32_16x16x32_bf16(wfa[ks], bv, acc[nt][0], 0, 0, 0);
            acc[nt][1] = __builtin_amdgcn_mfma_f32_16x16x32_bf16(wfb[ks], bv, acc[nt][1], 0, 0, 0);
        }
    }
    int y = y0 + ly;
    if (y < 94) {
#pragma unroll
        for (int nt = 0; nt < 8; ++nt) {
            int x = nt * 16 + nl;
            if (x < 126) {
#pragma unroll
                for (int mi = 0; mi < 2; ++mi) {
                    f32x4 a = acc[nt][mi];
                    u64 pk = pack4bf(fmaxf(a[0], 0.f), fmaxf(a[1], 0.f),
                                     fmaxf(a[2], 0.f), fmaxf(a[3], 0.f));
                    *(u64*)(out + (((size_t)b * 94 + y) * 126 + x) * 32 + mi * 16 + quad * 4) = pk;
                }
            }
        }
    }
}

// ---------------- conv2: NHWC in -> NHWC out [128][46][62][64]. Weights hoisted.
__global__ __launch_bounds__(256) void k_conv2m(const unsigned short* __restrict__ in,
                                                const unsigned short* __restrict__ w2t,
                                                const float* __restrict__ bias,
                                                unsigned short* __restrict__ out) {
    int b = blockIdx.x, y = blockIdx.y;
    int tid = threadIdx.x;
    int wave = tid >> 6, lane = tid & 63;
    int quad = lane >> 4, nl = lane & 15;
    int mtg = wave & 1, ntg = wave >> 1;
    __shared__ __align__(16) unsigned short lds[3 * 130 * 36];
    char* lb = (char*)lds;
    bf16x8 wfa[9], wfb[9];
#pragma unroll
    for (int ks = 0; ks < 9; ++ks) {
        wfa[ks] = *(const bf16x8*)(w2t + ((mtg * 2 + 0) * 16 + nl) * 288 + ks * 32 + quad * 8);
        wfb[ks] = *(const bf16x8*)(w2t + ((mtg * 2 + 1) * 16 + nl) * 288 + ks * 32 + quad * 8);
    }
    const u64* in64 = (const u64*)in;
    size_t gbase = ((size_t)b * 94 + 2 * y) * 126 * 8;
    for (int u = tid; u < 3024; u += 256) {
        int r = u / 1008, rem = u - r * 1008;
        int p = rem >> 3, h = rem & 7;
        u64 v = in64[gbase + (size_t)r * 126 * 8 + p * 8 + h];
        *(u64*)(lb + r * 9360 + p * 72 + h * 8) = v;
    }
    __syncthreads();
    f32x4 acc[4];
#pragma unroll
    for (int mi = 0; mi < 2; ++mi) {
        float4 bv = *(const float4*)(bias + (mtg * 2 + mi) * 16 + quad * 4);
#pragma unroll
        for (int ni = 0; ni < 2; ++ni) {
            acc[mi * 2 + ni][0] = bv.x; acc[mi * 2 + ni][1] = bv.y;
            acc[mi * 2 + ni][2] = bv.z; acc[mi * 2 + ni][3] = bv.w;
        }
    }
#pragma unroll
    for (int ks = 0; ks < 9; ++ks) {
        const int r = ks / 3, kx = ks - r * 3;
        int ro = r * 9360 + 72 * kx + quad * 16;
#pragma unroll
        for (int ni = 0; ni < 2; ++ni) {
            int x = (ntg * 2 + ni) * 16 + nl;
            union { u64 d[2]; bf16x8 v; } bb;
            bb.d[0] = *(const u64*)(lb + ro + 144 * x);
            bb.d[1] = *(const u64*)(lb + ro + 144 * x + 8);
            acc[0 * 2 + ni] = __builtin_amdgcn_mfma_f32_16x16x32_bf16(wfa[ks], bb.v, acc[0 * 2 + ni], 0, 0, 0);
            acc[1 * 2 + ni] = __builtin_amdgcn_mfma_f32_16x16x32_bf16(wfb[ks], bb.v, acc[1 * 2 + ni], 0, 0, 0);
        }
    }
#pragma unroll
    for (int ni = 0; ni < 2; ++ni) {
        int x = (ntg * 2 + ni) * 16 + nl;
        if (x < 62) {
#pragma unroll
            for (int mi = 0; mi < 2; ++mi) {
                int oc0 = (mtg * 2 + mi) * 16 + quad * 4;
                f32x4 a = acc[mi * 2 + ni];
                u64 pk = pack4bf(fmaxf(a[0], 0.f), fmaxf(a[1], 0.f), fmaxf(a[2], 0.f), fmaxf(a[3], 0.f));
                *(u64*)(out + (((size_t)b * 46 + y) * 62 + x) * 64 + oc0) = pk;
            }
        }
    }
}

// ---------------- conv3: NHWC in -> NCHW-flatten bf16 [b][64*660]. Weights hoisted.
__global__ __launch_bounds__(256) void k_conv3m(const unsigned short* __restrict__ in,
                                                const unsigned short* __restrict__ w3t,
                                                const float* __restrict__ bias,
                                                unsigned short* __restrict__ out) {
    int b = blockIdx.x, y = blockIdx.y;
    int tid = threadIdx.x;
    int wave = tid >> 6, lane = tid & 63;
    int quad = lane >> 4, nl = lane & 15;
    int mtg = wave & 1, nt = wave >> 1;
    __shared__ __align__(16) unsigned short lds[3 * 65 * 68];
    char* lb = (char*)lds;
    bf16x8 wfa[18], wfb[18];
#pragma unroll
    for (int ks = 0; ks < 18; ++ks) {
        wfa[ks] = *(const bf16x8*)(w3t + ((mtg * 2 + 0) * 16 + nl) * 576 + ks * 32 + quad * 8);
        wfb[ks] = *(const bf16x8*)(w3t + ((mtg * 2 + 1) * 16 + nl) * 576 + ks * 32 + quad * 8);
    }
    const u64* in64 = (const u64*)in;
    size_t gbase = ((size_t)b * 46 + 2 * y) * 62 * 16;
    for (int u = tid; u < 2976; u += 256) {
        int r = u / 992, rem = u - r * 992;
        int p = rem >> 4, h = rem & 15;
        u64 v = in64[gbase + (size_t)r * 62 * 16 + p * 16 + h];
        *(u64*)(lb + r * 8840 + p * 136 + h * 8) = v;
    }
    __syncthreads();
    f32x4 acc[2];
#pragma unroll
    for (int mi = 0; mi < 2; ++mi) {
        float4 bv = *(const float4*)(bias + (mtg * 2 + mi) * 16 + quad * 4);
        acc[mi][0] = bv.x; acc[mi][1] = bv.y; acc[mi][2] = bv.z; acc[mi][3] = bv.w;
    }
    int x = nt * 16 + nl;
#pragma unroll
    for (int ks = 0; ks < 18; ++ks) {
        const int pos = ks >> 1, half = ks & 1;
        const int r = pos / 3, kx = pos - r * 3;
        int ro = r * 8840 + 136 * kx + half * 64 + quad * 16;
        union { u64 d[2]; bf16x8 v; } bb;
        bb.d[0] = *(const u64*)(lb + ro + 272 * x);
        bb.d[1] = *(const u64*)(lb + ro + 272 * x + 8);
        acc[0] = __builtin_amdgcn_mfma_f32_16x16x32_bf16(wfa[ks], bb.v, acc[0], 0, 0, 0);
        acc[1] = __builtin_amdgcn_mfma_f32_16x16x32_bf16(wfb[ks], bb.v, acc[1], 0, 0, 0);
    }
    if (x < 30) {
#pragma unroll
        for (int mi = 0; mi < 2; ++mi) {
            int oc0 = (mtg * 2 + mi) * 16 + quad * 4;
#pragma unroll
            for (int r2 = 0; r2 < 4; ++r2)
                out[(size_t)b * 42240 + (oc0 + r2) * 660 + y * 30 + x] = f2bf(acc[mi][r2]);
        }
    }
}

// ---------------- fc1 v2: LDS-staged double-buffered bf16 MFMA GEMM.
__global__ __launch_bounds__(256) void k_fc1_mfma(const unsigned short* __restrict__ A,
                                                  const float* __restrict__ W,
                                                  float* __restrict__ part) {
    int kc = blockIdx.x;  // 0..59, 704 K each
    int nb = blockIdx.y;  // 0..3
    int tid = threadIdx.x;
    int wave = tid >> 6, lane = tid & 63;
    int m16 = lane & 15, quad = lane >> 4;
    __shared__ __align__(16) char lw[2][64 * 80];    // W: 64 rows x 32 bf16, stride 80
    __shared__ __align__(16) char la[2][128 * 80];   // A: 128 rows x 32 bf16, stride 80
    int k0 = kc * 704;
    int wrow = tid >> 2, wseg = tid & 3;   // 4 thr/row x 8 fp32
    const float* wsrc = W + (size_t)(nb * 64 + wrow) * 42240 + k0 + wseg * 8;
    int arow = tid >> 1, aseg = tid & 1;   // 2 thr/row x 16 bf16
    const uint4* asrc = (const uint4*)(A + (size_t)arow * 42240 + k0) + aseg * 2;
    float4 wr0 = ((const float4*)wsrc)[0];
    float4 wr1 = ((const float4*)wsrc)[1];
    uint4 ar0 = asrc[0];
    uint4 ar1 = asrc[1];
    f32x4 acc[8] = {};
    for (int ks = 0; ks < 22; ++ks) {
        int buf = ks & 1;
        uint4 wp;
        wp.x = pkbf2(wr0.x, wr0.y); wp.y = pkbf2(wr0.z, wr0.w);
        wp.z = pkbf2(wr1.x, wr1.y); wp.w = pkbf2(wr1.z, wr1.w);
        *(uint4*)(lw[buf] + wrow * 80 + wseg * 16) = wp;
        *(uint4*)(la[buf] + arow * 80 + aseg * 32) = ar0;
        *(uint4*)(la[buf] + arow * 80 + aseg * 32 + 16) = ar1;
        if (ks < 21) {
            wsrc += 32;
            asrc += 4;
            wr0 = ((const float4*)wsrc)[0];
            wr1 = ((const float4*)wsrc)[1];
            ar0 = asrc[0];
            ar1 = asrc[1];
        }
        __syncthreads();
        bf16x8 wf = *(const bf16x8*)(lw[buf] + (wave * 16 + m16) * 80 + quad * 16);
        const char* lab = la[buf] + m16 * 80 + quad * 16;
#pragma unroll
        for (int tm = 0; tm < 8; ++tm) {
            bf16x8 af = *(const bf16x8*)(lab + tm * 16 * 80);
            acc[tm] = __builtin_amdgcn_mfma_f32_16x16x32_bf16(af, wf, acc[tm], 0, 0, 0);
        }
    }
    int n = nb * 64 + wave * 16 + m16;
    float* pb = part + ((size_t)kc * 128) * 256 + n;
#pragma unroll
    for (int tm = 0; tm < 8; ++tm) {
        int row = tm * 16 + quad * 4;
#pragma unroll
        for (int r = 0; r < 4; ++r) pb[(size_t)(row + r) * 256] = acc[tm][r];
    }
}

// ---------------- fc1-combine + fc2 + lowd1 + lowd2 fused -> cnn_out2
__global__ __launch_bounds__(128) void k_head(const float* __restrict__ part,
                                              const float* __restrict__ f1b,
                                              const float* __restrict__ w2, const float* __restrict__ b2,
                                              const float* __restrict__ lw1, const float* __restrict__ lb1,
                                              const float* __restrict__ lw2, const float* __restrict__ lb2,
                                              float* __restrict__ cnn2) {
    int b = blockIdx.x, n = threadIdx.x;
    __shared__ float xa[256];
    __shared__ float xb[128];
    __shared__ float xc[128];
#pragma unroll
    for (int h = 0; h < 2; ++h) {
        int col = n + h * 128;
        float s = f1b[col];
        for (int kc = 0; kc < 60; ++kc) s += part[((size_t)kc * 128 + b) * 256 + col];
        xa[col] = fmaxf(s, 0.f);
    }
    __syncthreads();
    float acc = b2[n];
    for (int k = 0; k < 256; ++k) acc = fmaf(xa[k], w2[n * 256 + k], acc);
    xb[n] = acc;
    __syncthreads();
    acc = lb1[n];
    for (int k = 0; k < 128; ++k) acc = fmaf(xb[k], lw1[n * 128 + k], acc);
    xc[n] = fmaxf(acc, 0.f);
    __syncthreads();
    acc = lb2[n];
    for (int k = 0; k < 128; ++k) acc = fmaf(xc[k], lw2[n * 128 + k], acc);
    cnn2[b * 128 + n] = acc;
}

// ---------------- action MLP
__global__ __launch_bounds__(256) void k_act(const float* __restrict__ ain,
                                             const float* __restrict__ w1, const float* __restrict__ b1,
                                             const float* __restrict__ w2, const float* __restrict__ b2,
                                             float* __restrict__ abuf) {
    int idx = blockIdx.x * 256 + threadIdx.x;
    float x0 = ain[idx * 2], x1 = ain[idx * 2 + 1];
    float h1[16];
#pragma unroll
    for (int i = 0; i < 16; ++i)
        h1[i] = fmaxf(fmaf(x0, w1[i * 2], fmaf(x1, w1[i * 2 + 1], b1[i])), 0.f);
#pragma unroll
    for (int i = 0; i < 16; ++i) {
        float a = b2[i];
#pragma unroll
        for (int j = 0; j < 16; ++j) a = fmaf(h1[j], w2[i * 16 + j], a);
        abuf[idx * 16 + i] = a;
    }
}

// ---------------- LSTM v3: layer-pipelined, weights k-SPLIT across wave pairs.
// 128 blocks x 8 waves (512 thr). Wave w: layer-slot sl=w>>1 (0..3), part pt=w&1.
// pt=0 holds x-column weights (pairs 0..31) + biases; pt=1 holds h-column
// weights (pairs 32..63). 32 uint4/lane each = 128 VGPRs -> register-resident.
// Phase P: layers P*4+sl, 11 pipelined steps (t = s - sl). Per step: each wave
// computes 4 gate-partials (128 dot2), exchanges via LDS (barrier), both waves
// redundantly compute c,h (keeps recurrent h in-register for pt=1).
// Handoff: pt=0 writes packed h pairs to hbuf (next layer) / h3pk (phase 1) /
// lout (final). 22 sequential cell-steps total vs 64 unpipelined.
__global__ __launch_bounds__(512, 2) void k_lstm(const float* __restrict__ abuf,
                                                 const float* __restrict__ cnn2,
                                                 const uint32_t* __restrict__ wpk,
                                                 const float* __restrict__ bih,
                                                 const float* __restrict__ bhh,
                                                 float* __restrict__ lout) {
    int b = blockIdx.x;
    int tid = threadIdx.x;
    int w = tid >> 6, lane = tid & 63;
    int sl = w >> 1, pt = w & 1;
    __shared__ uint32_t hbuf[2][3][32];   // [step parity][producer slot][pair]
    __shared__ uint32_t h3pk[8][32];      // layer-3 h pairs (phase 0 -> 1)
    __shared__ float4 pex[8][64];         // gate-partial exchange

    // layer-0 x pairs: lane p (p<8) holds (a[2p], a[2p+1]); others zero.
    uint32_t xq[8];
#pragma unroll
    for (int t = 0; t < 8; ++t) {
        float x0 = 0.f, x1 = 0.f;
        if (lane < 8) {
            const float* ap = abuf + (b * 8 + t) * 16 + 2 * lane;
            x0 = ap[0];
            x1 = ap[1];
        }
        xq[t] = pkh2(x0, x1);
    }
    float h0 = cnn2[b * 128 + 64 + lane];
    float c0 = cnn2[b * 128 + lane];
    const u32x4* wbase = (const u32x4*)wpk;

#pragma unroll
    for (int P = 0; P < 2; ++P) {
        const int L = P * 4 + sl;
        u32x4 wreg[4][8];   // [gate][quad-of-pairs] -- 128 VGPRs, static-indexed
#pragma unroll
        for (int g = 0; g < 4; ++g)
#pragma unroll
            for (int q = 0; q < 8; ++q)
                wreg[g][q] = wbase[(size_t)L * 4096 + (g * 16 + pt * 8 + q) * 64 + lane];
        float bias0 = 0.f, bias1 = 0.f, bias2 = 0.f, bias3 = 0.f;
        if (pt == 0) {
            bias0 = bih[L * 256 + lane] + bhh[L * 256 + lane];
            bias1 = bih[L * 256 + 64 + lane] + bhh[L * 256 + 64 + lane];
            bias2 = bih[L * 256 + 128 + lane] + bhh[L * 256 + 128 + lane];
            bias3 = bih[L * 256 + 192 + lane] + bhh[L * 256 + 192 + lane];
        }
        float h = h0, c = c0;
        uint32_t hpk = packpair(h0);

        for (int s = 0; s < 11; ++s) {
            bool act = (s >= sl && s < sl + 8);
            float a0 = bias0, a1 = bias1, a2 = bias2, a3 = bias3;
            if (act) {
                if (pt == 0) {
                    uint32_t xcur;
                    if (sl == 0)
                        xcur = (P == 0) ? xq[0] : h3pk[s][lane & 31];
                    else
                        xcur = hbuf[(s & 1) ^ 1][sl - 1][lane & 31];
#pragma unroll
                    for (int m = 0; m < 32; ++m) {
                        uint32_t bx = (uint32_t)__builtin_amdgcn_readlane((int)xcur, m);
                        int q = m >> 2, e = m & 3;
                        a0 = dot2(comp4v(wreg[0][q], e), bx, a0);
                        a1 = dot2(comp4v(wreg[1][q], e), bx, a1);
                        a2 = dot2(comp4v(wreg[2][q], e), bx, a2);
                        a3 = dot2(comp4v(wreg[3][q], e), bx, a3);
                    }
                } else {
#pragma unroll
                    for (int m = 0; m < 32; ++m) {
                        uint32_t bh2 = (uint32_t)__builtin_amdgcn_readlane((int)hpk, 2 * m);
                        int q = m >> 2, e = m & 3;
                        a0 = dot2(comp4v(wreg[0][q], e), bh2, a0);
                        a1 = dot2(comp4v(wreg[1][q], e), bh2, a1);
                        a2 = dot2(comp4v(wreg[2][q], e), bh2, a2);
                        a3 = dot2(comp4v(wreg[3][q], e), bh2, a3);
                    }
                }
                float4 pv;
                pv.x = a0; pv.y = a1; pv.z = a2; pv.w = a3;
                pex[w][lane] = pv;
            }
            __syncthreads();
            if (act) {
                float4 po = pex[w ^ 1][lane];
                float g0 = a0 + po.x, g1 = a1 + po.y, g2 = a2 + po.z, g3 = a3 + po.w;
                float gi = sigm(g0), gf = sigm(g1), gv = tanh_(g2), go = sigm(g3);
                c = gf * c + gi * gv;
                h = go * tanh_(c);
                hpk = packpair(h);
                if (pt == 0) {
                    if (sl < 3) {
                        if (!(lane & 1)) hbuf[s & 1][sl][lane >> 1] = hpk;
                    } else if (P == 0) {
                        if (!(lane & 1)) h3pk[s - 3][lane >> 1] = hpk;
                    } else {
                        lout[((size_t)b * 8 + (s - 3)) * 64 + lane] = h;
                    }
                }
            }
            if (P == 0 && w == 0) {  // shift x queue (static indices only)
#pragma unroll
                for (int k = 0; k < 7; ++k) xq[k] = xq[k + 1];
            }
            __syncthreads();
        }
    }
}

// ---------------- out MLP + rotation -> d_out (128,8,4)
__global__ __launch_bounds__(256) void k_out(const float* __restrict__ lout,
                                             const float* __restrict__ w1, const float* __restrict__ b1,
                                             const float* __restrict__ w2, const float* __restrict__ b2,
                                             const float* __restrict__ gt, float* __restrict__ out) {
    int idx = blockIdx.x * 256 + threadIdx.x;
    int b = idx >> 3;
    float x[64];
#pragma unroll
    for (int j = 0; j < 64; ++j) x[j] = lout[idx * 64 + j];
    float h[32];
#pragma unroll 8
    for (int i = 0; i < 32; ++i) {
        float a = b1[i];
#pragma unroll
        for (int j = 0; j < 64; ++j) a = fmaf(x[j], w1[i * 64 + j], a);
        h[i] = fmaxf(a, 0.f);
    }
    float mo[4];
#pragma unroll
    for (int i = 0; i < 4; ++i) {
        float a = b2[i];
#pragma unroll
        for (int j = 0; j < 32; ++j) a = fmaf(h[j], w2[i * 32 + j], a);
        mo[i] = a;
    }
    float yaw = gt[b * 48 + 5];
    float cy = cosf(yaw), sy = sinf(yaw);
    out[idx * 4 + 0] = fmaf(mo[0], cy, fmaf(mo[1], sy, gt[b * 48 + 1]));
    out[idx * 4 + 1] = fmaf(mo[0], -sy, fmaf(mo[1], cy, gt[b * 48 + 2]));
    out[idx * 4 + 2] = mo[2] + gt[b * 48 + 3];
    out[idx * 4 + 3] = mo[3];
}

extern "C" void kernel_launch(void* const* d_in, const int* in_sizes, int n_in,
                              void* d_out, int out_size, void* d_ws, size_t ws_size,
                              hipStream_t stream) {
    const float* img = (const float*)d_in[0];
    const float* ain = (const float*)d_in[1];
    const float* gt = (const float*)d_in[2];
    const float* c1w = (const float*)d_in[3];
    const float* c1b = (const float*)d_in[4];
    const float* c2w = (const float*)d_in[5];
    const float* c2b = (const float*)d_in[6];
    const float* c3w = (const float*)d_in[7];
    const float* c3b = (const float*)d_in[8];
    const float* f1w = (const float*)d_in[9];
    const float* f1b = (const float*)d_in[10];
    const float* f2w = (const float*)d_in[11];
    const float* f2b = (const float*)d_in[12];
    const float* l1w = (const float*)d_in[13];
    const float* l1b = (const float*)d_in[14];
    const float* l2w = (const float*)d_in[15];
    const float* l2b = (const float*)d_in[16];
    const float* a1w = (const float*)d_in[17];
    const float* a1b = (const float*)d_in[18];
    const float* a2w = (const float*)d_in[19];
    const float* a2b = (const float*)d_in[20];
    const float* wih0 = (const float*)d_in[21];
    const float* wih = (const float*)d_in[22];
    const float* whh = (const float*)d_in[23];
    const float* bihp = (const float*)d_in[24];
    const float* bhhp = (const float*)d_in[25];
    const float* o1w = (const float*)d_in[26];
    const float* o1b = (const float*)d_in[27];
    const float* o2w = (const float*)d_in[28];
    const float* o2b = (const float*)d_in[29];
    float* out = (float*)d_out;

    char* ws = (char*)d_ws;
    unsigned short* c1o = (unsigned short*)(ws);                 // 97,026,048 B
    unsigned short* c2o = (unsigned short*)(ws + 97026048);      // 46,727,168 B
    unsigned short* c3o = (unsigned short*)(ws + 143753216);     // 10,813,440 B
    float* f1p = (float*)(ws + 154566656);                       // 60*128*256*4 = 7,864,320 B
    float* cnn2 = (float*)(ws + 163348480);
    float* abuf = (float*)(ws + 163414016);
    float* lo = (float*)(ws + 163479552);
    unsigned short* w1t = (unsigned short*)(ws + 163741696);     // 8,192 B
    unsigned short* w2t = (unsigned short*)(ws + 163749888);     // 36,864 B
    unsigned short* w3t = (unsigned short*)(ws + 163786752);     // 73,728 B
    uint32_t* wpk = (uint32_t*)(ws + 163860480);                 // 524,288 B

    k_wprep<<<232, 256, 0, stream>>>(c1w, c2w, c3w, w1t, w2t, w3t);
    k_wprep_lstm<<<128, 256, 0, stream>>>(wih0, wih, whh, wpk);
    k_conv1m<<<dim3(128, 24), 256, 0, stream>>>(img, w1t, c1b, c1o);
    k_conv2m<<<dim3(128, 46), 256, 0, stream>>>(c1o, w2t, c2b, c2o);
    k_conv3m<<<dim3(128, 22), 256, 0, stream>>>(c2o, w3t, c3b, c3o);
    k_fc1_mfma<<<dim3(60, 4), 256, 0, stream>>>(c3o, f1w, f1p);
    k_head<<<128, 128, 0, stream>>>(f1p, f1b, f2w, f2b, l1w, l1b, l2w, l2b, cnn2);
    k_act<<<4, 256, 0, stream>>>(ain, a1w, a1b, a2w, a2b, abuf);
    k_lstm<<<128, 512, 0, stream>>>(abuf, cnn2, wpk, bihp, bhhp, lo);
    k_out<<<4, 256, 0, stream>>>(lo, o1w, o1b, o2w, o2b, gt, out);
}

// Round 3
// 410.991 us; speedup vs baseline: 1.1208x; 1.1148x over previous
//
#include <hip/hip_runtime.h>
#include <cstdint>

#define DEV __device__ __forceinline__

typedef __attribute__((ext_vector_type(8))) short bf16x8;
typedef __attribute__((ext_vector_type(4))) float f32x4;
typedef __attribute__((ext_vector_type(2))) __fp16 h2t;
typedef __attribute__((ext_vector_type(4))) unsigned int u32x4;
typedef unsigned long long u64;

DEV unsigned short f2bf(float f) {
    unsigned u = __float_as_uint(f);
    unsigned r = u + 0x7fffu + ((u >> 16) & 1u);
    return (unsigned short)(r >> 16);
}
DEV uint32_t pkbf2(float a, float b) {
    return (uint32_t)f2bf(a) | ((uint32_t)f2bf(b) << 16);
}
DEV uint32_t pkh2(float a, float b) {
    h2t p = __builtin_amdgcn_cvt_pkrtz(a, b);
    union { h2t h; uint32_t u; } c;
    c.h = p;
    return c.u;
}
DEV float dot2(uint32_t w, uint32_t x, float acc) {
    union { uint32_t u; h2t h; } a, b;
    a.u = w; b.u = x;
    return __builtin_amdgcn_fdot2(a.h, b.h, acc, false);
}
DEV float sigm(float x) { return __builtin_amdgcn_rcpf(1.f + __expf(-x)); }
DEV float tanh_(float x) { return fmaf(2.f, sigm(2.f * x), -1.f); }
DEV uint32_t packpair(float h) {
    float hs = __int_as_float(__builtin_amdgcn_ds_swizzle(__float_as_int(h), 0x041F));
    return pkh2(h, hs);
}
DEV uint32_t comp4v(u32x4 v, int e) {
    return (e == 0) ? v[0] : (e == 1) ? v[1] : (e == 2) ? v[2] : v[3];
}
DEV u64 pack4bf(float a, float b, float c, float d) {
    unsigned lo = (unsigned)f2bf(a) | ((unsigned)f2bf(b) << 16);
    unsigned hi = (unsigned)f2bf(c) | ((unsigned)f2bf(d) << 16);
    return (u64)lo | ((u64)hi << 32);
}

// ---------------- weight prep (bf16, K-chunk order)
__global__ __launch_bounds__(256) void k_wprep(const float* __restrict__ w1,
                                               const float* __restrict__ w2,
                                               const float* __restrict__ w3,
                                               unsigned short* __restrict__ w1t,
                                               unsigned short* __restrict__ w2t,
                                               unsigned short* __restrict__ w3t) {
    int i = blockIdx.x * 256 + threadIdx.x;
    if (i < 32 * 128) {
        int oc = i >> 7, k = i & 127;
        int cc = k >> 3, u = (k >> 2) & 1, c = k & 3;
        int r = cc / 3, kx = 2 * (cc - 3 * r) + u;
        w1t[i] = (cc < 15 && kx < 5 && c < 3) ? f2bf(w1[oc * 75 + c * 25 + r * 5 + kx])
                                              : (unsigned short)0;
    } else if (i < 32 * 128 + 64 * 288) {
        int j = i - 32 * 128;
        int oc = j / 288, k = j - oc * 288;
        int pos = k >> 5, c = k & 31;
        w2t[j] = f2bf(w2[oc * 288 + c * 9 + pos]);
    } else if (i < 32 * 128 + 64 * 288 + 64 * 576) {
        int j = i - 32 * 128 - 64 * 288;
        int oc = j / 576, k = j - oc * 576;
        int pos = k >> 6, c = k & 63;
        w3t[j] = f2bf(w3[oc * 576 + c * 9 + pos]);
    }
}

// ---------------- LSTM weight prep: f16 pairs (see k_lstm)
__global__ __launch_bounds__(256) void k_wprep_lstm(const float* __restrict__ Wih0,
                                                    const float* __restrict__ Wih,
                                                    const float* __restrict__ Whh,
                                                    uint32_t* __restrict__ wpk) {
    int idx = blockIdx.x * 256 + threadIdx.x;  // 0..32767
    int lane = idx & 63;
    int j = (idx >> 6) & 63;
    int l = idx >> 12;
    int g = j >> 4, q = j & 15;
    int r = g * 64 + lane;
    uint32_t ov[4];
#pragma unroll
    for (int e = 0; e < 4; ++e) {
        int p = q * 4 + e;
        float w0, w1;
        if (p < 32) {
            int k0 = 2 * p;
            if (l == 0) {
                w0 = (k0 < 16) ? Wih0[r * 16 + k0] : 0.f;
                w1 = (k0 + 1 < 16) ? Wih0[r * 16 + k0 + 1] : 0.f;
            } else {
                const float* base = Wih + ((size_t)(l - 1) * 256 + r) * 64;
                w0 = base[k0];
                w1 = base[k0 + 1];
            }
        } else {
            int k0 = 2 * (p - 32);
            const float* base = Whh + ((size_t)l * 256 + r) * 64;
            w0 = base[k0];
            w1 = base[k0 + 1];
        }
        ov[e] = pkh2(w0, w1);
    }
    uint4 v;
    v.x = ov[0]; v.y = ov[1]; v.z = ov[2]; v.w = ov[3];
    ((uint4*)wpk)[idx] = v;
}

// ---------------- conv1: 4 output rows/block, wave=row. Batched staging.
__global__ __launch_bounds__(256, 3) void k_conv1m(const float* __restrict__ img,
                                                   const unsigned short* __restrict__ w1t,
                                                   const float* __restrict__ bias,
                                                   unsigned short* __restrict__ out) {
    int b = blockIdx.x, y0 = blockIdx.y * 4;
    int tid = threadIdx.x;
    __shared__ __align__(16) unsigned short lds[12 * 1040];
    char* lb = (char*)lds;
    const float* ib = img + (size_t)b * 3 * 192 * 256;
    // batch all 33 staging loads in flight, then write LDS
    float t0[11], t1[11], t2[11];
#pragma unroll
    for (int r = 0; r < 11; ++r) {
        int row = 2 * y0 + r;
        if (row > 191) row = 191;
        const float* ip = ib + row * 256 + tid;
        t0[r] = ip[0];
        t1[r] = ip[192 * 256];
        t2[r] = ip[2 * 192 * 256];
    }
#pragma unroll
    for (int r = 0; r < 11; ++r) {
        uint32_t lo = (uint32_t)f2bf(t0[r]) | ((uint32_t)f2bf(t1[r]) << 16);
        *(u64*)(lb + r * 2080 + tid * 8) = (u64)lo | ((u64)f2bf(t2[r]) << 32);
    }
    *(u64*)(lb + 11 * 2080 + tid * 8) = 0ull;
    __syncthreads();
    int wave = tid >> 6, lane = tid & 63;
    int quad = lane >> 4, nl = lane & 15;
    int ly = wave;
    float4 bv0 = *(const float4*)(bias + quad * 4);
    float4 bv1 = *(const float4*)(bias + 16 + quad * 4);
    f32x4 acc[8][2];
#pragma unroll
    for (int nt = 0; nt < 8; ++nt) {
        acc[nt][0][0] = bv0.x; acc[nt][0][1] = bv0.y; acc[nt][0][2] = bv0.z; acc[nt][0][3] = bv0.w;
        acc[nt][1][0] = bv1.x; acc[nt][1][1] = bv1.y; acc[nt][1][2] = bv1.z; acc[nt][1][3] = bv1.w;
    }
#pragma unroll
    for (int ks = 0; ks < 4; ++ks) {
        int cc = ks * 4 + quad;
        int r = cc / 3, kxp = cc - 3 * r;
        int rb = (2 * ly + r) * 2080 + kxp * 16 + nl * 16;
        bf16x8 af0 = *(const bf16x8*)(w1t + (nl) * 128 + ks * 32 + quad * 8);
        bf16x8 af1 = *(const bf16x8*)(w1t + (16 + nl) * 128 + ks * 32 + quad * 8);
#pragma unroll
        for (int nt = 0; nt < 8; ++nt) {
            bf16x8 bv = *(const bf16x8*)(lb + rb + nt * 256);
            acc[nt][0] = __builtin_amdgcn_mfma_f32_16x16x32_bf16(af0, bv, acc[nt][0], 0, 0, 0);
            acc[nt][1] = __builtin_amdgcn_mfma_f32_16x16x32_bf16(af1, bv, acc[nt][1], 0, 0, 0);
        }
    }
    int y = y0 + ly;
    if (y < 94) {
#pragma unroll
        for (int nt = 0; nt < 8; ++nt) {
            int x = nt * 16 + nl;
            if (x < 126) {
#pragma unroll
                for (int mi = 0; mi < 2; ++mi) {
                    f32x4 a = acc[nt][mi];
                    u64 pk = pack4bf(fmaxf(a[0], 0.f), fmaxf(a[1], 0.f),
                                     fmaxf(a[2], 0.f), fmaxf(a[3], 0.f));
                    *(u64*)(out + (((size_t)b * 94 + y) * 126 + x) * 32 + mi * 16 + quad * 4) = pk;
                }
            }
        }
    }
}

// ---------------- conv2: NHWC in -> NHWC out [128][46][62][64]. Batched staging.
__global__ __launch_bounds__(256, 4) void k_conv2m(const unsigned short* __restrict__ in,
                                                   const unsigned short* __restrict__ w2t,
                                                   const float* __restrict__ bias,
                                                   unsigned short* __restrict__ out) {
    int b = blockIdx.x, y = blockIdx.y;
    int tid = threadIdx.x;
    __shared__ __align__(16) unsigned short lds[3 * 130 * 36];
    char* lb = (char*)lds;
    const u64* in64 = (const u64*)in;
    size_t gbase = ((size_t)b * 94 + 2 * y) * 126 * 8;
    u64 tmp[12];
#pragma unroll
    for (int i = 0; i < 12; ++i) {
        int u = tid + i * 256;
        int uc = u < 3024 ? u : 3023;
        int r = uc / 1008, rem = uc - r * 1008;
        int p = rem >> 3, h = rem & 7;
        tmp[i] = in64[gbase + (size_t)r * 126 * 8 + p * 8 + h];
    }
#pragma unroll
    for (int i = 0; i < 12; ++i) {
        int u = tid + i * 256;
        if (u < 3024) {
            int r = u / 1008, rem = u - r * 1008;
            int p = rem >> 3, h = rem & 7;
            *(u64*)(lb + r * 9360 + p * 72 + h * 8) = tmp[i];
        }
    }
    __syncthreads();
    int wave = tid >> 6, lane = tid & 63;
    int quad = lane >> 4, nl = lane & 15;
    int mtg = wave & 1, ntg = wave >> 1;
    f32x4 acc[4];
#pragma unroll
    for (int mi = 0; mi < 2; ++mi) {
        float4 bv = *(const float4*)(bias + (mtg * 2 + mi) * 16 + quad * 4);
#pragma unroll
        for (int ni = 0; ni < 2; ++ni) {
            acc[mi * 2 + ni][0] = bv.x; acc[mi * 2 + ni][1] = bv.y;
            acc[mi * 2 + ni][2] = bv.z; acc[mi * 2 + ni][3] = bv.w;
        }
    }
#pragma unroll
    for (int ks = 0; ks < 9; ++ks) {
        const int r = ks / 3, kx = ks - r * 3;
        bf16x8 af0 = *(const bf16x8*)(w2t + ((mtg * 2 + 0) * 16 + nl) * 288 + ks * 32 + quad * 8);
        bf16x8 af1 = *(const bf16x8*)(w2t + ((mtg * 2 + 1) * 16 + nl) * 288 + ks * 32 + quad * 8);
        int ro = r * 9360 + 72 * kx + quad * 16;
#pragma unroll
        for (int ni = 0; ni < 2; ++ni) {
            int x = (ntg * 2 + ni) * 16 + nl;
            union { u64 d[2]; bf16x8 v; } bb;
            bb.d[0] = *(const u64*)(lb + ro + 144 * x);
            bb.d[1] = *(const u64*)(lb + ro + 144 * x + 8);
            acc[0 * 2 + ni] = __builtin_amdgcn_mfma_f32_16x16x32_bf16(af0, bb.v, acc[0 * 2 + ni], 0, 0, 0);
            acc[1 * 2 + ni] = __builtin_amdgcn_mfma_f32_16x16x32_bf16(af1, bb.v, acc[1 * 2 + ni], 0, 0, 0);
        }
    }
#pragma unroll
    for (int ni = 0; ni < 2; ++ni) {
        int x = (ntg * 2 + ni) * 16 + nl;
        if (x < 62) {
#pragma unroll
            for (int mi = 0; mi < 2; ++mi) {
                int oc0 = (mtg * 2 + mi) * 16 + quad * 4;
                f32x4 a = acc[mi * 2 + ni];
                u64 pk = pack4bf(fmaxf(a[0], 0.f), fmaxf(a[1], 0.f), fmaxf(a[2], 0.f), fmaxf(a[3], 0.f));
                *(u64*)(out + (((size_t)b * 46 + y) * 62 + x) * 64 + oc0) = pk;
            }
        }
    }
}

// ---------------- conv3: NHWC in -> NCHW-flatten bf16 [b][64*660]. Batched staging.
__global__ __launch_bounds__(256, 4) void k_conv3m(const unsigned short* __restrict__ in,
                                                   const unsigned short* __restrict__ w3t,
                                                   const float* __restrict__ bias,
                                                   unsigned short* __restrict__ out) {
    int b = blockIdx.x, y = blockIdx.y;
    int tid = threadIdx.x;
    __shared__ __align__(16) unsigned short lds[3 * 65 * 68];
    char* lb = (char*)lds;
    const u64* in64 = (const u64*)in;
    size_t gbase = ((size_t)b * 46 + 2 * y) * 62 * 16;
    u64 tmp[12];
#pragma unroll
    for (int i = 0; i < 12; ++i) {
        int u = tid + i * 256;
        int uc = u < 2976 ? u : 2975;
        int r = uc / 992, rem = uc - r * 992;
        int p = rem >> 4, h = rem & 15;
        tmp[i] = in64[gbase + (size_t)r * 992 + p * 16 + h];
    }
#pragma unroll
    for (int i = 0; i < 12; ++i) {
        int u = tid + i * 256;
        if (u < 2976) {
            int r = u / 992, rem = u - r * 992;
            int p = rem >> 4, h = rem & 15;
            *(u64*)(lb + r * 8840 + p * 136 + h * 8) = tmp[i];
        }
    }
    __syncthreads();
    int wave = tid >> 6, lane = tid & 63;
    int quad = lane >> 4, nl = lane & 15;
    int mtg = wave & 1, nt = wave >> 1;
    f32x4 acc[2];
#pragma unroll
    for (int mi = 0; mi < 2; ++mi) {
        float4 bv = *(const float4*)(bias + (mtg * 2 + mi) * 16 + quad * 4);
        acc[mi][0] = bv.x; acc[mi][1] = bv.y; acc[mi][2] = bv.z; acc[mi][3] = bv.w;
    }
    int x = nt * 16 + nl;
#pragma unroll
    for (int ks = 0; ks < 18; ++ks) {
        const int pos = ks >> 1, half = ks & 1;
        const int r = pos / 3, kx = pos - r * 3;
        bf16x8 af0 = *(const bf16x8*)(w3t + ((mtg * 2 + 0) * 16 + nl) * 576 + ks * 32 + quad * 8);
        bf16x8 af1 = *(const bf16x8*)(w3t + ((mtg * 2 + 1) * 16 + nl) * 576 + ks * 32 + quad * 8);
        int ro = r * 8840 + 136 * kx + half * 64 + quad * 16;
        union { u64 d[2]; bf16x8 v; } bb;
        bb.d[0] = *(const u64*)(lb + ro + 272 * x);
        bb.d[1] = *(const u64*)(lb + ro + 272 * x + 8);
        acc[0] = __builtin_amdgcn_mfma_f32_16x16x32_bf16(af0, bb.v, acc[0], 0, 0, 0);
        acc[1] = __builtin_amdgcn_mfma_f32_16x16x32_bf16(af1, bb.v, acc[1], 0, 0, 0);
    }
    if (x < 30) {
#pragma unroll
        for (int mi = 0; mi < 2; ++mi) {
            int oc0 = (mtg * 2 + mi) * 16 + quad * 4;
#pragma unroll
            for (int r2 = 0; r2 < 4; ++r2)
                out[(size_t)b * 42240 + (oc0 + r2) * 660 + y * 30 + x] = f2bf(acc[mi][r2]);
        }
    }
}

// ---------------- fc1 v2: LDS-staged double-buffered bf16 MFMA GEMM.
__global__ __launch_bounds__(256) void k_fc1_mfma(const unsigned short* __restrict__ A,
                                                  const float* __restrict__ W,
                                                  float* __restrict__ part) {
    int kc = blockIdx.x;  // 0..59, 704 K each
    int nb = blockIdx.y;  // 0..3
    int tid = threadIdx.x;
    int wave = tid >> 6, lane = tid & 63;
    int m16 = lane & 15, quad = lane >> 4;
    __shared__ __align__(16) char lw[2][64 * 80];    // W: 64 rows x 32 bf16, stride 80
    __shared__ __align__(16) char la[2][128 * 80];   // A: 128 rows x 32 bf16, stride 80
    int k0 = kc * 704;
    int wrow = tid >> 2, wseg = tid & 3;   // 4 thr/row x 8 fp32
    const float* wsrc = W + (size_t)(nb * 64 + wrow) * 42240 + k0 + wseg * 8;
    int arow = tid >> 1, aseg = tid & 1;   // 2 thr/row x 16 bf16
    const uint4* asrc = (const uint4*)(A + (size_t)arow * 42240 + k0) + aseg * 2;
    float4 wr0 = ((const float4*)wsrc)[0];
    float4 wr1 = ((const float4*)wsrc)[1];
    uint4 ar0 = asrc[0];
    uint4 ar1 = asrc[1];
    f32x4 acc[8] = {};
    for (int ks = 0; ks < 22; ++ks) {
        int buf = ks & 1;
        uint4 wp;
        wp.x = pkbf2(wr0.x, wr0.y); wp.y = pkbf2(wr0.z, wr0.w);
        wp.z = pkbf2(wr1.x, wr1.y); wp.w = pkbf2(wr1.z, wr1.w);
        *(uint4*)(lw[buf] + wrow * 80 + wseg * 16) = wp;
        *(uint4*)(la[buf] + arow * 80 + aseg * 32) = ar0;
        *(uint4*)(la[buf] + arow * 80 + aseg * 32 + 16) = ar1;
        if (ks < 21) {
            wsrc += 32;
            asrc += 4;
            wr0 = ((const float4*)wsrc)[0];
            wr1 = ((const float4*)wsrc)[1];
            ar0 = asrc[0];
            ar1 = asrc[1];
        }
        __syncthreads();
        bf16x8 wf = *(const bf16x8*)(lw[buf] + (wave * 16 + m16) * 80 + quad * 16);
        const char* lab = la[buf] + m16 * 80 + quad * 16;
#pragma unroll
        for (int tm = 0; tm < 8; ++tm) {
            bf16x8 af = *(const bf16x8*)(lab + tm * 16 * 80);
            acc[tm] = __builtin_amdgcn_mfma_f32_16x16x32_bf16(af, wf, acc[tm], 0, 0, 0);
        }
    }
    int n = nb * 64 + wave * 16 + m16;
    float* pb = part + ((size_t)kc * 128) * 256 + n;
#pragma unroll
    for (int tm = 0; tm < 8; ++tm) {
        int row = tm * 16 + quad * 4;
#pragma unroll
        for (int r = 0; r < 4; ++r) pb[(size_t)(row + r) * 256] = acc[tm][r];
    }
}

// ---------------- fc1-combine + fc2 + lowd1 + lowd2 fused -> cnn_out2
// 256 thr: phase1 each thread owns one of 256 cols (60 loads batched in flight);
// phases 2-4: 2-way k-split across thread halves, LDS combine.
__global__ __launch_bounds__(256) void k_head(const float* __restrict__ part,
                                              const float* __restrict__ f1b,
                                              const float* __restrict__ w2, const float* __restrict__ b2,
                                              const float* __restrict__ lw1, const float* __restrict__ lb1,
                                              const float* __restrict__ lw2, const float* __restrict__ lb2,
                                              float* __restrict__ cnn2) {
    int b = blockIdx.x, t = threadIdx.x;
    __shared__ float xa[256];
    __shared__ float xb[128];
    __shared__ float xc[128];
    __shared__ float pp[256];
    float s = f1b[t];
#pragma unroll
    for (int kc = 0; kc < 60; ++kc) s += part[((size_t)kc * 128 + b) * 256 + t];
    xa[t] = fmaxf(s, 0.f);
    __syncthreads();
    int n = t & 127, half = t >> 7;
    float acc = half ? 0.f : b2[n];
    {
        const float* w2r = w2 + n * 256 + half * 128;
        const float* xar = xa + half * 128;
#pragma unroll
        for (int k = 0; k < 128; ++k) acc = fmaf(xar[k], w2r[k], acc);
    }
    pp[t] = acc;
    __syncthreads();
    if (t < 128) xb[t] = pp[t] + pp[t + 128];
    __syncthreads();
    acc = half ? 0.f : lb1[n];
    {
        const float* l1r = lw1 + n * 128 + half * 64;
        const float* xbr = xb + half * 64;
#pragma unroll
        for (int k = 0; k < 64; ++k) acc = fmaf(xbr[k], l1r[k], acc);
    }
    pp[t] = acc;
    __syncthreads();
    if (t < 128) xc[t] = fmaxf(pp[t] + pp[t + 128], 0.f);
    __syncthreads();
    acc = half ? 0.f : lb2[n];
    {
        const float* l2r = lw2 + n * 128 + half * 64;
        const float* xcr = xc + half * 64;
#pragma unroll
        for (int k = 0; k < 64; ++k) acc = fmaf(xcr[k], l2r[k], acc);
    }
    pp[t] = acc;
    __syncthreads();
    if (t < 128) cnn2[b * 128 + t] = pp[t] + pp[t + 128];
}

// ---------------- action MLP
__global__ __launch_bounds__(256) void k_act(const float* __restrict__ ain,
                                             const float* __restrict__ w1, const float* __restrict__ b1,
                                             const float* __restrict__ w2, const float* __restrict__ b2,
                                             float* __restrict__ abuf) {
    int idx = blockIdx.x * 256 + threadIdx.x;
    float x0 = ain[idx * 2], x1 = ain[idx * 2 + 1];
    float h1[16];
#pragma unroll
    for (int i = 0; i < 16; ++i)
        h1[i] = fmaxf(fmaf(x0, w1[i * 2], fmaf(x1, w1[i * 2 + 1], b1[i])), 0.f);
#pragma unroll
    for (int i = 0; i < 16; ++i) {
        float a = b2[i];
#pragma unroll
        for (int j = 0; j < 16; ++j) a = fmaf(h1[j], w2[i * 16 + j], a);
        abuf[idx * 16 + i] = a;
    }
}

// ---------------- LSTM v3: layer-pipelined, weights k-SPLIT across wave pairs.
__global__ __launch_bounds__(512, 2) void k_lstm(const float* __restrict__ abuf,
                                                 const float* __restrict__ cnn2,
                                                 const uint32_t* __restrict__ wpk,
                                                 const float* __restrict__ bih,
                                                 const float* __restrict__ bhh,
                                                 float* __restrict__ lout) {
    int b = blockIdx.x;
    int tid = threadIdx.x;
    int w = tid >> 6, lane = tid & 63;
    int sl = w >> 1, pt = w & 1;
    __shared__ uint32_t hbuf[2][3][32];   // [step parity][producer slot][pair]
    __shared__ uint32_t h3pk[8][32];      // layer-3 h pairs (phase 0 -> 1)
    __shared__ float4 pex[8][64];         // gate-partial exchange

    uint32_t xq[8];
#pragma unroll
    for (int t = 0; t < 8; ++t) {
        float x0 = 0.f, x1 = 0.f;
        if (lane < 8) {
            const float* ap = abuf + (b * 8 + t) * 16 + 2 * lane;
            x0 = ap[0];
            x1 = ap[1];
        }
        xq[t] = pkh2(x0, x1);
    }
    float h0 = cnn2[b * 128 + 64 + lane];
    float c0 = cnn2[b * 128 + lane];
    const u32x4* wbase = (const u32x4*)wpk;

#pragma unroll
    for (int P = 0; P < 2; ++P) {
        const int L = P * 4 + sl;
        u32x4 wreg[4][8];   // [gate][quad-of-pairs] -- 128 VGPRs, static-indexed
#pragma unroll
        for (int g = 0; g < 4; ++g)
#pragma unroll
            for (int q = 0; q < 8; ++q)
                wreg[g][q] = wbase[(size_t)L * 4096 + (g * 16 + pt * 8 + q) * 64 + lane];
        float bias0 = 0.f, bias1 = 0.f, bias2 = 0.f, bias3 = 0.f;
        if (pt == 0) {
            bias0 = bih[L * 256 + lane] + bhh[L * 256 + lane];
            bias1 = bih[L * 256 + 64 + lane] + bhh[L * 256 + 64 + lane];
            bias2 = bih[L * 256 + 128 + lane] + bhh[L * 256 + 128 + lane];
            bias3 = bih[L * 256 + 192 + lane] + bhh[L * 256 + 192 + lane];
        }
        float h = h0, c = c0;
        uint32_t hpk = packpair(h0);

        for (int s = 0; s < 11; ++s) {
            bool act = (s >= sl && s < sl + 8);
            float a0 = bias0, a1 = bias1, a2 = bias2, a3 = bias3;
            if (act) {
                if (pt == 0) {
                    uint32_t xcur;
                    if (sl == 0)
                        xcur = (P == 0) ? xq[0] : h3pk[s][lane & 31];
                    else
                        xcur = hbuf[(s & 1) ^ 1][sl - 1][lane & 31];
#pragma unroll
                    for (int m = 0; m < 32; ++m) {
                        uint32_t bx = (uint32_t)__builtin_amdgcn_readlane((int)xcur, m);
                        int q = m >> 2, e = m & 3;
                        a0 = dot2(comp4v(wreg[0][q], e), bx, a0);
                        a1 = dot2(comp4v(wreg[1][q], e), bx, a1);
                        a2 = dot2(comp4v(wreg[2][q], e), bx, a2);
                        a3 = dot2(comp4v(wreg[3][q], e), bx, a3);
                    }
                } else {
#pragma unroll
                    for (int m = 0; m < 32; ++m) {
                        uint32_t bh2 = (uint32_t)__builtin_amdgcn_readlane((int)hpk, 2 * m);
                        int q = m >> 2, e = m & 3;
                        a0 = dot2(comp4v(wreg[0][q], e), bh2, a0);
                        a1 = dot2(comp4v(wreg[1][q], e), bh2, a1);
                        a2 = dot2(comp4v(wreg[2][q], e), bh2, a2);
                        a3 = dot2(comp4v(wreg[3][q], e), bh2, a3);
                    }
                }
                float4 pv;
                pv.x = a0; pv.y = a1; pv.z = a2; pv.w = a3;
                pex[w][lane] = pv;
            }
            __syncthreads();
            if (act) {
                float4 po = pex[w ^ 1][lane];
                float g0 = a0 + po.x, g1 = a1 + po.y, g2 = a2 + po.z, g3 = a3 + po.w;
                float gi = sigm(g0), gf = sigm(g1), gv = tanh_(g2), go = sigm(g3);
                c = gf * c + gi * gv;
                h = go * tanh_(c);
                hpk = packpair(h);
                if (pt == 0) {
                    if (sl < 3) {
                        if (!(lane & 1)) hbuf[s & 1][sl][lane >> 1] = hpk;
                    } else if (P == 0) {
                        if (!(lane & 1)) h3pk[s - 3][lane >> 1] = hpk;
                    } else {
                        lout[((size_t)b * 8 + (s - 3)) * 64 + lane] = h;
                    }
                }
            }
            if (P == 0 && w == 0) {  // shift x queue (static indices only)
#pragma unroll
                for (int k = 0; k < 7; ++k) xq[k] = xq[k + 1];
            }
            __syncthreads();
        }
    }
}

// ---------------- out MLP + rotation -> d_out (128,8,4)
__global__ __launch_bounds__(256) void k_out(const float* __restrict__ lout,
                                             const float* __restrict__ w1, const float* __restrict__ b1,
                                             const float* __restrict__ w2, const float* __restrict__ b2,
                                             const float* __restrict__ gt, float* __restrict__ out) {
    int idx = blockIdx.x * 256 + threadIdx.x;
    int b = idx >> 3;
    float x[64];
#pragma unroll
    for (int j = 0; j < 64; ++j) x[j] = lout[idx * 64 + j];
    float h[32];
#pragma unroll 8
    for (int i = 0; i < 32; ++i) {
        float a = b1[i];
#pragma unroll
        for (int j = 0; j < 64; ++j) a = fmaf(x[j], w1[i * 64 + j], a);
        h[i] = fmaxf(a, 0.f);
    }
    float mo[4];
#pragma unroll
    for (int i = 0; i < 4; ++i) {
        float a = b2[i];
#pragma unroll
        for (int j = 0; j < 32; ++j) a = fmaf(h[j], w2[i * 32 + j], a);
        mo[i] = a;
    }
    float yaw = gt[b * 48 + 5];
    float cy = cosf(yaw), sy = sinf(yaw);
    out[idx * 4 + 0] = fmaf(mo[0], cy, fmaf(mo[1], sy, gt[b * 48 + 1]));
    out[idx * 4 + 1] = fmaf(mo[0], -sy, fmaf(mo[1], cy, gt[b * 48 + 2]));
    out[idx * 4 + 2] = mo[2] + gt[b * 48 + 3];
    out[idx * 4 + 3] = mo[3];
}

extern "C" void kernel_launch(void* const* d_in, const int* in_sizes, int n_in,
                              void* d_out, int out_size, void* d_ws, size_t ws_size,
                              hipStream_t stream) {
    const float* img = (const float*)d_in[0];
    const float* ain = (const float*)d_in[1];
    const float* gt = (const float*)d_in[2];
    const float* c1w = (const float*)d_in[3];
    const float* c1b = (const float*)d_in[4];
    const float* c2w = (const float*)d_in[5];
    const float* c2b = (const float*)d_in[6];
    const float* c3w = (const float*)d_in[7];
    const float* c3b = (const float*)d_in[8];
    const float* f1w = (const float*)d_in[9];
    const float* f1b = (const float*)d_in[10];
    const float* f2w = (const float*)d_in[11];
    const float* f2b = (const float*)d_in[12];
    const float* l1w = (const float*)d_in[13];
    const float* l1b = (const float*)d_in[14];
    const float* l2w = (const float*)d_in[15];
    const float* l2b = (const float*)d_in[16];
    const float* a1w = (const float*)d_in[17];
    const float* a1b = (const float*)d_in[18];
    const float* a2w = (const float*)d_in[19];
    const float* a2b = (const float*)d_in[20];
    const float* wih0 = (const float*)d_in[21];
    const float* wih = (const float*)d_in[22];
    const float* whh = (const float*)d_in[23];
    const float* bihp = (const float*)d_in[24];
    const float* bhhp = (const float*)d_in[25];
    const float* o1w = (const float*)d_in[26];
    const float* o1b = (const float*)d_in[27];
    const float* o2w = (const float*)d_in[28];
    const float* o2b = (const float*)d_in[29];
    float* out = (float*)d_out;

    char* ws = (char*)d_ws;
    unsigned short* c1o = (unsigned short*)(ws);                 // 97,026,048 B
    unsigned short* c2o = (unsigned short*)(ws + 97026048);      // 46,727,168 B
    unsigned short* c3o = (unsigned short*)(ws + 143753216);     // 10,813,440 B
    float* f1p = (float*)(ws + 154566656);                       // 60*128*256*4 = 7,864,320 B
    float* cnn2 = (float*)(ws + 163348480);
    float* abuf = (float*)(ws + 163414016);
    float* lo = (float*)(ws + 163479552);
    unsigned short* w1t = (unsigned short*)(ws + 163741696);     // 8,192 B
    unsigned short* w2t = (unsigned short*)(ws + 163749888);     // 36,864 B
    unsigned short* w3t = (unsigned short*)(ws + 163786752);     // 73,728 B
    uint32_t* wpk = (uint32_t*)(ws + 163860480);                 // 524,288 B

    k_wprep<<<232, 256, 0, stream>>>(c1w, c2w, c3w, w1t, w2t, w3t);
    k_wprep_lstm<<<128, 256, 0, stream>>>(wih0, wih, whh, wpk);
    k_conv1m<<<dim3(128, 24), 256, 0, stream>>>(img, w1t, c1b, c1o);
    k_conv2m<<<dim3(128, 46), 256, 0, stream>>>(c1o, w2t, c2b, c2o);
    k_conv3m<<<dim3(128, 22), 256, 0, stream>>>(c2o, w3t, c3b, c3o);
    k_fc1_mfma<<<dim3(60, 4), 256, 0, stream>>>(c3o, f1w, f1p);
    k_head<<<128, 256, 0, stream>>>(f1p, f1b, f2w, f2b, l1w, l1b, l2w, l2b, cnn2);
    k_act<<<4, 256, 0, stream>>>(ain, a1w, a1b, a2w, a2b, abuf);
    k_lstm<<<128, 512, 0, stream>>>(abuf, cnn2, wpk, bihp, bhhp, lo);
    k_out<<<4, 256, 0, stream>>>(lo, o1w, o1b, o2w, o2b, gt, out);
}

// Round 4
// 408.404 us; speedup vs baseline: 1.1279x; 1.0063x over previous
//
#include <hip/hip_runtime.h>
#include <cstdint>

#define DEV __device__ __forceinline__

typedef __attribute__((ext_vector_type(8))) short bf16x8;
typedef __attribute__((ext_vector_type(4))) float f32x4;
typedef __attribute__((ext_vector_type(2))) __fp16 h2t;
typedef __attribute__((ext_vector_type(4))) unsigned int u32x4;
typedef unsigned long long u64;

DEV unsigned short f2bf(float f) {
    unsigned u = __float_as_uint(f);
    unsigned r = u + 0x7fffu + ((u >> 16) & 1u);
    return (unsigned short)(r >> 16);
}
DEV uint32_t pkbf2(float a, float b) {
    return (uint32_t)f2bf(a) | ((uint32_t)f2bf(b) << 16);
}
DEV uint32_t pkh2(float a, float b) {
    h2t p = __builtin_amdgcn_cvt_pkrtz(a, b);
    union { h2t h; uint32_t u; } c;
    c.h = p;
    return c.u;
}
DEV float dot2(uint32_t w, uint32_t x, float acc) {
    union { uint32_t u; h2t h; } a, b;
    a.u = w; b.u = x;
    return __builtin_amdgcn_fdot2(a.h, b.h, acc, false);
}
DEV float sigm(float x) { return __builtin_amdgcn_rcpf(1.f + __expf(-x)); }
DEV float tanh_(float x) { return fmaf(2.f, sigm(2.f * x), -1.f); }
DEV uint32_t packpair(float h) {
    float hs = __int_as_float(__builtin_amdgcn_ds_swizzle(__float_as_int(h), 0x041F));
    return pkh2(h, hs);
}
DEV uint32_t comp4v(u32x4 v, int e) {
    return (e == 0) ? v[0] : (e == 1) ? v[1] : (e == 2) ? v[2] : v[3];
}
DEV u64 pack4bf(float a, float b, float c, float d) {
    unsigned lo = (unsigned)f2bf(a) | ((unsigned)f2bf(b) << 16);
    unsigned hi = (unsigned)f2bf(c) | ((unsigned)f2bf(d) << 16);
    return (u64)lo | ((u64)hi << 32);
}

// ---------------- weight prep (bf16, K-chunk order)
// conv1: w1t[oc][k] as before.
// w2t[64][288]: k = tap*32 + c'  where channel SLOT c' corresponds to conv1's
//   permuted output layout oc' = quad*8 + mi*4 + r2  (real oc = mi*16+quad*4+r2).
// w3t[64][576]: k = tap*64 + c (conv2 output unpermuted).
__global__ __launch_bounds__(256) void k_wprep(const float* __restrict__ w1,
                                               const float* __restrict__ w2,
                                               const float* __restrict__ w3,
                                               unsigned short* __restrict__ w1t,
                                               unsigned short* __restrict__ w2t,
                                               unsigned short* __restrict__ w3t) {
    int i = blockIdx.x * 256 + threadIdx.x;
    if (i < 32 * 128) {
        int oc = i >> 7, k = i & 127;
        int cc = k >> 3, u = (k >> 2) & 1, c = k & 3;
        int r = cc / 3, kx = 2 * (cc - 3 * r) + u;
        w1t[i] = (cc < 15 && kx < 5 && c < 3) ? f2bf(w1[oc * 75 + c * 25 + r * 5 + kx])
                                              : (unsigned short)0;
    } else if (i < 32 * 128 + 64 * 288) {
        int j = i - 32 * 128;
        int oc = j / 288, k = j - oc * 288;
        int pos = k >> 5, c = k & 31;
        int ocr = ((c >> 2) & 1) * 16 + (c >> 3) * 4 + (c & 3);  // inverse of conv1 store perm
        w2t[j] = f2bf(w2[oc * 288 + ocr * 9 + pos]);
    } else if (i < 32 * 128 + 64 * 288 + 64 * 576) {
        int j = i - 32 * 128 - 64 * 288;
        int oc = j / 576, k = j - oc * 576;
        int pos = k >> 6, c = k & 63;
        w3t[j] = f2bf(w3[oc * 576 + c * 9 + pos]);
    }
}

// ---------------- LSTM weight prep: f16 pairs (see k_lstm)
__global__ __launch_bounds__(256) void k_wprep_lstm(const float* __restrict__ Wih0,
                                                    const float* __restrict__ Wih,
                                                    const float* __restrict__ Whh,
                                                    uint32_t* __restrict__ wpk) {
    int idx = blockIdx.x * 256 + threadIdx.x;  // 0..32767
    int lane = idx & 63;
    int j = (idx >> 6) & 63;
    int l = idx >> 12;
    int g = j >> 4, q = j & 15;
    int r = g * 64 + lane;
    uint32_t ov[4];
#pragma unroll
    for (int e = 0; e < 4; ++e) {
        int p = q * 4 + e;
        float w0, w1;
        if (p < 32) {
            int k0 = 2 * p;
            if (l == 0) {
                w0 = (k0 < 16) ? Wih0[r * 16 + k0] : 0.f;
                w1 = (k0 + 1 < 16) ? Wih0[r * 16 + k0 + 1] : 0.f;
            } else {
                const float* base = Wih + ((size_t)(l - 1) * 256 + r) * 64;
                w0 = base[k0];
                w1 = base[k0 + 1];
            }
        } else {
            int k0 = 2 * (p - 32);
            const float* base = Whh + ((size_t)l * 256 + r) * 64;
            w0 = base[k0];
            w1 = base[k0 + 1];
        }
        ov[e] = pkh2(w0, w1);
    }
    uint4 v;
    v.x = ov[0]; v.y = ov[1]; v.z = ov[2]; v.w = ov[3];
    ((uint4*)wpk)[idx] = v;
}

// ---------------- conv1: 4 output rows/block, wave=row. Pinned batch staging,
// permuted-channel uint4 stores (wave covers contiguous 1KB per nt).
__global__ __launch_bounds__(256, 3) void k_conv1m(const float* __restrict__ img,
                                                   const unsigned short* __restrict__ w1t,
                                                   const float* __restrict__ bias,
                                                   unsigned short* __restrict__ out) {
    int b = blockIdx.x, y0 = blockIdx.y * 4;
    int tid = threadIdx.x;
    __shared__ __align__(16) unsigned short lds[12 * 1040];
    char* lb = (char*)lds;
    const float* ib = img + (size_t)b * 3 * 192 * 256;
    float t0[11], t1[11], t2[11];
#pragma unroll
    for (int r = 0; r < 11; ++r) {
        int row = 2 * y0 + r;
        if (row > 191) row = 191;
        const float* ip = ib + row * 256 + tid;
        t0[r] = ip[0];
        t1[r] = ip[192 * 256];
        t2[r] = ip[2 * 192 * 256];
    }
    __builtin_amdgcn_sched_barrier(0);   // keep all 33 loads in flight
#pragma unroll
    for (int r = 0; r < 11; ++r) {
        uint32_t lo = (uint32_t)f2bf(t0[r]) | ((uint32_t)f2bf(t1[r]) << 16);
        *(u64*)(lb + r * 2080 + tid * 8) = (u64)lo | ((u64)f2bf(t2[r]) << 32);
    }
    *(u64*)(lb + 11 * 2080 + tid * 8) = 0ull;
    __syncthreads();
    int wave = tid >> 6, lane = tid & 63;
    int quad = lane >> 4, nl = lane & 15;
    int ly = wave;
    float4 bv0 = *(const float4*)(bias + quad * 4);
    float4 bv1 = *(const float4*)(bias + 16 + quad * 4);
    f32x4 acc[8][2];
#pragma unroll
    for (int nt = 0; nt < 8; ++nt) {
        acc[nt][0][0] = bv0.x; acc[nt][0][1] = bv0.y; acc[nt][0][2] = bv0.z; acc[nt][0][3] = bv0.w;
        acc[nt][1][0] = bv1.x; acc[nt][1][1] = bv1.y; acc[nt][1][2] = bv1.z; acc[nt][1][3] = bv1.w;
    }
#pragma unroll
    for (int ks = 0; ks < 4; ++ks) {
        int cc = ks * 4 + quad;
        int r = cc / 3, kxp = cc - 3 * r;
        int rb = (2 * ly + r) * 2080 + kxp * 16 + nl * 16;
        bf16x8 af0 = *(const bf16x8*)(w1t + (nl) * 128 + ks * 32 + quad * 8);
        bf16x8 af1 = *(const bf16x8*)(w1t + (16 + nl) * 128 + ks * 32 + quad * 8);
#pragma unroll
        for (int nt = 0; nt < 8; ++nt) {
            bf16x8 bv = *(const bf16x8*)(lb + rb + nt * 256);
            acc[nt][0] = __builtin_amdgcn_mfma_f32_16x16x32_bf16(af0, bv, acc[nt][0], 0, 0, 0);
            acc[nt][1] = __builtin_amdgcn_mfma_f32_16x16x32_bf16(af1, bv, acc[nt][1], 0, 0, 0);
        }
    }
    int y = y0 + ly;
    if (y < 94) {
#pragma unroll
        for (int nt = 0; nt < 8; ++nt) {
            int x = nt * 16 + nl;
            if (x < 126) {
                f32x4 a0 = acc[nt][0], a1 = acc[nt][1];
                u64 lo = pack4bf(fmaxf(a0[0], 0.f), fmaxf(a0[1], 0.f),
                                 fmaxf(a0[2], 0.f), fmaxf(a0[3], 0.f));
                u64 hi = pack4bf(fmaxf(a1[0], 0.f), fmaxf(a1[1], 0.f),
                                 fmaxf(a1[2], 0.f), fmaxf(a1[3], 0.f));
                uint4 st;
                st.x = (uint32_t)lo; st.y = (uint32_t)(lo >> 32);
                st.z = (uint32_t)hi; st.w = (uint32_t)(hi >> 32);
                *(uint4*)(out + (((size_t)b * 94 + y) * 126 + x) * 32 + quad * 8) = st;
            }
        }
    }
}

// ---------------- conv2: NHWC(perm) in -> NHWC out [128][46][62][64]. 3x3 s2 ReLU.
__global__ __launch_bounds__(256, 4) void k_conv2m(const unsigned short* __restrict__ in,
                                                   const unsigned short* __restrict__ w2t,
                                                   const float* __restrict__ bias,
                                                   unsigned short* __restrict__ out) {
    int b = blockIdx.x, y = blockIdx.y;
    int tid = threadIdx.x;
    __shared__ __align__(16) unsigned short lds[3 * 130 * 36];
    char* lb = (char*)lds;
    const u64* in64 = (const u64*)in;
    size_t gbase = ((size_t)b * 94 + 2 * y) * 126 * 8;
    u64 tmp[12];
#pragma unroll
    for (int i = 0; i < 12; ++i) {
        int u = tid + i * 256;
        int uc = u < 3024 ? u : 3023;
        int r = uc / 1008, rem = uc - r * 1008;
        int p = rem >> 3, h = rem & 7;
        tmp[i] = in64[gbase + (size_t)r * 126 * 8 + p * 8 + h];
    }
    __builtin_amdgcn_sched_barrier(0);   // keep 12 loads in flight
#pragma unroll
    for (int i = 0; i < 12; ++i) {
        int u = tid + i * 256;
        if (u < 3024) {
            int r = u / 1008, rem = u - r * 1008;
            int p = rem >> 3, h = rem & 7;
            *(u64*)(lb + r * 9360 + p * 72 + h * 8) = tmp[i];
        }
    }
    __syncthreads();
    int wave = tid >> 6, lane = tid & 63;
    int quad = lane >> 4, nl = lane & 15;
    int mtg = wave & 1, ntg = wave >> 1;
    f32x4 acc[4];
#pragma unroll
    for (int mi = 0; mi < 2; ++mi) {
        float4 bv = *(const float4*)(bias + (mtg * 2 + mi) * 16 + quad * 4);
#pragma unroll
        for (int ni = 0; ni < 2; ++ni) {
            acc[mi * 2 + ni][0] = bv.x; acc[mi * 2 + ni][1] = bv.y;
            acc[mi * 2 + ni][2] = bv.z; acc[mi * 2 + ni][3] = bv.w;
        }
    }
#pragma unroll
    for (int ks = 0; ks < 9; ++ks) {
        const int r = ks / 3, kx = ks - r * 3;
        bf16x8 af0 = *(const bf16x8*)(w2t + ((mtg * 2 + 0) * 16 + nl) * 288 + ks * 32 + quad * 8);
        bf16x8 af1 = *(const bf16x8*)(w2t + ((mtg * 2 + 1) * 16 + nl) * 288 + ks * 32 + quad * 8);
        int ro = r * 9360 + 72 * kx + quad * 16;
#pragma unroll
        for (int ni = 0; ni < 2; ++ni) {
            int x = (ntg * 2 + ni) * 16 + nl;
            union { u64 d[2]; bf16x8 v; } bb;
            bb.d[0] = *(const u64*)(lb + ro + 144 * x);
            bb.d[1] = *(const u64*)(lb + ro + 144 * x + 8);
            acc[0 * 2 + ni] = __builtin_amdgcn_mfma_f32_16x16x32_bf16(af0, bb.v, acc[0 * 2 + ni], 0, 0, 0);
            acc[1 * 2 + ni] = __builtin_amdgcn_mfma_f32_16x16x32_bf16(af1, bb.v, acc[1 * 2 + ni], 0, 0, 0);
        }
    }
#pragma unroll
    for (int ni = 0; ni < 2; ++ni) {
        int x = (ntg * 2 + ni) * 16 + nl;
        if (x < 62) {
#pragma unroll
            for (int mi = 0; mi < 2; ++mi) {
                int oc0 = (mtg * 2 + mi) * 16 + quad * 4;
                f32x4 a = acc[mi * 2 + ni];
                u64 pk = pack4bf(fmaxf(a[0], 0.f), fmaxf(a[1], 0.f), fmaxf(a[2], 0.f), fmaxf(a[3], 0.f));
                *(u64*)(out + (((size_t)b * 46 + y) * 62 + x) * 64 + oc0) = pk;
            }
        }
    }
}

// ---------------- conv3: NHWC in -> NCHW-flatten bf16 [b][64*660]. Pinned staging.
__global__ __launch_bounds__(256, 4) void k_conv3m(const unsigned short* __restrict__ in,
                                                   const unsigned short* __restrict__ w3t,
                                                   const float* __restrict__ bias,
                                                   unsigned short* __restrict__ out) {
    int b = blockIdx.x, y = blockIdx.y;
    int tid = threadIdx.x;
    __shared__ __align__(16) unsigned short lds[3 * 65 * 68];
    char* lb = (char*)lds;
    const u64* in64 = (const u64*)in;
    size_t gbase = ((size_t)b * 46 + 2 * y) * 62 * 16;
    u64 tmp[12];
#pragma unroll
    for (int i = 0; i < 12; ++i) {
        int u = tid + i * 256;
        int uc = u < 2976 ? u : 2975;
        int r = uc / 992, rem = uc - r * 992;
        int p = rem >> 4, h = rem & 15;
        tmp[i] = in64[gbase + (size_t)r * 992 + p * 16 + h];
    }
    __builtin_amdgcn_sched_barrier(0);   // keep 12 loads in flight
#pragma unroll
    for (int i = 0; i < 12; ++i) {
        int u = tid + i * 256;
        if (u < 2976) {
            int r = u / 992, rem = u - r * 992;
            int p = rem >> 4, h = rem & 15;
            *(u64*)(lb + r * 8840 + p * 136 + h * 8) = tmp[i];
        }
    }
    __syncthreads();
    int wave = tid >> 6, lane = tid & 63;
    int quad = lane >> 4, nl = lane & 15;
    int mtg = wave & 1, nt = wave >> 1;
    f32x4 acc[2];
#pragma unroll
    for (int mi = 0; mi < 2; ++mi) {
        float4 bv = *(const float4*)(bias + (mtg * 2 + mi) * 16 + quad * 4);
        acc[mi][0] = bv.x; acc[mi][1] = bv.y; acc[mi][2] = bv.z; acc[mi][3] = bv.w;
    }
    int x = nt * 16 + nl;
#pragma unroll
    for (int ks = 0; ks < 18; ++ks) {
        const int pos = ks >> 1, half = ks & 1;
        const int r = pos / 3, kx = pos - r * 3;
        bf16x8 af0 = *(const bf16x8*)(w3t + ((mtg * 2 + 0) * 16 + nl) * 576 + ks * 32 + quad * 8);
        bf16x8 af1 = *(const bf16x8*)(w3t + ((mtg * 2 + 1) * 16 + nl) * 576 + ks * 32 + quad * 8);
        int ro = r * 8840 + 136 * kx + half * 64 + quad * 16;
        union { u64 d[2]; bf16x8 v; } bb;
        bb.d[0] = *(const u64*)(lb + ro + 272 * x);
        bb.d[1] = *(const u64*)(lb + ro + 272 * x + 8);
        acc[0] = __builtin_amdgcn_mfma_f32_16x16x32_bf16(af0, bb.v, acc[0], 0, 0, 0);
        acc[1] = __builtin_amdgcn_mfma_f32_16x16x32_bf16(af1, bb.v, acc[1], 0, 0, 0);
    }
    if (x < 30) {
#pragma unroll
        for (int mi = 0; mi < 2; ++mi) {
            int oc0 = (mtg * 2 + mi) * 16 + quad * 4;
#pragma unroll
            for (int r2 = 0; r2 < 4; ++r2)
                out[(size_t)b * 42240 + (oc0 + r2) * 660 + y * 30 + x] = f2bf(acc[mi][r2]);
        }
    }
}

// ---------------- fc1 v2: LDS-staged double-buffered bf16 MFMA GEMM.
__global__ __launch_bounds__(256) void k_fc1_mfma(const unsigned short* __restrict__ A,
                                                  const float* __restrict__ W,
                                                  float* __restrict__ part) {
    int kc = blockIdx.x;  // 0..59, 704 K each
    int nb = blockIdx.y;  // 0..3
    int tid = threadIdx.x;
    int wave = tid >> 6, lane = tid & 63;
    int m16 = lane & 15, quad = lane >> 4;
    __shared__ __align__(16) char lw[2][64 * 80];    // W: 64 rows x 32 bf16, stride 80
    __shared__ __align__(16) char la[2][128 * 80];   // A: 128 rows x 32 bf16, stride 80
    int k0 = kc * 704;
    int wrow = tid >> 2, wseg = tid & 3;   // 4 thr/row x 8 fp32
    const float* wsrc = W + (size_t)(nb * 64 + wrow) * 42240 + k0 + wseg * 8;
    int arow = tid >> 1, aseg = tid & 1;   // 2 thr/row x 16 bf16
    const uint4* asrc = (const uint4*)(A + (size_t)arow * 42240 + k0) + aseg * 2;
    float4 wr0 = ((const float4*)wsrc)[0];
    float4 wr1 = ((const float4*)wsrc)[1];
    uint4 ar0 = asrc[0];
    uint4 ar1 = asrc[1];
    f32x4 acc[8] = {};
    for (int ks = 0; ks < 22; ++ks) {
        int buf = ks & 1;
        uint4 wp;
        wp.x = pkbf2(wr0.x, wr0.y); wp.y = pkbf2(wr0.z, wr0.w);
        wp.z = pkbf2(wr1.x, wr1.y); wp.w = pkbf2(wr1.z, wr1.w);
        *(uint4*)(lw[buf] + wrow * 80 + wseg * 16) = wp;
        *(uint4*)(la[buf] + arow * 80 + aseg * 32) = ar0;
        *(uint4*)(la[buf] + arow * 80 + aseg * 32 + 16) = ar1;
        if (ks < 21) {
            wsrc += 32;
            asrc += 4;
            wr0 = ((const float4*)wsrc)[0];
            wr1 = ((const float4*)wsrc)[1];
            ar0 = asrc[0];
            ar1 = asrc[1];
        }
        __syncthreads();
        bf16x8 wf = *(const bf16x8*)(lw[buf] + (wave * 16 + m16) * 80 + quad * 16);
        const char* lab = la[buf] + m16 * 80 + quad * 16;
#pragma unroll
        for (int tm = 0; tm < 8; ++tm) {
            bf16x8 af = *(const bf16x8*)(lab + tm * 16 * 80);
            acc[tm] = __builtin_amdgcn_mfma_f32_16x16x32_bf16(af, wf, acc[tm], 0, 0, 0);
        }
    }
    int n = nb * 64 + wave * 16 + m16;
    float* pb = part + ((size_t)kc * 128) * 256 + n;
#pragma unroll
    for (int tm = 0; tm < 8; ++tm) {
        int row = tm * 16 + quad * 4;
#pragma unroll
        for (int r = 0; r < 4; ++r) pb[(size_t)(row + r) * 256] = acc[tm][r];
    }
}

// ---------------- fc1-combine + fc2 + lowd1 + lowd2 fused -> cnn_out2
__global__ __launch_bounds__(256) void k_head(const float* __restrict__ part,
                                              const float* __restrict__ f1b,
                                              const float* __restrict__ w2, const float* __restrict__ b2,
                                              const float* __restrict__ lw1, const float* __restrict__ lb1,
                                              const float* __restrict__ lw2, const float* __restrict__ lb2,
                                              float* __restrict__ cnn2) {
    int b = blockIdx.x, t = threadIdx.x;
    __shared__ float xa[256];
    __shared__ float xb[128];
    __shared__ float xc[128];
    __shared__ float pp[256];
    float s = f1b[t];
#pragma unroll
    for (int kc = 0; kc < 60; ++kc) s += part[((size_t)kc * 128 + b) * 256 + t];
    xa[t] = fmaxf(s, 0.f);
    __syncthreads();
    int n = t & 127, half = t >> 7;
    float acc = half ? 0.f : b2[n];
    {
        const float* w2r = w2 + n * 256 + half * 128;
        const float* xar = xa + half * 128;
#pragma unroll
        for (int k = 0; k < 128; ++k) acc = fmaf(xar[k], w2r[k], acc);
    }
    pp[t] = acc;
    __syncthreads();
    if (t < 128) xb[t] = pp[t] + pp[t + 128];
    __syncthreads();
    acc = half ? 0.f : lb1[n];
    {
        const float* l1r = lw1 + n * 128 + half * 64;
        const float* xbr = xb + half * 64;
#pragma unroll
        for (int k = 0; k < 64; ++k) acc = fmaf(xbr[k], l1r[k], acc);
    }
    pp[t] = acc;
    __syncthreads();
    if (t < 128) xc[t] = fmaxf(pp[t] + pp[t + 128], 0.f);
    __syncthreads();
    acc = half ? 0.f : lb2[n];
    {
        const float* l2r = lw2 + n * 128 + half * 64;
        const float* xcr = xc + half * 64;
#pragma unroll
        for (int k = 0; k < 64; ++k) acc = fmaf(xcr[k], l2r[k], acc);
    }
    pp[t] = acc;
    __syncthreads();
    if (t < 128) cnn2[b * 128 + t] = pp[t] + pp[t + 128];
}

// ---------------- action MLP
__global__ __launch_bounds__(256) void k_act(const float* __restrict__ ain,
                                             const float* __restrict__ w1, const float* __restrict__ b1,
                                             const float* __restrict__ w2, const float* __restrict__ b2,
                                             float* __restrict__ abuf) {
    int idx = blockIdx.x * 256 + threadIdx.x;
    float x0 = ain[idx * 2], x1 = ain[idx * 2 + 1];
    float h1[16];
#pragma unroll
    for (int i = 0; i < 16; ++i)
        h1[i] = fmaxf(fmaf(x0, w1[i * 2], fmaf(x1, w1[i * 2 + 1], b1[i])), 0.f);
#pragma unroll
    for (int i = 0; i < 16; ++i) {
        float a = b2[i];
#pragma unroll
        for (int j = 0; j < 16; ++j) a = fmaf(h1[j], w2[i * 16 + j], a);
        abuf[idx * 16 + i] = a;
    }
}

// ---------------- LSTM v3: layer-pipelined, weights k-SPLIT across wave pairs.
__global__ __launch_bounds__(512, 2) void k_lstm(const float* __restrict__ abuf,
                                                 const float* __restrict__ cnn2,
                                                 const uint32_t* __restrict__ wpk,
                                                 const float* __restrict__ bih,
                                                 const float* __restrict__ bhh,
                                                 float* __restrict__ lout) {
    int b = blockIdx.x;
    int tid = threadIdx.x;
    int w = tid >> 6, lane = tid & 63;
    int sl = w >> 1, pt = w & 1;
    __shared__ uint32_t hbuf[2][3][32];   // [step parity][producer slot][pair]
    __shared__ uint32_t h3pk[8][32];      // layer-3 h pairs (phase 0 -> 1)
    __shared__ float4 pex[8][64];         // gate-partial exchange

    uint32_t xq[8];
#pragma unroll
    for (int t = 0; t < 8; ++t) {
        float x0 = 0.f, x1 = 0.f;
        if (lane < 8) {
            const float* ap = abuf + (b * 8 + t) * 16 + 2 * lane;
            x0 = ap[0];
            x1 = ap[1];
        }
        xq[t] = pkh2(x0, x1);
    }
    float h0 = cnn2[b * 128 + 64 + lane];
    float c0 = cnn2[b * 128 + lane];
    const u32x4* wbase = (const u32x4*)wpk;

#pragma unroll
    for (int P = 0; P < 2; ++P) {
        const int L = P * 4 + sl;
        u32x4 wreg[4][8];   // [gate][quad-of-pairs] -- 128 VGPRs, static-indexed
#pragma unroll
        for (int g = 0; g < 4; ++g)
#pragma unroll
            for (int q = 0; q < 8; ++q)
                wreg[g][q] = wbase[(size_t)L * 4096 + (g * 16 + pt * 8 + q) * 64 + lane];
        float bias0 = 0.f, bias1 = 0.f, bias2 = 0.f, bias3 = 0.f;
        if (pt == 0) {
            bias0 = bih[L * 256 + lane] + bhh[L * 256 + lane];
            bias1 = bih[L * 256 + 64 + lane] + bhh[L * 256 + 64 + lane];
            bias2 = bih[L * 256 + 128 + lane] + bhh[L * 256 + 128 + lane];
            bias3 = bih[L * 256 + 192 + lane] + bhh[L * 256 + 192 + lane];
        }
        float h = h0, c = c0;
        uint32_t hpk = packpair(h0);

        for (int s = 0; s < 11; ++s) {
            bool act = (s >= sl && s < sl + 8);
            float a0 = bias0, a1 = bias1, a2 = bias2, a3 = bias3;
            if (act) {
                if (pt == 0) {
                    uint32_t xcur;
                    if (sl == 0)
                        xcur = (P == 0) ? xq[0] : h3pk[s][lane & 31];
                    else
                        xcur = hbuf[(s & 1) ^ 1][sl - 1][lane & 31];
#pragma unroll
                    for (int m = 0; m < 32; ++m) {
                        uint32_t bx = (uint32_t)__builtin_amdgcn_readlane((int)xcur, m);
                        int q = m >> 2, e = m & 3;
                        a0 = dot2(comp4v(wreg[0][q], e), bx, a0);
                        a1 = dot2(comp4v(wreg[1][q], e), bx, a1);
                        a2 = dot2(comp4v(wreg[2][q], e), bx, a2);
                        a3 = dot2(comp4v(wreg[3][q], e), bx, a3);
                    }
                } else {
#pragma unroll
                    for (int m = 0; m < 32; ++m) {
                        uint32_t bh2 = (uint32_t)__builtin_amdgcn_readlane((int)hpk, 2 * m);
                        int q = m >> 2, e = m & 3;
                        a0 = dot2(comp4v(wreg[0][q], e), bh2, a0);
                        a1 = dot2(comp4v(wreg[1][q], e), bh2, a1);
                        a2 = dot2(comp4v(wreg[2][q], e), bh2, a2);
                        a3 = dot2(comp4v(wreg[3][q], e), bh2, a3);
                    }
                }
                float4 pv;
                pv.x = a0; pv.y = a1; pv.z = a2; pv.w = a3;
                pex[w][lane] = pv;
            }
            __syncthreads();
            if (act) {
                float4 po = pex[w ^ 1][lane];
                float g0 = a0 + po.x, g1 = a1 + po.y, g2 = a2 + po.z, g3 = a3 + po.w;
                float gi = sigm(g0), gf = sigm(g1), gv = tanh_(g2), go = sigm(g3);
                c = gf * c + gi * gv;
                h = go * tanh_(c);
                hpk = packpair(h);
                if (pt == 0) {
                    if (sl < 3) {
                        if (!(lane & 1)) hbuf[s & 1][sl][lane >> 1] = hpk;
                    } else if (P == 0) {
                        if (!(lane & 1)) h3pk[s - 3][lane >> 1] = hpk;
                    } else {
                        lout[((size_t)b * 8 + (s - 3)) * 64 + lane] = h;
                    }
                }
            }
            if (P == 0 && w == 0) {  // shift x queue (static indices only)
#pragma unroll
                for (int k = 0; k < 7; ++k) xq[k] = xq[k + 1];
            }
            __syncthreads();
        }
    }
}

// ---------------- out MLP + rotation -> d_out (128,8,4)
__global__ __launch_bounds__(256) void k_out(const float* __restrict__ lout,
                                             const float* __restrict__ w1, const float* __restrict__ b1,
                                             const float* __restrict__ w2, const float* __restrict__ b2,
                                             const float* __restrict__ gt, float* __restrict__ out) {
    int idx = blockIdx.x * 256 + threadIdx.x;
    int b = idx >> 3;
    float x[64];
#pragma unroll
    for (int j = 0; j < 64; ++j) x[j] = lout[idx * 64 + j];
    float h[32];
#pragma unroll 8
    for (int i = 0; i < 32; ++i) {
        float a = b1[i];
#pragma unroll
        for (int j = 0; j < 64; ++j) a = fmaf(x[j], w1[i * 64 + j], a);
        h[i] = fmaxf(a, 0.f);
    }
    float mo[4];
#pragma unroll
    for (int i = 0; i < 4; ++i) {
        float a = b2[i];
#pragma unroll
        for (int j = 0; j < 32; ++j) a = fmaf(h[j], w2[i * 32 + j], a);
        mo[i] = a;
    }
    float yaw = gt[b * 48 + 5];
    float cy = cosf(yaw), sy = sinf(yaw);
    out[idx * 4 + 0] = fmaf(mo[0], cy, fmaf(mo[1], sy, gt[b * 48 + 1]));
    out[idx * 4 + 1] = fmaf(mo[0], -sy, fmaf(mo[1], cy, gt[b * 48 + 2]));
    out[idx * 4 + 2] = mo[2] + gt[b * 48 + 3];
    out[idx * 4 + 3] = mo[3];
}

extern "C" void kernel_launch(void* const* d_in, const int* in_sizes, int n_in,
                              void* d_out, int out_size, void* d_ws, size_t ws_size,
                              hipStream_t stream) {
    const float* img = (const float*)d_in[0];
    const float* ain = (const float*)d_in[1];
    const float* gt = (const float*)d_in[2];
    const float* c1w = (const float*)d_in[3];
    const float* c1b = (const float*)d_in[4];
    const float* c2w = (const float*)d_in[5];
    const float* c2b = (const float*)d_in[6];
    const float* c3w = (const float*)d_in[7];
    const float* c3b = (const float*)d_in[8];
    const float* f1w = (const float*)d_in[9];
    const float* f1b = (const float*)d_in[10];
    const float* f2w = (const float*)d_in[11];
    const float* f2b = (const float*)d_in[12];
    const float* l1w = (const float*)d_in[13];
    const float* l1b = (const float*)d_in[14];
    const float* l2w = (const float*)d_in[15];
    const float* l2b = (const float*)d_in[16];
    const float* a1w = (const float*)d_in[17];
    const float* a1b = (const float*)d_in[18];
    const float* a2w = (const float*)d_in[19];
    const float* a2b = (const float*)d_in[20];
    const float* wih0 = (const float*)d_in[21];
    const float* wih = (const float*)d_in[22];
    const float* whh = (const float*)d_in[23];
    const float* bihp = (const float*)d_in[24];
    const float* bhhp = (const float*)d_in[25];
    const float* o1w = (const float*)d_in[26];
    const float* o1b = (const float*)d_in[27];
    const float* o2w = (const float*)d_in[28];
    const float* o2b = (const float*)d_in[29];
    float* out = (float*)d_out;

    char* ws = (char*)d_ws;
    unsigned short* c1o = (unsigned short*)(ws);                 // 97,026,048 B
    unsigned short* c2o = (unsigned short*)(ws + 97026048);      // 46,727,168 B
    unsigned short* c3o = (unsigned short*)(ws + 143753216);     // 10,813,440 B
    float* f1p = (float*)(ws + 154566656);                       // 60*128*256*4 = 7,864,320 B
    float* cnn2 = (float*)(ws + 163348480);
    float* abuf = (float*)(ws + 163414016);
    float* lo = (float*)(ws + 163479552);
    unsigned short* w1t = (unsigned short*)(ws + 163741696);     // 8,192 B
    unsigned short* w2t = (unsigned short*)(ws + 163749888);     // 36,864 B
    unsigned short* w3t = (unsigned short*)(ws + 163786752);     // 73,728 B
    uint32_t* wpk = (uint32_t*)(ws + 163860480);                 // 524,288 B

    k_wprep<<<232, 256, 0, stream>>>(c1w, c2w, c3w, w1t, w2t, w3t);
    k_wprep_lstm<<<128, 256, 0, stream>>>(wih0, wih, whh, wpk);
    k_conv1m<<<dim3(128, 24), 256, 0, stream>>>(img, w1t, c1b, c1o);
    k_conv2m<<<dim3(128, 46), 256, 0, stream>>>(c1o, w2t, c2b, c2o);
    k_conv3m<<<dim3(128, 22), 256, 0, stream>>>(c2o, w3t, c3b, c3o);
    k_fc1_mfma<<<dim3(60, 4), 256, 0, stream>>>(c3o, f1w, f1p);
    k_head<<<128, 256, 0, stream>>>(f1p, f1b, f2w, f2b, l1w, l1b, l2w, l2b, cnn2);
    k_act<<<4, 256, 0, stream>>>(ain, a1w, a1b, a2w, a2b, abuf);
    k_lstm<<<128, 512, 0, stream>>>(abuf, cnn2, wpk, bihp, bhhp, lo);
    k_out<<<4, 256, 0, stream>>>(lo, o1w, o1b, o2w, o2b, gt, out);
}

// Round 5
// 357.313 us; speedup vs baseline: 1.2891x; 1.1430x over previous
//
#include <hip/hip_runtime.h>
#include <cstdint>

#define DEV __device__ __forceinline__

typedef __attribute__((ext_vector_type(8))) short bf16x8;
typedef __attribute__((ext_vector_type(4))) float f32x4;
typedef __attribute__((ext_vector_type(2))) __fp16 h2t;
typedef __attribute__((ext_vector_type(4))) unsigned int u32x4;
typedef unsigned long long u64;

DEV unsigned short f2bf(float f) {
    unsigned u = __float_as_uint(f);
    unsigned r = u + 0x7fffu + ((u >> 16) & 1u);
    return (unsigned short)(r >> 16);
}
DEV uint32_t pkbf2(float a, float b) {
    return (uint32_t)f2bf(a) | ((uint32_t)f2bf(b) << 16);
}
DEV uint32_t pkh2(float a, float b) {
    h2t p = __builtin_amdgcn_cvt_pkrtz(a, b);
    union { h2t h; uint32_t u; } c;
    c.h = p;
    return c.u;
}
DEV float dot2(uint32_t w, uint32_t x, float acc) {
    union { uint32_t u; h2t h; } a, b;
    a.u = w; b.u = x;
    return __builtin_amdgcn_fdot2(a.h, b.h, acc, false);
}
DEV float sigm(float x) { return __builtin_amdgcn_rcpf(1.f + __expf(-x)); }
DEV float tanh_(float x) { return fmaf(2.f, sigm(2.f * x), -1.f); }
DEV uint32_t packpair(float h) {
    float hs = __int_as_float(__builtin_amdgcn_ds_swizzle(__float_as_int(h), 0x041F));
    return pkh2(h, hs);
}
DEV uint32_t comp4v(u32x4 v, int e) {
    return (e == 0) ? v[0] : (e == 1) ? v[1] : (e == 2) ? v[2] : v[3];
}
DEV u64 pack4bf(float a, float b, float c, float d) {
    unsigned lo = (unsigned)f2bf(a) | ((unsigned)f2bf(b) << 16);
    unsigned hi = (unsigned)f2bf(c) | ((unsigned)f2bf(d) << 16);
    return (u64)lo | ((u64)hi << 32);
}

// ---------------- weight prep (bf16, K-chunk order)
// conv1: w1t[oc][k] as before.
// w2t[64][288]: k = tap*32 + c'  where channel SLOT c' corresponds to conv1's
//   permuted output layout oc' = quad*8 + mi*4 + r2  (real oc = mi*16+quad*4+r2).
// w3t[64][576]: k = tap*64 + c (conv2 output unpermuted).
__global__ __launch_bounds__(256) void k_wprep(const float* __restrict__ w1,
                                               const float* __restrict__ w2,
                                               const float* __restrict__ w3,
                                               unsigned short* __restrict__ w1t,
                                               unsigned short* __restrict__ w2t,
                                               unsigned short* __restrict__ w3t) {
    int i = blockIdx.x * 256 + threadIdx.x;
    if (i < 32 * 128) {
        int oc = i >> 7, k = i & 127;
        int cc = k >> 3, u = (k >> 2) & 1, c = k & 3;
        int r = cc / 3, kx = 2 * (cc - 3 * r) + u;
        w1t[i] = (cc < 15 && kx < 5 && c < 3) ? f2bf(w1[oc * 75 + c * 25 + r * 5 + kx])
                                              : (unsigned short)0;
    } else if (i < 32 * 128 + 64 * 288) {
        int j = i - 32 * 128;
        int oc = j / 288, k = j - oc * 288;
        int pos = k >> 5, c = k & 31;
        int ocr = ((c >> 2) & 1) * 16 + (c >> 3) * 4 + (c & 3);  // inverse of conv1 store perm
        w2t[j] = f2bf(w2[oc * 288 + ocr * 9 + pos]);
    } else if (i < 32 * 128 + 64 * 288 + 64 * 576) {
        int j = i - 32 * 128 - 64 * 288;
        int oc = j / 576, k = j - oc * 576;
        int pos = k >> 6, c = k & 63;
        w3t[j] = f2bf(w3[oc * 576 + c * 9 + pos]);
    }
}

// ---------------- LSTM weight prep: f16 pairs (see k_lstm)
__global__ __launch_bounds__(256) void k_wprep_lstm(const float* __restrict__ Wih0,
                                                    const float* __restrict__ Wih,
                                                    const float* __restrict__ Whh,
                                                    uint32_t* __restrict__ wpk) {
    int idx = blockIdx.x * 256 + threadIdx.x;  // 0..32767
    int lane = idx & 63;
    int j = (idx >> 6) & 63;
    int l = idx >> 12;
    int g = j >> 4, q = j & 15;
    int r = g * 64 + lane;
    uint32_t ov[4];
#pragma unroll
    for (int e = 0; e < 4; ++e) {
        int p = q * 4 + e;
        float w0, w1;
        if (p < 32) {
            int k0 = 2 * p;
            if (l == 0) {
                w0 = (k0 < 16) ? Wih0[r * 16 + k0] : 0.f;
                w1 = (k0 + 1 < 16) ? Wih0[r * 16 + k0 + 1] : 0.f;
            } else {
                const float* base = Wih + ((size_t)(l - 1) * 256 + r) * 64;
                w0 = base[k0];
                w1 = base[k0 + 1];
            }
        } else {
            int k0 = 2 * (p - 32);
            const float* base = Whh + ((size_t)l * 256 + r) * 64;
            w0 = base[k0];
            w1 = base[k0 + 1];
        }
        ov[e] = pkh2(w0, w1);
    }
    uint4 v;
    v.x = ov[0]; v.y = ov[1]; v.z = ov[2]; v.w = ov[3];
    ((uint4*)wpk)[idx] = v;
}

// ---------------- conv1: 4 output rows/block, wave=row. Pinned batch staging,
// permuted-channel uint4 stores (wave covers contiguous 1KB per nt).
__global__ __launch_bounds__(256, 3) void k_conv1m(const float* __restrict__ img,
                                                   const unsigned short* __restrict__ w1t,
                                                   const float* __restrict__ bias,
                                                   unsigned short* __restrict__ out) {
    int b = blockIdx.x, y0 = blockIdx.y * 4;
    int tid = threadIdx.x;
    __shared__ __align__(16) unsigned short lds[12 * 1040];
    char* lb = (char*)lds;
    const float* ib = img + (size_t)b * 3 * 192 * 256;
    float t0[11], t1[11], t2[11];
#pragma unroll
    for (int r = 0; r < 11; ++r) {
        int row = 2 * y0 + r;
        if (row > 191) row = 191;
        const float* ip = ib + row * 256 + tid;
        t0[r] = ip[0];
        t1[r] = ip[192 * 256];
        t2[r] = ip[2 * 192 * 256];
    }
    __builtin_amdgcn_sched_barrier(0);
#pragma unroll
    for (int r = 0; r < 11; ++r) {
        uint32_t lo = (uint32_t)f2bf(t0[r]) | ((uint32_t)f2bf(t1[r]) << 16);
        *(u64*)(lb + r * 2080 + tid * 8) = (u64)lo | ((u64)f2bf(t2[r]) << 32);
    }
    *(u64*)(lb + 11 * 2080 + tid * 8) = 0ull;
    __syncthreads();
    int wave = tid >> 6, lane = tid & 63;
    int quad = lane >> 4, nl = lane & 15;
    int ly = wave;
    float4 bv0 = *(const float4*)(bias + quad * 4);
    float4 bv1 = *(const float4*)(bias + 16 + quad * 4);
    f32x4 acc[8][2];
#pragma unroll
    for (int nt = 0; nt < 8; ++nt) {
        acc[nt][0][0] = bv0.x; acc[nt][0][1] = bv0.y; acc[nt][0][2] = bv0.z; acc[nt][0][3] = bv0.w;
        acc[nt][1][0] = bv1.x; acc[nt][1][1] = bv1.y; acc[nt][1][2] = bv1.z; acc[nt][1][3] = bv1.w;
    }
#pragma unroll
    for (int ks = 0; ks < 4; ++ks) {
        int cc = ks * 4 + quad;
        int r = cc / 3, kxp = cc - 3 * r;
        int rb = (2 * ly + r) * 2080 + kxp * 16 + nl * 16;
        bf16x8 af0 = *(const bf16x8*)(w1t + (nl) * 128 + ks * 32 + quad * 8);
        bf16x8 af1 = *(const bf16x8*)(w1t + (16 + nl) * 128 + ks * 32 + quad * 8);
#pragma unroll
        for (int nt = 0; nt < 8; ++nt) {
            bf16x8 bv = *(const bf16x8*)(lb + rb + nt * 256);
            acc[nt][0] = __builtin_amdgcn_mfma_f32_16x16x32_bf16(af0, bv, acc[nt][0], 0, 0, 0);
            acc[nt][1] = __builtin_amdgcn_mfma_f32_16x16x32_bf16(af1, bv, acc[nt][1], 0, 0, 0);
        }
    }
    int y = y0 + ly;
    if (y < 94) {
#pragma unroll
        for (int nt = 0; nt < 8; ++nt) {
            int x = nt * 16 + nl;
            if (x < 126) {
                f32x4 a0 = acc[nt][0], a1 = acc[nt][1];
                u64 lo = pack4bf(fmaxf(a0[0], 0.f), fmaxf(a0[1], 0.f),
                                 fmaxf(a0[2], 0.f), fmaxf(a0[3], 0.f));
                u64 hi = pack4bf(fmaxf(a1[0], 0.f), fmaxf(a1[1], 0.f),
                                 fmaxf(a1[2], 0.f), fmaxf(a1[3], 0.f));
                uint4 st;
                st.x = (uint32_t)lo; st.y = (uint32_t)(lo >> 32);
                st.z = (uint32_t)hi; st.w = (uint32_t)(hi >> 32);
                *(uint4*)(out + (((size_t)b * 94 + y) * 126 + x) * 32 + quad * 8) = st;
            }
        }
    }
}

// ---------------- conv2 v2: y-strip kernel. Grid (128 b, 2 xh, 2 yh), 4 waves.
// 4-slot LDS row ring (slot = row&3, 65-pos padded stride 72B), 2-row lookahead
// in registers. Per y: each wave 9ks x 2mi MFMA over its 16-x tile.
__global__ __launch_bounds__(256, 1) void k_conv2m(const unsigned short* __restrict__ in,
                                                   const unsigned short* __restrict__ w2t,
                                                   const float* __restrict__ bias,
                                                   unsigned short* __restrict__ out) {
    int b = blockIdx.x, xh = blockIdx.y, yh = blockIdx.z;
    int tid = threadIdx.x;
    int wave = tid >> 6, lane = tid & 63;
    int quad = lane >> 4, nl = lane & 15;
    int mtg = wave & 1, ntg = wave >> 1;
    __shared__ __align__(16) char lds[4 * 4680];   // 4 slots x 65 pos x 72B
    const u64* in64 = (const u64*)in;

    bf16x8 wfa[9], wfb[9];
#pragma unroll
    for (int ks = 0; ks < 9; ++ks) {
        wfa[ks] = *(const bf16x8*)(w2t + ((mtg * 2 + 0) * 16 + nl) * 288 + ks * 32 + quad * 8);
        wfb[ks] = *(const bf16x8*)(w2t + ((mtg * 2 + 1) * 16 + nl) * 288 + ks * 32 + quad * 8);
    }
    float4 bv0 = *(const float4*)(bias + (mtg * 2 + 0) * 16 + quad * 4);
    float4 bv1 = *(const float4*)(bias + (mtg * 2 + 1) * 16 + quad * 4);

    int y0 = yh * 23;
    int rr = tid >> 7, li = tid & 127;   // row-pair staging: 504 u64/row, 128 thr each

    // prologue: rows 2y0+rr and 2y0+2
    {
        int y2 = 2 * y0 + rr;
        const u64* s = in64 + ((size_t)(b * 94 + y2) * 126 + 62 * xh) * 8;
        int slot = y2 & 3;
        u64 g0[4];
#pragma unroll
        for (int j = 0; j < 4; ++j) { int idx = li + j * 128; g0[j] = (idx < 504) ? s[idx] : 0ull; }
#pragma unroll
        for (int j = 0; j < 4; ++j) {
            int idx = li + j * 128;
            if (idx < 504) *(u64*)(lds + slot * 4680 + (idx >> 3) * 72 + (idx & 7) * 8) = g0[j];
        }
        int y2b = 2 * y0 + 2;
        const u64* s2 = in64 + ((size_t)(b * 94 + y2b) * 126 + 62 * xh) * 8;
        int slot2 = y2b & 3;
        u64 g1[2];
#pragma unroll
        for (int j = 0; j < 2; ++j) { int idx = tid + j * 256; g1[j] = (idx < 504) ? s2[idx] : 0ull; }
#pragma unroll
        for (int j = 0; j < 2; ++j) {
            int idx = tid + j * 256;
            if (idx < 504) *(u64*)(lds + slot2 * 4680 + (idx >> 3) * 72 + (idx & 7) * 8) = g1[j];
        }
    }
    // lookahead loads: rows 2y0+3+rr
    u64 g[4];
    {
        int y2 = 2 * y0 + 3 + rr;
        const u64* s = in64 + ((size_t)(b * 94 + y2) * 126 + 62 * xh) * 8;
#pragma unroll
        for (int j = 0; j < 4; ++j) { int idx = li + j * 128; g[j] = (idx < 504) ? s[idx] : 0ull; }
    }
    __syncthreads();

    int xl = ntg * 16 + nl;
    for (int yy = 0; yy < 23; ++yy) {
        int y = y0 + yy;
        f32x4 acc0, acc1;
        acc0[0] = bv0.x; acc0[1] = bv0.y; acc0[2] = bv0.z; acc0[3] = bv0.w;
        acc1[0] = bv1.x; acc1[1] = bv1.y; acc1[2] = bv1.z; acc1[3] = bv1.w;
        int sb0 = ((2 * y) & 3) * 4680;
        int sb1 = ((2 * y + 1) & 3) * 4680;
        int sb2 = ((2 * y + 2) & 3) * 4680;
#pragma unroll
        for (int ks = 0; ks < 9; ++ks) {
            const int r = ks / 3, kx = ks - r * 3;
            int sb = (r == 0) ? sb0 : (r == 1) ? sb1 : sb2;
            union { u64 d[2]; bf16x8 v; } bb;
            const char* base = lds + sb + (2 * xl + kx) * 72 + quad * 16;
            bb.d[0] = *(const u64*)(base);
            bb.d[1] = *(const u64*)(base + 8);
            acc0 = __builtin_amdgcn_mfma_f32_16x16x32_bf16(wfa[ks], bb.v, acc0, 0, 0, 0);
            acc1 = __builtin_amdgcn_mfma_f32_16x16x32_bf16(wfb[ks], bb.v, acc1, 0, 0, 0);
        }
        if (xl < 31) {
            int xg = xh * 31 + xl;
            u64 p0 = pack4bf(fmaxf(acc0[0], 0.f), fmaxf(acc0[1], 0.f),
                             fmaxf(acc0[2], 0.f), fmaxf(acc0[3], 0.f));
            u64 p1 = pack4bf(fmaxf(acc1[0], 0.f), fmaxf(acc1[1], 0.f),
                             fmaxf(acc1[2], 0.f), fmaxf(acc1[3], 0.f));
            *(u64*)(out + (((size_t)b * 46 + y) * 62 + xg) * 64 + (mtg * 2 + 0) * 16 + quad * 4) = p0;
            *(u64*)(out + (((size_t)b * 46 + y) * 62 + xg) * 64 + (mtg * 2 + 1) * 16 + quad * 4) = p1;
        }
        __syncthreads();
        {
            int row = 2 * y + 3 + rr;
            int slot = row & 3;
#pragma unroll
            for (int j = 0; j < 4; ++j) {
                int idx = li + j * 128;
                if (idx < 504) *(u64*)(lds + slot * 4680 + (idx >> 3) * 72 + (idx & 7) * 8) = g[j];
            }
        }
        if (yy < 22) {
            int y2 = 2 * y + 5 + rr;
            if (y2 > 93) y2 = 93;
            const u64* s = in64 + ((size_t)(b * 94 + y2) * 126 + 62 * xh) * 8;
#pragma unroll
            for (int j = 0; j < 4; ++j) { int idx = li + j * 128; g[j] = (idx < 504) ? s[idx] : 0ull; }
        }
        __syncthreads();
    }
}

// ---------------- conv3 v2: y-strip kernel. Grid (128 b, 2 xh, 2 yh), 4 waves.
// 4-slot LDS row ring (33-pos padded stride 136B), 2-row register lookahead.
// Per y: each wave owns one 16-oc tile, 18 MFMA.
__global__ __launch_bounds__(256, 1) void k_conv3m(const unsigned short* __restrict__ in,
                                                   const unsigned short* __restrict__ w3t,
                                                   const float* __restrict__ bias,
                                                   unsigned short* __restrict__ out) {
    int b = blockIdx.x, xh = blockIdx.y, yh = blockIdx.z;
    int tid = threadIdx.x;
    int wave = tid >> 6, lane = tid & 63;
    int quad = lane >> 4, nl = lane & 15;
    __shared__ __align__(16) char lds[4 * 4488];   // 4 slots x 33 pos x 136B
    const u64* in64 = (const u64*)in;

    bf16x8 wf[18];
#pragma unroll
    for (int ks = 0; ks < 18; ++ks)
        wf[ks] = *(const bf16x8*)(w3t + (wave * 16 + nl) * 576 + ks * 32 + quad * 8);
    float4 bv = *(const float4*)(bias + wave * 16 + quad * 4);

    int y0 = yh * 11;
    int rr = tid >> 7, li = tid & 127;   // 496 u64/row, 128 thr each

    // prologue: rows 2y0+rr and 2y0+2
    {
        int y2 = 2 * y0 + rr;
        const u64* s = in64 + ((size_t)(b * 46 + y2) * 62 + 30 * xh) * 16;
        int slot = y2 & 3;
        u64 g0[4];
#pragma unroll
        for (int j = 0; j < 4; ++j) { int idx = li + j * 128; g0[j] = (idx < 496) ? s[idx] : 0ull; }
#pragma unroll
        for (int j = 0; j < 4; ++j) {
            int idx = li + j * 128;
            if (idx < 496) *(u64*)(lds + slot * 4488 + (idx >> 4) * 136 + (idx & 15) * 8) = g0[j];
        }
        int y2b = 2 * y0 + 2;
        const u64* s2 = in64 + ((size_t)(b * 46 + y2b) * 62 + 30 * xh) * 16;
        int slot2 = y2b & 3;
        u64 g1[2];
#pragma unroll
        for (int j = 0; j < 2; ++j) { int idx = tid + j * 256; g1[j] = (idx < 496) ? s2[idx] : 0ull; }
#pragma unroll
        for (int j = 0; j < 2; ++j) {
            int idx = tid + j * 256;
            if (idx < 496) *(u64*)(lds + slot2 * 4488 + (idx >> 4) * 136 + (idx & 15) * 8) = g1[j];
        }
    }
    u64 g[4];
    {
        int y2 = 2 * y0 + 3 + rr;
        const u64* s = in64 + ((size_t)(b * 46 + y2) * 62 + 30 * xh) * 16;
#pragma unroll
        for (int j = 0; j < 4; ++j) { int idx = li + j * 128; g[j] = (idx < 496) ? s[idx] : 0ull; }
    }
    __syncthreads();

    for (int yy = 0; yy < 11; ++yy) {
        int y = y0 + yy;
        f32x4 acc;
        acc[0] = bv.x; acc[1] = bv.y; acc[2] = bv.z; acc[3] = bv.w;
        int sb0 = ((2 * y) & 3) * 4488;
        int sb1 = ((2 * y + 1) & 3) * 4488;
        int sb2 = ((2 * y + 2) & 3) * 4488;
#pragma unroll
        for (int ks = 0; ks < 18; ++ks) {
            const int pos = ks >> 1, half = ks & 1;
            const int r = pos / 3, kx = pos - r * 3;
            int sb = (r == 0) ? sb0 : (r == 1) ? sb1 : sb2;
            union { u64 d[2]; bf16x8 v; } bb;
            const char* base = lds + sb + (2 * nl + kx) * 136 + half * 64 + quad * 16;
            bb.d[0] = *(const u64*)(base);
            bb.d[1] = *(const u64*)(base + 8);
            acc = __builtin_amdgcn_mfma_f32_16x16x32_bf16(wf[ks], bb.v, acc, 0, 0, 0);
        }
        if (nl < 15) {
            int xg = xh * 15 + nl;
#pragma unroll
            for (int r2 = 0; r2 < 4; ++r2)
                out[(size_t)b * 42240 + (wave * 16 + quad * 4 + r2) * 660 + y * 30 + xg] = f2bf(acc[r2]);
        }
        __syncthreads();
        {
            int row = 2 * y + 3 + rr;
            int slot = row & 3;
#pragma unroll
            for (int j = 0; j < 4; ++j) {
                int idx = li + j * 128;
                if (idx < 496) *(u64*)(lds + slot * 4488 + (idx >> 4) * 136 + (idx & 15) * 8) = g[j];
            }
        }
        if (yy < 10) {
            int y2 = 2 * y + 5 + rr;
            if (y2 > 45) y2 = 45;
            const u64* s = in64 + ((size_t)(b * 46 + y2) * 62 + 30 * xh) * 16;
#pragma unroll
            for (int j = 0; j < 4; ++j) { int idx = li + j * 128; g[j] = (idx < 496) ? s[idx] : 0ull; }
        }
        __syncthreads();
    }
}

// ---------------- fc1 v2: LDS-staged double-buffered bf16 MFMA GEMM.
__global__ __launch_bounds__(256) void k_fc1_mfma(const unsigned short* __restrict__ A,
                                                  const float* __restrict__ W,
                                                  float* __restrict__ part) {
    int kc = blockIdx.x;  // 0..59, 704 K each
    int nb = blockIdx.y;  // 0..3
    int tid = threadIdx.x;
    int wave = tid >> 6, lane = tid & 63;
    int m16 = lane & 15, quad = lane >> 4;
    __shared__ __align__(16) char lw[2][64 * 80];    // W: 64 rows x 32 bf16, stride 80
    __shared__ __align__(16) char la[2][128 * 80];   // A: 128 rows x 32 bf16, stride 80
    int k0 = kc * 704;
    int wrow = tid >> 2, wseg = tid & 3;   // 4 thr/row x 8 fp32
    const float* wsrc = W + (size_t)(nb * 64 + wrow) * 42240 + k0 + wseg * 8;
    int arow = tid >> 1, aseg = tid & 1;   // 2 thr/row x 16 bf16
    const uint4* asrc = (const uint4*)(A + (size_t)arow * 42240 + k0) + aseg * 2;
    float4 wr0 = ((const float4*)wsrc)[0];
    float4 wr1 = ((const float4*)wsrc)[1];
    uint4 ar0 = asrc[0];
    uint4 ar1 = asrc[1];
    f32x4 acc[8] = {};
    for (int ks = 0; ks < 22; ++ks) {
        int buf = ks & 1;
        uint4 wp;
        wp.x = pkbf2(wr0.x, wr0.y); wp.y = pkbf2(wr0.z, wr0.w);
        wp.z = pkbf2(wr1.x, wr1.y); wp.w = pkbf2(wr1.z, wr1.w);
        *(uint4*)(lw[buf] + wrow * 80 + wseg * 16) = wp;
        *(uint4*)(la[buf] + arow * 80 + aseg * 32) = ar0;
        *(uint4*)(la[buf] + arow * 80 + aseg * 32 + 16) = ar1;
        if (ks < 21) {
            wsrc += 32;
            asrc += 4;
            wr0 = ((const float4*)wsrc)[0];
            wr1 = ((const float4*)wsrc)[1];
            ar0 = asrc[0];
            ar1 = asrc[1];
        }
        __syncthreads();
        bf16x8 wf = *(const bf16x8*)(lw[buf] + (wave * 16 + m16) * 80 + quad * 16);
        const char* lab = la[buf] + m16 * 80 + quad * 16;
#pragma unroll
        for (int tm = 0; tm < 8; ++tm) {
            bf16x8 af = *(const bf16x8*)(lab + tm * 16 * 80);
            acc[tm] = __builtin_amdgcn_mfma_f32_16x16x32_bf16(af, wf, acc[tm], 0, 0, 0);
        }
    }
    int n = nb * 64 + wave * 16 + m16;
    float* pb = part + ((size_t)kc * 128) * 256 + n;
#pragma unroll
    for (int tm = 0; tm < 8; ++tm) {
        int row = tm * 16 + quad * 4;
#pragma unroll
        for (int r = 0; r < 4; ++r) pb[(size_t)(row + r) * 256] = acc[tm][r];
    }
}

// ---------------- fc1-combine + fc2 + lowd1 + lowd2 fused -> cnn_out2
__global__ __launch_bounds__(256) void k_head(const float* __restrict__ part,
                                              const float* __restrict__ f1b,
                                              const float* __restrict__ w2, const float* __restrict__ b2,
                                              const float* __restrict__ lw1, const float* __restrict__ lb1,
                                              const float* __restrict__ lw2, const float* __restrict__ lb2,
                                              float* __restrict__ cnn2) {
    int b = blockIdx.x, t = threadIdx.x;
    __shared__ float xa[256];
    __shared__ float xb[128];
    __shared__ float xc[128];
    __shared__ float pp[256];
    float s = f1b[t];
#pragma unroll
    for (int kc = 0; kc < 60; ++kc) s += part[((size_t)kc * 128 + b) * 256 + t];
    xa[t] = fmaxf(s, 0.f);
    __syncthreads();
    int n = t & 127, half = t >> 7;
    float acc = half ? 0.f : b2[n];
    {
        const float* w2r = w2 + n * 256 + half * 128;
        const float* xar = xa + half * 128;
#pragma unroll
        for (int k = 0; k < 128; ++k) acc = fmaf(xar[k], w2r[k], acc);
    }
    pp[t] = acc;
    __syncthreads();
    if (t < 128) xb[t] = pp[t] + pp[t + 128];
    __syncthreads();
    acc = half ? 0.f : lb1[n];
    {
        const float* l1r = lw1 + n * 128 + half * 64;
        const float* xbr = xb + half * 64;
#pragma unroll
        for (int k = 0; k < 64; ++k) acc = fmaf(xbr[k], l1r[k], acc);
    }
    pp[t] = acc;
    __syncthreads();
    if (t < 128) xc[t] = fmaxf(pp[t] + pp[t + 128], 0.f);
    __syncthreads();
    acc = half ? 0.f : lb2[n];
    {
        const float* l2r = lw2 + n * 128 + half * 64;
        const float* xcr = xc + half * 64;
#pragma unroll
        for (int k = 0; k < 64; ++k) acc = fmaf(xcr[k], l2r[k], acc);
    }
    pp[t] = acc;
    __syncthreads();
    if (t < 128) cnn2[b * 128 + t] = pp[t] + pp[t + 128];
}

// ---------------- action MLP
__global__ __launch_bounds__(256) void k_act(const float* __restrict__ ain,
                                             const float* __restrict__ w1, const float* __restrict__ b1,
                                             const float* __restrict__ w2, const float* __restrict__ b2,
                                             float* __restrict__ abuf) {
    int idx = blockIdx.x * 256 + threadIdx.x;
    float x0 = ain[idx * 2], x1 = ain[idx * 2 + 1];
    float h1[16];
#pragma unroll
    for (int i = 0; i < 16; ++i)
        h1[i] = fmaxf(fmaf(x0, w1[i * 2], fmaf(x1, w1[i * 2 + 1], b1[i])), 0.f);
#pragma unroll
    for (int i = 0; i < 16; ++i) {
        float a = b2[i];
#pragma unroll
        for (int j = 0; j < 16; ++j) a = fmaf(h1[j], w2[i * 16 + j], a);
        abuf[idx * 16 + i] = a;
    }
}

// ---------------- LSTM v3: layer-pipelined, weights k-SPLIT across wave pairs.
__global__ __launch_bounds__(512, 2) void k_lstm(const float* __restrict__ abuf,
                                                 const float* __restrict__ cnn2,
                                                 const uint32_t* __restrict__ wpk,
                                                 const float* __restrict__ bih,
                                                 const float* __restrict__ bhh,
                                                 float* __restrict__ lout) {
    int b = blockIdx.x;
    int tid = threadIdx.x;
    int w = tid >> 6, lane = tid & 63;
    int sl = w >> 1, pt = w & 1;
    __shared__ uint32_t hbuf[2][3][32];   // [step parity][producer slot][pair]
    __shared__ uint32_t h3pk[8][32];      // layer-3 h pairs (phase 0 -> 1)
    __shared__ float4 pex[8][64];         // gate-partial exchange

    uint32_t xq[8];
#pragma unroll
    for (int t = 0; t < 8; ++t) {
        float x0 = 0.f, x1 = 0.f;
        if (lane < 8) {
            const float* ap = abuf + (b * 8 + t) * 16 + 2 * lane;
            x0 = ap[0];
            x1 = ap[1];
        }
        xq[t] = pkh2(x0, x1);
    }
    float h0 = cnn2[b * 128 + 64 + lane];
    float c0 = cnn2[b * 128 + lane];
    const u32x4* wbase = (const u32x4*)wpk;

#pragma unroll
    for (int P = 0; P < 2; ++P) {
        const int L = P * 4 + sl;
        u32x4 wreg[4][8];   // [gate][quad-of-pairs] -- 128 VGPRs, static-indexed
#pragma unroll
        for (int g = 0; g < 4; ++g)
#pragma unroll
            for (int q = 0; q < 8; ++q)
                wreg[g][q] = wbase[(size_t)L * 4096 + (g * 16 + pt * 8 + q) * 64 + lane];
        float bias0 = 0.f, bias1 = 0.f, bias2 = 0.f, bias3 = 0.f;
        if (pt == 0) {
            bias0 = bih[L * 256 + lane] + bhh[L * 256 + lane];
            bias1 = bih[L * 256 + 64 + lane] + bhh[L * 256 + 64 + lane];
            bias2 = bih[L * 256 + 128 + lane] + bhh[L * 256 + 128 + lane];
            bias3 = bih[L * 256 + 192 + lane] + bhh[L * 256 + 192 + lane];
        }
        float h = h0, c = c0;
        uint32_t hpk = packpair(h0);

        for (int s = 0; s < 11; ++s) {
            bool act = (s >= sl && s < sl + 8);
            float a0 = bias0, a1 = bias1, a2 = bias2, a3 = bias3;
            if (act) {
                if (pt == 0) {
                    uint32_t xcur;
                    if (sl == 0)
                        xcur = (P == 0) ? xq[0] : h3pk[s][lane & 31];
                    else
                        xcur = hbuf[(s & 1) ^ 1][sl - 1][lane & 31];
#pragma unroll
                    for (int m = 0; m < 32; ++m) {
                        uint32_t bx = (uint32_t)__builtin_amdgcn_readlane((int)xcur, m);
                        int q = m >> 2, e = m & 3;
                        a0 = dot2(comp4v(wreg[0][q], e), bx, a0);
                        a1 = dot2(comp4v(wreg[1][q], e), bx, a1);
                        a2 = dot2(comp4v(wreg[2][q], e), bx, a2);
                        a3 = dot2(comp4v(wreg[3][q], e), bx, a3);
                    }
                } else {
#pragma unroll
                    for (int m = 0; m < 32; ++m) {
                        uint32_t bh2 = (uint32_t)__builtin_amdgcn_readlane((int)hpk, 2 * m);
                        int q = m >> 2, e = m & 3;
                        a0 = dot2(comp4v(wreg[0][q], e), bh2, a0);
                        a1 = dot2(comp4v(wreg[1][q], e), bh2, a1);
                        a2 = dot2(comp4v(wreg[2][q], e), bh2, a2);
                        a3 = dot2(comp4v(wreg[3][q], e), bh2, a3);
                    }
                }
                float4 pv;
                pv.x = a0; pv.y = a1; pv.z = a2; pv.w = a3;
                pex[w][lane] = pv;
            }
            __syncthreads();
            if (act) {
                float4 po = pex[w ^ 1][lane];
                float g0 = a0 + po.x, g1 = a1 + po.y, g2 = a2 + po.z, g3 = a3 + po.w;
                float gi = sigm(g0), gf = sigm(g1), gv = tanh_(g2), go = sigm(g3);
                c = gf * c + gi * gv;
                h = go * tanh_(c);
                hpk = packpair(h);
                if (pt == 0) {
                    if (sl < 3) {
                        if (!(lane & 1)) hbuf[s & 1][sl][lane >> 1] = hpk;
                    } else if (P == 0) {
                        if (!(lane & 1)) h3pk[s - 3][lane >> 1] = hpk;
                    } else {
                        lout[((size_t)b * 8 + (s - 3)) * 64 + lane] = h;
                    }
                }
            }
            if (P == 0 && w == 0) {  // shift x queue (static indices only)
#pragma unroll
                for (int k = 0; k < 7; ++k) xq[k] = xq[k + 1];
            }
            __syncthreads();
        }
    }
}

// ---------------- out MLP + rotation -> d_out (128,8,4)
__global__ __launch_bounds__(256) void k_out(const float* __restrict__ lout,
                                             const float* __restrict__ w1, const float* __restrict__ b1,
                                             const float* __restrict__ w2, const float* __restrict__ b2,
                                             const float* __restrict__ gt, float* __restrict__ out) {
    int idx = blockIdx.x * 256 + threadIdx.x;
    int b = idx >> 3;
    float x[64];
#pragma unroll
    for (int j = 0; j < 64; ++j) x[j] = lout[idx * 64 + j];
    float h[32];
#pragma unroll 8
    for (int i = 0; i < 32; ++i) {
        float a = b1[i];
#pragma unroll
        for (int j = 0; j < 64; ++j) a = fmaf(x[j], w1[i * 64 + j], a);
        h[i] = fmaxf(a, 0.f);
    }
    float mo[4];
#pragma unroll
    for (int i = 0; i < 4; ++i) {
        float a = b2[i];
#pragma unroll
        for (int j = 0; j < 32; ++j) a = fmaf(h[j], w2[i * 32 + j], a);
        mo[i] = a;
    }
    float yaw = gt[b * 48 + 5];
    float cy = cosf(yaw), sy = sinf(yaw);
    out[idx * 4 + 0] = fmaf(mo[0], cy, fmaf(mo[1], sy, gt[b * 48 + 1]));
    out[idx * 4 + 1] = fmaf(mo[0], -sy, fmaf(mo[1], cy, gt[b * 48 + 2]));
    out[idx * 4 + 2] = mo[2] + gt[b * 48 + 3];
    out[idx * 4 + 3] = mo[3];
}

extern "C" void kernel_launch(void* const* d_in, const int* in_sizes, int n_in,
                              void* d_out, int out_size, void* d_ws, size_t ws_size,
                              hipStream_t stream) {
    const float* img = (const float*)d_in[0];
    const float* ain = (const float*)d_in[1];
    const float* gt = (const float*)d_in[2];
    const float* c1w = (const float*)d_in[3];
    const float* c1b = (const float*)d_in[4];
    const float* c2w = (const float*)d_in[5];
    const float* c2b = (const float*)d_in[6];
    const float* c3w = (const float*)d_in[7];
    const float* c3b = (const float*)d_in[8];
    const float* f1w = (const float*)d_in[9];
    const float* f1b = (const float*)d_in[10];
    const float* f2w = (const float*)d_in[11];
    const float* f2b = (const float*)d_in[12];
    const float* l1w = (const float*)d_in[13];
    const float* l1b = (const float*)d_in[14];
    const float* l2w = (const float*)d_in[15];
    const float* l2b = (const float*)d_in[16];
    const float* a1w = (const float*)d_in[17];
    const float* a1b = (const float*)d_in[18];
    const float* a2w = (const float*)d_in[19];
    const float* a2b = (const float*)d_in[20];
    const float* wih0 = (const float*)d_in[21];
    const float* wih = (const float*)d_in[22];
    const float* whh = (const float*)d_in[23];
    const float* bihp = (const float*)d_in[24];
    const float* bhhp = (const float*)d_in[25];
    const float* o1w = (const float*)d_in[26];
    const float* o1b = (const float*)d_in[27];
    const float* o2w = (const float*)d_in[28];
    const float* o2b = (const float*)d_in[29];
    float* out = (float*)d_out;

    char* ws = (char*)d_ws;
    unsigned short* c1o = (unsigned short*)(ws);                 // 97,026,048 B
    unsigned short* c2o = (unsigned short*)(ws + 97026048);      // 46,727,168 B
    unsigned short* c3o = (unsigned short*)(ws + 143753216);     // 10,813,440 B
    float* f1p = (float*)(ws + 154566656);                       // 60*128*256*4 = 7,864,320 B
    float* cnn2 = (float*)(ws + 163348480);
    float* abuf = (float*)(ws + 163414016);
    float* lo = (float*)(ws + 163479552);
    unsigned short* w1t = (unsigned short*)(ws + 163741696);     // 8,192 B
    unsigned short* w2t = (unsigned short*)(ws + 163749888);     // 36,864 B
    unsigned short* w3t = (unsigned short*)(ws + 163786752);     // 73,728 B
    uint32_t* wpk = (uint32_t*)(ws + 163860480);                 // 524,288 B

    k_wprep<<<232, 256, 0, stream>>>(c1w, c2w, c3w, w1t, w2t, w3t);
    k_wprep_lstm<<<128, 256, 0, stream>>>(wih0, wih, whh, wpk);
    k_conv1m<<<dim3(128, 24), 256, 0, stream>>>(img, w1t, c1b, c1o);
    k_conv2m<<<dim3(128, 2, 2), 256, 0, stream>>>(c1o, w2t, c2b, c2o);
    k_conv3m<<<dim3(128, 2, 2), 256, 0, stream>>>(c2o, w3t, c3b, c3o);
    k_fc1_mfma<<<dim3(60, 4), 256, 0, stream>>>(c3o, f1w, f1p);
    k_head<<<128, 256, 0, stream>>>(f1p, f1b, f2w, f2b, l1w, l1b, l2w, l2b, cnn2);
    k_act<<<4, 256, 0, stream>>>(ain, a1w, a1b, a2w, a2b, abuf);
    k_lstm<<<128, 512, 0, stream>>>(abuf, cnn2, wpk, bihp, bhhp, lo);
    k_out<<<4, 256, 0, stream>>>(lo, o1w, o1b, o2w, o2b, gt, out);
}

// Round 6
// 347.998 us; speedup vs baseline: 1.3236x; 1.0268x over previous
//
#include <hip/hip_runtime.h>
#include <cstdint>

#define DEV __device__ __forceinline__

typedef __attribute__((ext_vector_type(8))) short bf16x8;
typedef __attribute__((ext_vector_type(4))) float f32x4;
typedef __attribute__((ext_vector_type(2))) __fp16 h2t;
typedef __attribute__((ext_vector_type(4))) unsigned int u32x4;
typedef unsigned long long u64;

DEV unsigned short f2bf(float f) {
    unsigned u = __float_as_uint(f);
    unsigned r = u + 0x7fffu + ((u >> 16) & 1u);
    return (unsigned short)(r >> 16);
}
DEV uint32_t pkbf2(float a, float b) {
    return (uint32_t)f2bf(a) | ((uint32_t)f2bf(b) << 16);
}
DEV uint32_t pkh2(float a, float b) {
    h2t p = __builtin_amdgcn_cvt_pkrtz(a, b);
    union { h2t h; uint32_t u; } c;
    c.h = p;
    return c.u;
}
DEV float dot2(uint32_t w, uint32_t x, float acc) {
    union { uint32_t u; h2t h; } a, b;
    a.u = w; b.u = x;
    return __builtin_amdgcn_fdot2(a.h, b.h, acc, false);
}
DEV float sigm(float x) { return __builtin_amdgcn_rcpf(1.f + __expf(-x)); }
DEV float tanh_(float x) { return fmaf(2.f, sigm(2.f * x), -1.f); }
DEV uint32_t packpair(float h) {
    float hs = __int_as_float(__builtin_amdgcn_ds_swizzle(__float_as_int(h), 0x041F));
    return pkh2(h, hs);
}
DEV uint32_t comp4v(u32x4 v, int e) {
    return (e == 0) ? v[0] : (e == 1) ? v[1] : (e == 2) ? v[2] : v[3];
}
DEV u64 pack4bf(float a, float b, float c, float d) {
    unsigned lo = (unsigned)f2bf(a) | ((unsigned)f2bf(b) << 16);
    unsigned hi = (unsigned)f2bf(c) | ((unsigned)f2bf(d) << 16);
    return (u64)lo | ((u64)hi << 32);
}

// ---------------- weight prep (bf16, K-chunk order)
// conv1: w1t[oc][k] as before.
// w2t[64][288]: k = tap*32 + c'  where channel SLOT c' corresponds to conv1's
//   permuted output layout oc' = quad*8 + mi*4 + r2  (real oc = mi*16+quad*4+r2).
// w3t[64][576]: k = tap*64 + c (conv2 output unpermuted).
__global__ __launch_bounds__(256) void k_wprep(const float* __restrict__ w1,
                                               const float* __restrict__ w2,
                                               const float* __restrict__ w3,
                                               unsigned short* __restrict__ w1t,
                                               unsigned short* __restrict__ w2t,
                                               unsigned short* __restrict__ w3t) {
    int i = blockIdx.x * 256 + threadIdx.x;
    if (i < 32 * 128) {
        int oc = i >> 7, k = i & 127;
        int cc = k >> 3, u = (k >> 2) & 1, c = k & 3;
        int r = cc / 3, kx = 2 * (cc - 3 * r) + u;
        w1t[i] = (cc < 15 && kx < 5 && c < 3) ? f2bf(w1[oc * 75 + c * 25 + r * 5 + kx])
                                              : (unsigned short)0;
    } else if (i < 32 * 128 + 64 * 288) {
        int j = i - 32 * 128;
        int oc = j / 288, k = j - oc * 288;
        int pos = k >> 5, c = k & 31;
        int ocr = ((c >> 2) & 1) * 16 + (c >> 3) * 4 + (c & 3);  // inverse of conv1 store perm
        w2t[j] = f2bf(w2[oc * 288 + ocr * 9 + pos]);
    } else if (i < 32 * 128 + 64 * 288 + 64 * 576) {
        int j = i - 32 * 128 - 64 * 288;
        int oc = j / 576, k = j - oc * 576;
        int pos = k >> 6, c = k & 63;
        w3t[j] = f2bf(w3[oc * 576 + c * 9 + pos]);
    }
}

// ---------------- LSTM weight prep: f16 pairs (see k_lstm)
__global__ __launch_bounds__(256) void k_wprep_lstm(const float* __restrict__ Wih0,
                                                    const float* __restrict__ Wih,
                                                    const float* __restrict__ Whh,
                                                    uint32_t* __restrict__ wpk) {
    int idx = blockIdx.x * 256 + threadIdx.x;  // 0..32767
    int lane = idx & 63;
    int j = (idx >> 6) & 63;
    int l = idx >> 12;
    int g = j >> 4, q = j & 15;
    int r = g * 64 + lane;
    uint32_t ov[4];
#pragma unroll
    for (int e = 0; e < 4; ++e) {
        int p = q * 4 + e;
        float w0, w1;
        if (p < 32) {
            int k0 = 2 * p;
            if (l == 0) {
                w0 = (k0 < 16) ? Wih0[r * 16 + k0] : 0.f;
                w1 = (k0 + 1 < 16) ? Wih0[r * 16 + k0 + 1] : 0.f;
            } else {
                const float* base = Wih + ((size_t)(l - 1) * 256 + r) * 64;
                w0 = base[k0];
                w1 = base[k0 + 1];
            }
        } else {
            int k0 = 2 * (p - 32);
            const float* base = Whh + ((size_t)l * 256 + r) * 64;
            w0 = base[k0];
            w1 = base[k0 + 1];
        }
        ov[e] = pkh2(w0, w1);
    }
    uint4 v;
    v.x = ov[0]; v.y = ov[1]; v.z = ov[2]; v.w = ov[3];
    ((uint4*)wpk)[idx] = v;
}

// ---------------- conv1 v2: y-strip kernel. Grid (128 b, 4 yh), 4 waves.
// Block owns 24 output rows (6 iters x 4 rows, wave=row). 16-slot LDS img-row
// ring (slot = row & 15; R0 = 48*yh so R0 % 16 == 0), 8-row register lookahead.
// Slot 11 zeroed in prologue: cc=15 phantom tap reads it in iter 0 (zero weight,
// but 0 x uninitialized-NaN would poison acc). Permuted-channel uint4 stores.
__global__ __launch_bounds__(256, 2) void k_conv1m(const float* __restrict__ img,
                                                   const unsigned short* __restrict__ w1t,
                                                   const float* __restrict__ bias,
                                                   unsigned short* __restrict__ out) {
    int b = blockIdx.x, yh = blockIdx.y;
    int y0 = yh * 24;
    int tid = threadIdx.x;
    __shared__ __align__(16) unsigned short lds[16 * 1040];   // 16 slots x 2080B
    char* lb = (char*)lds;
    const float* ib = img + (size_t)b * 3 * 192 * 256;
    int R0 = 2 * y0;

    int wave = tid >> 6, lane = tid & 63;
    int quad = lane >> 4, nl = lane & 15;
    // hoisted weight fragments
    bf16x8 af0[4], af1[4];
#pragma unroll
    for (int ks = 0; ks < 4; ++ks) {
        af0[ks] = *(const bf16x8*)(w1t + nl * 128 + ks * 32 + quad * 8);
        af1[ks] = *(const bf16x8*)(w1t + (16 + nl) * 128 + ks * 32 + quad * 8);
    }
    float4 bv0 = *(const float4*)(bias + quad * 4);
    float4 bv1 = *(const float4*)(bias + 16 + quad * 4);

    // prologue: rows R0..R0+10 -> slots 0..10; slot 11 zeroed
    {
        float t0[11], t1[11], t2[11];
#pragma unroll
        for (int r = 0; r < 11; ++r) {
            int row = R0 + r;
            if (row > 191) row = 191;
            const float* ip = ib + row * 256 + tid;
            t0[r] = ip[0];
            t1[r] = ip[192 * 256];
            t2[r] = ip[2 * 192 * 256];
        }
        __builtin_amdgcn_sched_barrier(0);
#pragma unroll
        for (int r = 0; r < 11; ++r) {
            uint32_t lo = (uint32_t)f2bf(t0[r]) | ((uint32_t)f2bf(t1[r]) << 16);
            *(u64*)(lb + r * 2080 + tid * 8) = (u64)lo | ((u64)f2bf(t2[r]) << 32);
        }
        *(u64*)(lb + 11 * 2080 + tid * 8) = 0ull;
    }
    // lookahead: rows R0+11..R0+18
    float g0[8], g1[8], g2[8];
#pragma unroll
    for (int r = 0; r < 8; ++r) {
        int row = R0 + 11 + r;
        if (row > 191) row = 191;
        const float* ip = ib + row * 256 + tid;
        g0[r] = ip[0];
        g1[r] = ip[192 * 256];
        g2[r] = ip[2 * 192 * 256];
    }
    __syncthreads();

    for (int it = 0; it < 6; ++it) {
        int R = R0 + 8 * it;
        int y = y0 + it * 4 + wave;
        f32x4 acc[8][2];
#pragma unroll
        for (int nt = 0; nt < 8; ++nt) {
            acc[nt][0][0] = bv0.x; acc[nt][0][1] = bv0.y; acc[nt][0][2] = bv0.z; acc[nt][0][3] = bv0.w;
            acc[nt][1][0] = bv1.x; acc[nt][1][1] = bv1.y; acc[nt][1][2] = bv1.z; acc[nt][1][3] = bv1.w;
        }
#pragma unroll
        for (int ks = 0; ks < 4; ++ks) {
            int cc = ks * 4 + quad;
            int r = cc / 3, kxp = cc - 3 * r;
            int slot = (R + 2 * wave + r) & 15;
            int rb = slot * 2080 + kxp * 16 + nl * 16;
#pragma unroll
            for (int nt = 0; nt < 8; ++nt) {
                bf16x8 bv = *(const bf16x8*)(lb + rb + nt * 256);
                acc[nt][0] = __builtin_amdgcn_mfma_f32_16x16x32_bf16(af0[ks], bv, acc[nt][0], 0, 0, 0);
                acc[nt][1] = __builtin_amdgcn_mfma_f32_16x16x32_bf16(af1[ks], bv, acc[nt][1], 0, 0, 0);
            }
        }
        if (y < 94) {
#pragma unroll
            for (int nt = 0; nt < 8; ++nt) {
                int x = nt * 16 + nl;
                if (x < 126) {
                    f32x4 a0 = acc[nt][0], a1 = acc[nt][1];
                    u64 lo = pack4bf(fmaxf(a0[0], 0.f), fmaxf(a0[1], 0.f),
                                     fmaxf(a0[2], 0.f), fmaxf(a0[3], 0.f));
                    u64 hi = pack4bf(fmaxf(a1[0], 0.f), fmaxf(a1[1], 0.f),
                                     fmaxf(a1[2], 0.f), fmaxf(a1[3], 0.f));
                    uint4 st;
                    st.x = (uint32_t)lo; st.y = (uint32_t)(lo >> 32);
                    st.z = (uint32_t)hi; st.w = (uint32_t)(hi >> 32);
                    *(uint4*)(out + (((size_t)b * 94 + y) * 126 + x) * 32 + quad * 8) = st;
                }
            }
        }
        if (it < 5) {
            __syncthreads();
            // write lookahead rows R+11..R+18 into ring
#pragma unroll
            for (int r = 0; r < 8; ++r) {
                int slot = (R + 11 + r) & 15;
                uint32_t lo = (uint32_t)f2bf(g0[r]) | ((uint32_t)f2bf(g1[r]) << 16);
                *(u64*)(lb + slot * 2080 + tid * 8) = (u64)lo | ((u64)f2bf(g2[r]) << 32);
            }
            if (it < 4) {
                // load next lookahead: rows R+19..R+26
#pragma unroll
                for (int r = 0; r < 8; ++r) {
                    int row = R + 19 + r;
                    if (row > 191) row = 191;
                    const float* ip = ib + row * 256 + tid;
                    g0[r] = ip[0];
                    g1[r] = ip[192 * 256];
                    g2[r] = ip[2 * 192 * 256];
                }
            }
            __syncthreads();
        }
    }
}

// ---------------- conv2 v2: y-strip kernel. Grid (128 b, 2 xh, 2 yh), 4 waves.
__global__ __launch_bounds__(256, 1) void k_conv2m(const unsigned short* __restrict__ in,
                                                   const unsigned short* __restrict__ w2t,
                                                   const float* __restrict__ bias,
                                                   unsigned short* __restrict__ out) {
    int b = blockIdx.x, xh = blockIdx.y, yh = blockIdx.z;
    int tid = threadIdx.x;
    int wave = tid >> 6, lane = tid & 63;
    int quad = lane >> 4, nl = lane & 15;
    int mtg = wave & 1, ntg = wave >> 1;
    __shared__ __align__(16) char lds[4 * 4680];   // 4 slots x 65 pos x 72B
    const u64* in64 = (const u64*)in;

    bf16x8 wfa[9], wfb[9];
#pragma unroll
    for (int ks = 0; ks < 9; ++ks) {
        wfa[ks] = *(const bf16x8*)(w2t + ((mtg * 2 + 0) * 16 + nl) * 288 + ks * 32 + quad * 8);
        wfb[ks] = *(const bf16x8*)(w2t + ((mtg * 2 + 1) * 16 + nl) * 288 + ks * 32 + quad * 8);
    }
    float4 bv0 = *(const float4*)(bias + (mtg * 2 + 0) * 16 + quad * 4);
    float4 bv1 = *(const float4*)(bias + (mtg * 2 + 1) * 16 + quad * 4);

    int y0 = yh * 23;
    int rr = tid >> 7, li = tid & 127;   // row-pair staging: 504 u64/row, 128 thr each

    {
        int y2 = 2 * y0 + rr;
        const u64* s = in64 + ((size_t)(b * 94 + y2) * 126 + 62 * xh) * 8;
        int slot = y2 & 3;
        u64 g0[4];
#pragma unroll
        for (int j = 0; j < 4; ++j) { int idx = li + j * 128; g0[j] = (idx < 504) ? s[idx] : 0ull; }
#pragma unroll
        for (int j = 0; j < 4; ++j) {
            int idx = li + j * 128;
            if (idx < 504) *(u64*)(lds + slot * 4680 + (idx >> 3) * 72 + (idx & 7) * 8) = g0[j];
        }
        int y2b = 2 * y0 + 2;
        const u64* s2 = in64 + ((size_t)(b * 94 + y2b) * 126 + 62 * xh) * 8;
        int slot2 = y2b & 3;
        u64 g1[2];
#pragma unroll
        for (int j = 0; j < 2; ++j) { int idx = tid + j * 256; g1[j] = (idx < 504) ? s2[idx] : 0ull; }
#pragma unroll
        for (int j = 0; j < 2; ++j) {
            int idx = tid + j * 256;
            if (idx < 504) *(u64*)(lds + slot2 * 4680 + (idx >> 3) * 72 + (idx & 7) * 8) = g1[j];
        }
    }
    u64 g[4];
    {
        int y2 = 2 * y0 + 3 + rr;
        const u64* s = in64 + ((size_t)(b * 94 + y2) * 126 + 62 * xh) * 8;
#pragma unroll
        for (int j = 0; j < 4; ++j) { int idx = li + j * 128; g[j] = (idx < 504) ? s[idx] : 0ull; }
    }
    __syncthreads();

    int xl = ntg * 16 + nl;
    for (int yy = 0; yy < 23; ++yy) {
        int y = y0 + yy;
        f32x4 acc0, acc1;
        acc0[0] = bv0.x; acc0[1] = bv0.y; acc0[2] = bv0.z; acc0[3] = bv0.w;
        acc1[0] = bv1.x; acc1[1] = bv1.y; acc1[2] = bv1.z; acc1[3] = bv1.w;
        int sb0 = ((2 * y) & 3) * 4680;
        int sb1 = ((2 * y + 1) & 3) * 4680;
        int sb2 = ((2 * y + 2) & 3) * 4680;
#pragma unroll
        for (int ks = 0; ks < 9; ++ks) {
            const int r = ks / 3, kx = ks - r * 3;
            int sb = (r == 0) ? sb0 : (r == 1) ? sb1 : sb2;
            union { u64 d[2]; bf16x8 v; } bb;
            const char* base = lds + sb + (2 * xl + kx) * 72 + quad * 16;
            bb.d[0] = *(const u64*)(base);
            bb.d[1] = *(const u64*)(base + 8);
            acc0 = __builtin_amdgcn_mfma_f32_16x16x32_bf16(wfa[ks], bb.v, acc0, 0, 0, 0);
            acc1 = __builtin_amdgcn_mfma_f32_16x16x32_bf16(wfb[ks], bb.v, acc1, 0, 0, 0);
        }
        if (xl < 31) {
            int xg = xh * 31 + xl;
            u64 p0 = pack4bf(fmaxf(acc0[0], 0.f), fmaxf(acc0[1], 0.f),
                             fmaxf(acc0[2], 0.f), fmaxf(acc0[3], 0.f));
            u64 p1 = pack4bf(fmaxf(acc1[0], 0.f), fmaxf(acc1[1], 0.f),
                             fmaxf(acc1[2], 0.f), fmaxf(acc1[3], 0.f));
            *(u64*)(out + (((size_t)b * 46 + y) * 62 + xg) * 64 + (mtg * 2 + 0) * 16 + quad * 4) = p0;
            *(u64*)(out + (((size_t)b * 46 + y) * 62 + xg) * 64 + (mtg * 2 + 1) * 16 + quad * 4) = p1;
        }
        __syncthreads();
        {
            int row = 2 * y + 3 + rr;
            int slot = row & 3;
#pragma unroll
            for (int j = 0; j < 4; ++j) {
                int idx = li + j * 128;
                if (idx < 504) *(u64*)(lds + slot * 4680 + (idx >> 3) * 72 + (idx & 7) * 8) = g[j];
            }
        }
        if (yy < 22) {
            int y2 = 2 * y + 5 + rr;
            if (y2 > 93) y2 = 93;
            const u64* s = in64 + ((size_t)(b * 94 + y2) * 126 + 62 * xh) * 8;
#pragma unroll
            for (int j = 0; j < 4; ++j) { int idx = li + j * 128; g[j] = (idx < 504) ? s[idx] : 0ull; }
        }
        __syncthreads();
    }
}

// ---------------- conv3 v2: y-strip kernel. Grid (128 b, 2 xh, 2 yh), 4 waves.
__global__ __launch_bounds__(256, 1) void k_conv3m(const unsigned short* __restrict__ in,
                                                   const unsigned short* __restrict__ w3t,
                                                   const float* __restrict__ bias,
                                                   unsigned short* __restrict__ out) {
    int b = blockIdx.x, xh = blockIdx.y, yh = blockIdx.z;
    int tid = threadIdx.x;
    int wave = tid >> 6, lane = tid & 63;
    int quad = lane >> 4, nl = lane & 15;
    __shared__ __align__(16) char lds[4 * 4488];   // 4 slots x 33 pos x 136B
    const u64* in64 = (const u64*)in;

    bf16x8 wf[18];
#pragma unroll
    for (int ks = 0; ks < 18; ++ks)
        wf[ks] = *(const bf16x8*)(w3t + (wave * 16 + nl) * 576 + ks * 32 + quad * 8);
    float4 bv = *(const float4*)(bias + wave * 16 + quad * 4);

    int y0 = yh * 11;
    int rr = tid >> 7, li = tid & 127;   // 496 u64/row, 128 thr each

    {
        int y2 = 2 * y0 + rr;
        const u64* s = in64 + ((size_t)(b * 46 + y2) * 62 + 30 * xh) * 16;
        int slot = y2 & 3;
        u64 g0[4];
#pragma unroll
        for (int j = 0; j < 4; ++j) { int idx = li + j * 128; g0[j] = (idx < 496) ? s[idx] : 0ull; }
#pragma unroll
        for (int j = 0; j < 4; ++j) {
            int idx = li + j * 128;
            if (idx < 496) *(u64*)(lds + slot * 4488 + (idx >> 4) * 136 + (idx & 15) * 8) = g0[j];
        }
        int y2b = 2 * y0 + 2;
        const u64* s2 = in64 + ((size_t)(b * 46 + y2b) * 62 + 30 * xh) * 16;
        int slot2 = y2b & 3;
        u64 g1[2];
#pragma unroll
        for (int j = 0; j < 2; ++j) { int idx = tid + j * 256; g1[j] = (idx < 496) ? s2[idx] : 0ull; }
#pragma unroll
        for (int j = 0; j < 2; ++j) {
            int idx = tid + j * 256;
            if (idx < 496) *(u64*)(lds + slot2 * 4488 + (idx >> 4) * 136 + (idx & 15) * 8) = g1[j];
        }
    }
    u64 g[4];
    {
        int y2 = 2 * y0 + 3 + rr;
        const u64* s = in64 + ((size_t)(b * 46 + y2) * 62 + 30 * xh) * 16;
#pragma unroll
        for (int j = 0; j < 4; ++j) { int idx = li + j * 128; g[j] = (idx < 496) ? s[idx] : 0ull; }
    }
    __syncthreads();

    for (int yy = 0; yy < 11; ++yy) {
        int y = y0 + yy;
        f32x4 acc;
        acc[0] = bv.x; acc[1] = bv.y; acc[2] = bv.z; acc[3] = bv.w;
        int sb0 = ((2 * y) & 3) * 4488;
        int sb1 = ((2 * y + 1) & 3) * 4488;
        int sb2 = ((2 * y + 2) & 3) * 4488;
#pragma unroll
        for (int ks = 0; ks < 18; ++ks) {
            const int pos = ks >> 1, half = ks & 1;
            const int r = pos / 3, kx = pos - r * 3;
            int sb = (r == 0) ? sb0 : (r == 1) ? sb1 : sb2;
            union { u64 d[2]; bf16x8 v; } bb;
            const char* base = lds + sb + (2 * nl + kx) * 136 + half * 64 + quad * 16;
            bb.d[0] = *(const u64*)(base);
            bb.d[1] = *(const u64*)(base + 8);
            acc = __builtin_amdgcn_mfma_f32_16x16x32_bf16(wf[ks], bb.v, acc, 0, 0, 0);
        }
        if (nl < 15) {
            int xg = xh * 15 + nl;
#pragma unroll
            for (int r2 = 0; r2 < 4; ++r2)
                out[(size_t)b * 42240 + (wave * 16 + quad * 4 + r2) * 660 + y * 30 + xg] = f2bf(acc[r2]);
        }
        __syncthreads();
        {
            int row = 2 * y + 3 + rr;
            int slot = row & 3;
#pragma unroll
            for (int j = 0; j < 4; ++j) {
                int idx = li + j * 128;
                if (idx < 496) *(u64*)(lds + slot * 4488 + (idx >> 4) * 136 + (idx & 15) * 8) = g[j];
            }
        }
        if (yy < 10) {
            int y2 = 2 * y + 5 + rr;
            if (y2 > 45) y2 = 45;
            const u64* s = in64 + ((size_t)(b * 46 + y2) * 62 + 30 * xh) * 16;
#pragma unroll
            for (int j = 0; j < 4; ++j) { int idx = li + j * 128; g[j] = (idx < 496) ? s[idx] : 0ull; }
        }
        __syncthreads();
    }
}

// ---------------- fc1 v2: LDS-staged double-buffered bf16 MFMA GEMM.
__global__ __launch_bounds__(256) void k_fc1_mfma(const unsigned short* __restrict__ A,
                                                  const float* __restrict__ W,
                                                  float* __restrict__ part) {
    int kc = blockIdx.x;  // 0..59, 704 K each
    int nb = blockIdx.y;  // 0..3
    int tid = threadIdx.x;
    int wave = tid >> 6, lane = tid & 63;
    int m16 = lane & 15, quad = lane >> 4;
    __shared__ __align__(16) char lw[2][64 * 80];    // W: 64 rows x 32 bf16, stride 80
    __shared__ __align__(16) char la[2][128 * 80];   // A: 128 rows x 32 bf16, stride 80
    int k0 = kc * 704;
    int wrow = tid >> 2, wseg = tid & 3;   // 4 thr/row x 8 fp32
    const float* wsrc = W + (size_t)(nb * 64 + wrow) * 42240 + k0 + wseg * 8;
    int arow = tid >> 1, aseg = tid & 1;   // 2 thr/row x 16 bf16
    const uint4* asrc = (const uint4*)(A + (size_t)arow * 42240 + k0) + aseg * 2;
    float4 wr0 = ((const float4*)wsrc)[0];
    float4 wr1 = ((const float4*)wsrc)[1];
    uint4 ar0 = asrc[0];
    uint4 ar1 = asrc[1];
    f32x4 acc[8] = {};
    for (int ks = 0; ks < 22; ++ks) {
        int buf = ks & 1;
        uint4 wp;
        wp.x = pkbf2(wr0.x, wr0.y); wp.y = pkbf2(wr0.z, wr0.w);
        wp.z = pkbf2(wr1.x, wr1.y); wp.w = pkbf2(wr1.z, wr1.w);
        *(uint4*)(lw[buf] + wrow * 80 + wseg * 16) = wp;
        *(uint4*)(la[buf] + arow * 80 + aseg * 32) = ar0;
        *(uint4*)(la[buf] + arow * 80 + aseg * 32 + 16) = ar1;
        if (ks < 21) {
            wsrc += 32;
            asrc += 4;
            wr0 = ((const float4*)wsrc)[0];
            wr1 = ((const float4*)wsrc)[1];
            ar0 = asrc[0];
            ar1 = asrc[1];
        }
        __syncthreads();
        bf16x8 wf = *(const bf16x8*)(lw[buf] + (wave * 16 + m16) * 80 + quad * 16);
        const char* lab = la[buf] + m16 * 80 + quad * 16;
#pragma unroll
        for (int tm = 0; tm < 8; ++tm) {
            bf16x8 af = *(const bf16x8*)(lab + tm * 16 * 80);
            acc[tm] = __builtin_amdgcn_mfma_f32_16x16x32_bf16(af, wf, acc[tm], 0, 0, 0);
        }
    }
    int n = nb * 64 + wave * 16 + m16;
    float* pb = part + ((size_t)kc * 128) * 256 + n;
#pragma unroll
    for (int tm = 0; tm < 8; ++tm) {
        int row = tm * 16 + quad * 4;
#pragma unroll
        for (int r = 0; r < 4; ++r) pb[(size_t)(row + r) * 256] = acc[tm][r];
    }
}

// ---------------- fc1-combine + fc2 + lowd1 + lowd2 fused -> cnn_out2
__global__ __launch_bounds__(256) void k_head(const float* __restrict__ part,
                                              const float* __restrict__ f1b,
                                              const float* __restrict__ w2, const float* __restrict__ b2,
                                              const float* __restrict__ lw1, const float* __restrict__ lb1,
                                              const float* __restrict__ lw2, const float* __restrict__ lb2,
                                              float* __restrict__ cnn2) {
    int b = blockIdx.x, t = threadIdx.x;
    __shared__ float xa[256];
    __shared__ float xb[128];
    __shared__ float xc[128];
    __shared__ float pp[256];
    float s = f1b[t];
#pragma unroll
    for (int kc = 0; kc < 60; ++kc) s += part[((size_t)kc * 128 + b) * 256 + t];
    xa[t] = fmaxf(s, 0.f);
    __syncthreads();
    int n = t & 127, half = t >> 7;
    float acc = half ? 0.f : b2[n];
    {
        const float* w2r = w2 + n * 256 + half * 128;
        const float* xar = xa + half * 128;
#pragma unroll
        for (int k = 0; k < 128; ++k) acc = fmaf(xar[k], w2r[k], acc);
    }
    pp[t] = acc;
    __syncthreads();
    if (t < 128) xb[t] = pp[t] + pp[t + 128];
    __syncthreads();
    acc = half ? 0.f : lb1[n];
    {
        const float* l1r = lw1 + n * 128 + half * 64;
        const float* xbr = xb + half * 64;
#pragma unroll
        for (int k = 0; k < 64; ++k) acc = fmaf(xbr[k], l1r[k], acc);
    }
    pp[t] = acc;
    __syncthreads();
    if (t < 128) xc[t] = fmaxf(pp[t] + pp[t + 128], 0.f);
    __syncthreads();
    acc = half ? 0.f : lb2[n];
    {
        const float* l2r = lw2 + n * 128 + half * 64;
        const float* xcr = xc + half * 64;
#pragma unroll
        for (int k = 0; k < 64; ++k) acc = fmaf(xcr[k], l2r[k], acc);
    }
    pp[t] = acc;
    __syncthreads();
    if (t < 128) cnn2[b * 128 + t] = pp[t] + pp[t + 128];
}

// ---------------- action MLP
__global__ __launch_bounds__(256) void k_act(const float* __restrict__ ain,
                                             const float* __restrict__ w1, const float* __restrict__ b1,
                                             const float* __restrict__ w2, const float* __restrict__ b2,
                                             float* __restrict__ abuf) {
    int idx = blockIdx.x * 256 + threadIdx.x;
    float x0 = ain[idx * 2], x1 = ain[idx * 2 + 1];
    float h1[16];
#pragma unroll
    for (int i = 0; i < 16; ++i)
        h1[i] = fmaxf(fmaf(x0, w1[i * 2], fmaf(x1, w1[i * 2 + 1], b1[i])), 0.f);
#pragma unroll
    for (int i = 0; i < 16; ++i) {
        float a = b2[i];
#pragma unroll
        for (int j = 0; j < 16; ++j) a = fmaf(h1[j], w2[i * 16 + j], a);
        abuf[idx * 16 + i] = a;
    }
}

// ---------------- LSTM v3: layer-pipelined, weights k-SPLIT across wave pairs.
__global__ __launch_bounds__(512, 2) void k_lstm(const float* __restrict__ abuf,
                                                 const float* __restrict__ cnn2,
                                                 const uint32_t* __restrict__ wpk,
                                                 const float* __restrict__ bih,
                                                 const float* __restrict__ bhh,
                                                 float* __restrict__ lout) {
    int b = blockIdx.x;
    int tid = threadIdx.x;
    int w = tid >> 6, lane = tid & 63;
    int sl = w >> 1, pt = w & 1;
    __shared__ uint32_t hbuf[2][3][32];   // [step parity][producer slot][pair]
    __shared__ uint32_t h3pk[8][32];      // layer-3 h pairs (phase 0 -> 1)
    __shared__ float4 pex[8][64];         // gate-partial exchange

    uint32_t xq[8];
#pragma unroll
    for (int t = 0; t < 8; ++t) {
        float x0 = 0.f, x1 = 0.f;
        if (lane < 8) {
            const float* ap = abuf + (b * 8 + t) * 16 + 2 * lane;
            x0 = ap[0];
            x1 = ap[1];
        }
        xq[t] = pkh2(x0, x1);
    }
    float h0 = cnn2[b * 128 + 64 + lane];
    float c0 = cnn2[b * 128 + lane];
    const u32x4* wbase = (const u32x4*)wpk;

#pragma unroll
    for (int P = 0; P < 2; ++P) {
        const int L = P * 4 + sl;
        u32x4 wreg[4][8];   // [gate][quad-of-pairs] -- 128 VGPRs, static-indexed
#pragma unroll
        for (int g = 0; g < 4; ++g)
#pragma unroll
            for (int q = 0; q < 8; ++q)
                wreg[g][q] = wbase[(size_t)L * 4096 + (g * 16 + pt * 8 + q) * 64 + lane];
        float bias0 = 0.f, bias1 = 0.f, bias2 = 0.f, bias3 = 0.f;
        if (pt == 0) {
            bias0 = bih[L * 256 + lane] + bhh[L * 256 + lane];
            bias1 = bih[L * 256 + 64 + lane] + bhh[L * 256 + 64 + lane];
            bias2 = bih[L * 256 + 128 + lane] + bhh[L * 256 + 128 + lane];
            bias3 = bih[L * 256 + 192 + lane] + bhh[L * 256 + 192 + lane];
        }
        float h = h0, c = c0;
        uint32_t hpk = packpair(h0);

        for (int s = 0; s < 11; ++s) {
            bool act = (s >= sl && s < sl + 8);
            float a0 = bias0, a1 = bias1, a2 = bias2, a3 = bias3;
            if (act) {
                if (pt == 0) {
                    uint32_t xcur;
                    if (sl == 0)
                        xcur = (P == 0) ? xq[0] : h3pk[s][lane & 31];
                    else
                        xcur = hbuf[(s & 1) ^ 1][sl - 1][lane & 31];
#pragma unroll
                    for (int m = 0; m < 32; ++m) {
                        uint32_t bx = (uint32_t)__builtin_amdgcn_readlane((int)xcur, m);
                        int q = m >> 2, e = m & 3;
                        a0 = dot2(comp4v(wreg[0][q], e), bx, a0);
                        a1 = dot2(comp4v(wreg[1][q], e), bx, a1);
                        a2 = dot2(comp4v(wreg[2][q], e), bx, a2);
                        a3 = dot2(comp4v(wreg[3][q], e), bx, a3);
                    }
                } else {
#pragma unroll
                    for (int m = 0; m < 32; ++m) {
                        uint32_t bh2 = (uint32_t)__builtin_amdgcn_readlane((int)hpk, 2 * m);
                        int q = m >> 2, e = m & 3;
                        a0 = dot2(comp4v(wreg[0][q], e), bh2, a0);
                        a1 = dot2(comp4v(wreg[1][q], e), bh2, a1);
                        a2 = dot2(comp4v(wreg[2][q], e), bh2, a2);
                        a3 = dot2(comp4v(wreg[3][q], e), bh2, a3);
                    }
                }
                float4 pv;
                pv.x = a0; pv.y = a1; pv.z = a2; pv.w = a3;
                pex[w][lane] = pv;
            }
            __syncthreads();
            if (act) {
                float4 po = pex[w ^ 1][lane];
                float g0 = a0 + po.x, g1 = a1 + po.y, g2 = a2 + po.z, g3 = a3 + po.w;
                float gi = sigm(g0), gf = sigm(g1), gv = tanh_(g2), go = sigm(g3);
                c = gf * c + gi * gv;
                h = go * tanh_(c);
                hpk = packpair(h);
                if (pt == 0) {
                    if (sl < 3) {
                        if (!(lane & 1)) hbuf[s & 1][sl][lane >> 1] = hpk;
                    } else if (P == 0) {
                        if (!(lane & 1)) h3pk[s - 3][lane >> 1] = hpk;
                    } else {
                        lout[((size_t)b * 8 + (s - 3)) * 64 + lane] = h;
                    }
                }
            }
            if (P == 0 && w == 0) {  // shift x queue (static indices only)
#pragma unroll
                for (int k = 0; k < 7; ++k) xq[k] = xq[k + 1];
            }
            __syncthreads();
        }
    }
}

// ---------------- out MLP + rotation -> d_out (128,8,4)
__global__ __launch_bounds__(256) void k_out(const float* __restrict__ lout,
                                             const float* __restrict__ w1, const float* __restrict__ b1,
                                             const float* __restrict__ w2, const float* __restrict__ b2,
                                             const float* __restrict__ gt, float* __restrict__ out) {
    int idx = blockIdx.x * 256 + threadIdx.x;
    int b = idx >> 3;
    float x[64];
#pragma unroll
    for (int j = 0; j < 64; ++j) x[j] = lout[idx * 64 + j];
    float h[32];
#pragma unroll 8
    for (int i = 0; i < 32; ++i) {
        float a = b1[i];
#pragma unroll
        for (int j = 0; j < 64; ++j) a = fmaf(x[j], w1[i * 64 + j], a);
        h[i] = fmaxf(a, 0.f);
    }
    float mo[4];
#pragma unroll
    for (int i = 0; i < 4; ++i) {
        float a = b2[i];
#pragma unroll
        for (int j = 0; j < 32; ++j) a = fmaf(h[j], w2[i * 32 + j], a);
        mo[i] = a;
    }
    float yaw = gt[b * 48 + 5];
    float cy = cosf(yaw), sy = sinf(yaw);
    out[idx * 4 + 0] = fmaf(mo[0], cy, fmaf(mo[1], sy, gt[b * 48 + 1]));
    out[idx * 4 + 1] = fmaf(mo[0], -sy, fmaf(mo[1], cy, gt[b * 48 + 2]));
    out[idx * 4 + 2] = mo[2] + gt[b * 48 + 3];
    out[idx * 4 + 3] = mo[3];
}

extern "C" void kernel_launch(void* const* d_in, const int* in_sizes, int n_in,
                              void* d_out, int out_size, void* d_ws, size_t ws_size,
                              hipStream_t stream) {
    const float* img = (const float*)d_in[0];
    const float* ain = (const float*)d_in[1];
    const float* gt = (const float*)d_in[2];
    const float* c1w = (const float*)d_in[3];
    const float* c1b = (const float*)d_in[4];
    const float* c2w = (const float*)d_in[5];
    const float* c2b = (const float*)d_in[6];
    const float* c3w = (const float*)d_in[7];
    const float* c3b = (const float*)d_in[8];
    const float* f1w = (const float*)d_in[9];
    const float* f1b = (const float*)d_in[10];
    const float* f2w = (const float*)d_in[11];
    const float* f2b = (const float*)d_in[12];
    const float* l1w = (const float*)d_in[13];
    const float* l1b = (const float*)d_in[14];
    const float* l2w = (const float*)d_in[15];
    const float* l2b = (const float*)d_in[16];
    const float* a1w = (const float*)d_in[17];
    const float* a1b = (const float*)d_in[18];
    const float* a2w = (const float*)d_in[19];
    const float* a2b = (const float*)d_in[20];
    const float* wih0 = (const float*)d_in[21];
    const float* wih = (const float*)d_in[22];
    const float* whh = (const float*)d_in[23];
    const float* bihp = (const float*)d_in[24];
    const float* bhhp = (const float*)d_in[25];
    const float* o1w = (const float*)d_in[26];
    const float* o1b = (const float*)d_in[27];
    const float* o2w = (const float*)d_in[28];
    const float* o2b = (const float*)d_in[29];
    float* out = (float*)d_out;

    char* ws = (char*)d_ws;
    unsigned short* c1o = (unsigned short*)(ws);                 // 97,026,048 B
    unsigned short* c2o = (unsigned short*)(ws + 97026048);      // 46,727,168 B
    unsigned short* c3o = (unsigned short*)(ws + 143753216);     // 10,813,440 B
    float* f1p = (float*)(ws + 154566656);                       // 60*128*256*4 = 7,864,320 B
    float* cnn2 = (float*)(ws + 163348480);
    float* abuf = (float*)(ws + 163414016);
    float* lo = (float*)(ws + 163479552);
    unsigned short* w1t = (unsigned short*)(ws + 163741696);     // 8,192 B
    unsigned short* w2t = (unsigned short*)(ws + 163749888);     // 36,864 B
    unsigned short* w3t = (unsigned short*)(ws + 163786752);     // 73,728 B
    uint32_t* wpk = (uint32_t*)(ws + 163860480);                 // 524,288 B

    k_wprep<<<232, 256, 0, stream>>>(c1w, c2w, c3w, w1t, w2t, w3t);
    k_wprep_lstm<<<128, 256, 0, stream>>>(wih0, wih, whh, wpk);
    k_conv1m<<<dim3(128, 4), 256, 0, stream>>>(img, w1t, c1b, c1o);
    k_conv2m<<<dim3(128, 2, 2), 256, 0, stream>>>(c1o, w2t, c2b, c2o);
    k_conv3m<<<dim3(128, 2, 2), 256, 0, stream>>>(c2o, w3t, c3b, c3o);
    k_fc1_mfma<<<dim3(60, 4), 256, 0, stream>>>(c3o, f1w, f1p);
    k_head<<<128, 256, 0, stream>>>(f1p, f1b, f2w, f2b, l1w, l1b, l2w, l2b, cnn2);
    k_act<<<4, 256, 0, stream>>>(ain, a1w, a1b, a2w, a2b, abuf);
    k_lstm<<<128, 512, 0, stream>>>(abuf, cnn2, wpk, bihp, bhhp, lo);
    k_out<<<4, 256, 0, stream>>>(lo, o1w, o1b, o2w, o2b, gt, out);
}

// Round 7
// 331.760 us; speedup vs baseline: 1.3884x; 1.0489x over previous
//
#include <hip/hip_runtime.h>
#include <cstdint>

#define DEV __device__ __forceinline__

typedef __attribute__((ext_vector_type(8))) short bf16x8;
typedef __attribute__((ext_vector_type(4))) float f32x4;
typedef __attribute__((ext_vector_type(2))) __fp16 h2t;
typedef __attribute__((ext_vector_type(4))) unsigned int u32x4;
typedef unsigned long long u64;

DEV unsigned short f2bf(float f) {
    unsigned u = __float_as_uint(f);
    unsigned r = u + 0x7fffu + ((u >> 16) & 1u);
    return (unsigned short)(r >> 16);
}
DEV uint32_t pkbf2(float a, float b) {
    return (uint32_t)f2bf(a) | ((uint32_t)f2bf(b) << 16);
}
DEV uint32_t pkh2(float a, float b) {
    h2t p = __builtin_amdgcn_cvt_pkrtz(a, b);
    union { h2t h; uint32_t u; } c;
    c.h = p;
    return c.u;
}
DEV float dot2(uint32_t w, uint32_t x, float acc) {
    union { uint32_t u; h2t h; } a, b;
    a.u = w; b.u = x;
    return __builtin_amdgcn_fdot2(a.h, b.h, acc, false);
}
DEV float sigm(float x) { return __builtin_amdgcn_rcpf(1.f + __expf(-x)); }
DEV float tanh_(float x) { return fmaf(2.f, sigm(2.f * x), -1.f); }
DEV uint32_t packpair(float h) {
    float hs = __int_as_float(__builtin_amdgcn_ds_swizzle(__float_as_int(h), 0x041F));
    return pkh2(h, hs);
}
DEV uint32_t comp4v(u32x4 v, int e) {
    return (e == 0) ? v[0] : (e == 1) ? v[1] : (e == 2) ? v[2] : v[3];
}
DEV u64 pack4bf(float a, float b, float c, float d) {
    unsigned lo = (unsigned)f2bf(a) | ((unsigned)f2bf(b) << 16);
    unsigned hi = (unsigned)f2bf(c) | ((unsigned)f2bf(d) << 16);
    return (u64)lo | ((u64)hi << 32);
}

// ---------------- weight prep (bf16, K-chunk order)
// conv1: w1t[oc][k] as before.
// w2t[64][288]: k = tap*32 + c'  where channel SLOT c' corresponds to conv1's
//   permuted output layout oc' = quad*8 + mi*4 + r2  (real oc = mi*16+quad*4+r2).
// w3t[64][576]: k = tap*64 + c (conv2 output unpermuted).
__global__ __launch_bounds__(256) void k_wprep(const float* __restrict__ w1,
                                               const float* __restrict__ w2,
                                               const float* __restrict__ w3,
                                               unsigned short* __restrict__ w1t,
                                               unsigned short* __restrict__ w2t,
                                               unsigned short* __restrict__ w3t) {
    int i = blockIdx.x * 256 + threadIdx.x;
    if (i < 32 * 128) {
        int oc = i >> 7, k = i & 127;
        int cc = k >> 3, u = (k >> 2) & 1, c = k & 3;
        int r = cc / 3, kx = 2 * (cc - 3 * r) + u;
        w1t[i] = (cc < 15 && kx < 5 && c < 3) ? f2bf(w1[oc * 75 + c * 25 + r * 5 + kx])
                                              : (unsigned short)0;
    } else if (i < 32 * 128 + 64 * 288) {
        int j = i - 32 * 128;
        int oc = j / 288, k = j - oc * 288;
        int pos = k >> 5, c = k & 31;
        int ocr = ((c >> 2) & 1) * 16 + (c >> 3) * 4 + (c & 3);  // inverse of conv1 store perm
        w2t[j] = f2bf(w2[oc * 288 + ocr * 9 + pos]);
    } else if (i < 32 * 128 + 64 * 288 + 64 * 576) {
        int j = i - 32 * 128 - 64 * 288;
        int oc = j / 576, k = j - oc * 576;
        int pos = k >> 6, c = k & 63;
        w3t[j] = f2bf(w3[oc * 576 + c * 9 + pos]);
    }
}

// ---------------- LSTM weight prep: f16 pairs (see k_lstm)
__global__ __launch_bounds__(256) void k_wprep_lstm(const float* __restrict__ Wih0,
                                                    const float* __restrict__ Wih,
                                                    const float* __restrict__ Whh,
                                                    uint32_t* __restrict__ wpk) {
    int idx = blockIdx.x * 256 + threadIdx.x;  // 0..32767
    int lane = idx & 63;
    int j = (idx >> 6) & 63;
    int l = idx >> 12;
    int g = j >> 4, q = j & 15;
    int r = g * 64 + lane;
    uint32_t ov[4];
#pragma unroll
    for (int e = 0; e < 4; ++e) {
        int p = q * 4 + e;
        float w0, w1;
        if (p < 32) {
            int k0 = 2 * p;
            if (l == 0) {
                w0 = (k0 < 16) ? Wih0[r * 16 + k0] : 0.f;
                w1 = (k0 + 1 < 16) ? Wih0[r * 16 + k0 + 1] : 0.f;
            } else {
                const float* base = Wih + ((size_t)(l - 1) * 256 + r) * 64;
                w0 = base[k0];
                w1 = base[k0 + 1];
            }
        } else {
            int k0 = 2 * (p - 32);
            const float* base = Whh + ((size_t)l * 256 + r) * 64;
            w0 = base[k0];
            w1 = base[k0 + 1];
        }
        ov[e] = pkh2(w0, w1);
    }
    uint4 v;
    v.x = ov[0]; v.y = ov[1]; v.z = ov[2]; v.w = ov[3];
    ((uint4*)wpk)[idx] = v;
}

// ---------------- FUSED conv1+conv2: c1o intermediate eliminated.
// Grid (128 b, 2 xh, 2 yh), 4 waves, 23 conv2-rows/block.
// LDS: img ring 8 slots x 2080B (packed [c0,c1,c2,0] u64 per x, absolute x addressing,
// only x in [124xh, 124xh+131] staged); conv1-out ring 4 slots x 63 pos x 72B in the
// permuted-c' layout conv2's w2t expects (byte-compatible with conv2 v2 reads).
// Per iter: A) 4 waves compute conv1 rows 2y+2,2y+3 (wave = rowparity x xhalf) -> ring;
// issue 4 img-row loads; barrier; C) 4 waves conv2 row y (v2 body) -> c2o store; write
// img regs -> ring; barrier. Slot algebra: A-writes (2y+2,2y+3)&3 disjoint from C-reads
// (2y..2y+2)&3; img slots overwritten only after consumption.
__global__ __launch_bounds__(256, 1) void k_conv12(const float* __restrict__ img,
                                                   const unsigned short* __restrict__ w1t,
                                                   const float* __restrict__ b1,
                                                   const unsigned short* __restrict__ w2t,
                                                   const float* __restrict__ b2,
                                                   unsigned short* __restrict__ out) {
    int b = blockIdx.x, xh = blockIdx.y, yh = blockIdx.z;
    int tid = threadIdx.x;
    int w = tid >> 6, lane = tid & 63;
    int quad = lane >> 4, nl = lane & 15;
    int nh = w >> 1, rw = w & 1;   // conv1: x-half, row-parity; conv2: x-half, oc-half
    __shared__ __align__(16) char ldsI[8 * 2080];
    __shared__ __align__(16) char ldsC[4 * 4536];
    const float* ib = img + (size_t)b * 3 * 192 * 256;
    int y0 = yh * 23;
    int imx = 124 * xh + tid;
    bool stg = tid < 132;

    bf16x8 wa1[4], wb1[4];
#pragma unroll
    for (int ks = 0; ks < 4; ++ks) {
        wa1[ks] = *(const bf16x8*)(w1t + nl * 128 + ks * 32 + quad * 8);
        wb1[ks] = *(const bf16x8*)(w1t + (16 + nl) * 128 + ks * 32 + quad * 8);
    }
    bf16x8 wa2[9], wb2[9];
#pragma unroll
    for (int ks = 0; ks < 9; ++ks) {
        wa2[ks] = *(const bf16x8*)(w2t + ((rw * 2 + 0) * 16 + nl) * 288 + ks * 32 + quad * 8);
        wb2[ks] = *(const bf16x8*)(w2t + ((rw * 2 + 1) * 16 + nl) * 288 + ks * 32 + quad * 8);
    }
    float4 c1b0 = *(const float4*)(b1 + quad * 4);
    float4 c1b1 = *(const float4*)(b1 + 16 + quad * 4);
    float4 c2b0 = *(const float4*)(b2 + (rw * 2 + 0) * 16 + quad * 4);
    float4 c2b1 = *(const float4*)(b2 + (rw * 2 + 1) * 16 + quad * 4);

    auto ldimg = [&](int row, float& f0, float& f1, float& f2) {
        if (row > 191) row = 191;
        const float* ip = ib + row * 256 + imx;
        f0 = ip[0];
        f1 = ip[192 * 256];
        f2 = ip[2 * 192 * 256];
    };
    auto stimg = [&](int row, float f0, float f1, float f2) {
        uint32_t lo = (uint32_t)f2bf(f0) | ((uint32_t)f2bf(f1) << 16);
        *(u64*)(ldsI + (row & 7) * 2080 + imx * 8) = (u64)lo | ((u64)f2bf(f2) << 32);
    };
    // compute one conv1 row R1 (this wave's x-half), write to conv1 ring
    auto conv1row = [&](int R1) {
        f32x4 a00, a01;
        a00[0] = c1b0.x; a00[1] = c1b0.y; a00[2] = c1b0.z; a00[3] = c1b0.w;
        a01[0] = c1b1.x; a01[1] = c1b1.y; a01[2] = c1b1.z; a01[3] = c1b1.w;
        f32x4 a10 = a00, a11 = a01;
#pragma unroll
        for (int ks = 0; ks < 4; ++ks) {
            int cc = ks * 4 + quad;
            int r = cc / 3, kxp = cc - 3 * r;
            int rb = ((2 * R1 + r) & 7) * 2080 + 992 * xh + 512 * nh + kxp * 16 + nl * 16;
            bf16x8 v0 = *(const bf16x8*)(ldsI + rb);
            bf16x8 v1 = *(const bf16x8*)(ldsI + rb + 256);
            a00 = __builtin_amdgcn_mfma_f32_16x16x32_bf16(wa1[ks], v0, a00, 0, 0, 0);
            a01 = __builtin_amdgcn_mfma_f32_16x16x32_bf16(wb1[ks], v0, a01, 0, 0, 0);
            a10 = __builtin_amdgcn_mfma_f32_16x16x32_bf16(wa1[ks], v1, a10, 0, 0, 0);
            a11 = __builtin_amdgcn_mfma_f32_16x16x32_bf16(wb1[ks], v1, a11, 0, 0, 0);
        }
        int cs = (R1 & 3) * 4536;
        int xl0 = nh * 32 + nl;        // <= 47, always valid
        {
            u64 lo = pack4bf(fmaxf(a00[0], 0.f), fmaxf(a00[1], 0.f),
                             fmaxf(a00[2], 0.f), fmaxf(a00[3], 0.f));
            u64 hi = pack4bf(fmaxf(a01[0], 0.f), fmaxf(a01[1], 0.f),
                             fmaxf(a01[2], 0.f), fmaxf(a01[3], 0.f));
            uint4 st;
            st.x = (uint32_t)lo; st.y = (uint32_t)(lo >> 32);
            st.z = (uint32_t)hi; st.w = (uint32_t)(hi >> 32);
            *(uint4*)(ldsC + cs + xl0 * 72 + quad * 16) = st;
        }
        int xl1 = xl0 + 16;
        if (xl1 < 63) {
            u64 lo = pack4bf(fmaxf(a10[0], 0.f), fmaxf(a10[1], 0.f),
                             fmaxf(a10[2], 0.f), fmaxf(a10[3], 0.f));
            u64 hi = pack4bf(fmaxf(a11[0], 0.f), fmaxf(a11[1], 0.f),
                             fmaxf(a11[2], 0.f), fmaxf(a11[3], 0.f));
            uint4 st;
            st.x = (uint32_t)lo; st.y = (uint32_t)(lo >> 32);
            st.z = (uint32_t)hi; st.w = (uint32_t)(hi >> 32);
            *(uint4*)(ldsC + cs + xl1 * 72 + quad * 16) = st;
        }
    };

    // prologue: img rows 4y0..4y0+7; conv1 rows 2y0,2y0+1; img rows 4y0+8..11
    {
        float p0[8], p1[8], p2[8];
        if (stg) {
#pragma unroll
            for (int r = 0; r < 8; ++r) ldimg(4 * y0 + r, p0[r], p1[r], p2[r]);
        }
        __builtin_amdgcn_sched_barrier(0);
        if (stg) {
#pragma unroll
            for (int r = 0; r < 8; ++r) stimg(4 * y0 + r, p0[r], p1[r], p2[r]);
        }
    }
    __syncthreads();
    conv1row(2 * y0 + rw);
    float g0[4], g1[4], g2[4];
    if (stg) {
#pragma unroll
        for (int r = 0; r < 4; ++r) ldimg(4 * y0 + 8 + r, g0[r], g1[r], g2[r]);
    }
    __syncthreads();
    if (stg) {
#pragma unroll
        for (int r = 0; r < 4; ++r) stimg(4 * y0 + 8 + r, g0[r], g1[r], g2[r]);
    }
    __syncthreads();

    for (int t = 0; t < 23; ++t) {
        int y = y0 + t;
        // phase A: conv1 rows 2y+2+rw; issue next img loads
        conv1row(2 * y + 2 + rw);
        if (stg) {
#pragma unroll
            for (int r = 0; r < 4; ++r) ldimg(4 * y + 12 + r, g0[r], g1[r], g2[r]);
        }
        __syncthreads();
        // phase C: conv2 row y
        {
            f32x4 acc0, acc1;
            acc0[0] = c2b0.x; acc0[1] = c2b0.y; acc0[2] = c2b0.z; acc0[3] = c2b0.w;
            acc1[0] = c2b1.x; acc1[1] = c2b1.y; acc1[2] = c2b1.z; acc1[3] = c2b1.w;
            int xl = nh * 16 + nl;
#pragma unroll
            for (int ks = 0; ks < 9; ++ks) {
                int r = ks / 3, kx = ks - r * 3;
                const char* base = ldsC + ((2 * y + r) & 3) * 4536 + (2 * xl + kx) * 72 + quad * 16;
                union { u64 d[2]; bf16x8 v; } bb;
                bb.d[0] = *(const u64*)(base);
                bb.d[1] = *(const u64*)(base + 8);
                acc0 = __builtin_amdgcn_mfma_f32_16x16x32_bf16(wa2[ks], bb.v, acc0, 0, 0, 0);
                acc1 = __builtin_amdgcn_mfma_f32_16x16x32_bf16(wb2[ks], bb.v, acc1, 0, 0, 0);
            }
            if (xl < 31) {
                int xg = xh * 31 + xl;
                u64 q0 = pack4bf(fmaxf(acc0[0], 0.f), fmaxf(acc0[1], 0.f),
                                 fmaxf(acc0[2], 0.f), fmaxf(acc0[3], 0.f));
                u64 q1 = pack4bf(fmaxf(acc1[0], 0.f), fmaxf(acc1[1], 0.f),
                                 fmaxf(acc1[2], 0.f), fmaxf(acc1[3], 0.f));
                *(u64*)(out + (((size_t)b * 46 + y) * 62 + xg) * 64 + (rw * 2 + 0) * 16 + quad * 4) = q0;
                *(u64*)(out + (((size_t)b * 46 + y) * 62 + xg) * 64 + (rw * 2 + 1) * 16 + quad * 4) = q1;
            }
        }
        if (stg) {
#pragma unroll
            for (int r = 0; r < 4; ++r) stimg(4 * y + 12 + r, g0[r], g1[r], g2[r]);
        }
        __syncthreads();
    }
}

// ---------------- conv3 v2: y-strip kernel. Grid (128 b, 2 xh, 2 yh), 4 waves.
__global__ __launch_bounds__(256, 1) void k_conv3m(const unsigned short* __restrict__ in,
                                                   const unsigned short* __restrict__ w3t,
                                                   const float* __restrict__ bias,
                                                   unsigned short* __restrict__ out) {
    int b = blockIdx.x, xh = blockIdx.y, yh = blockIdx.z;
    int tid = threadIdx.x;
    int wave = tid >> 6, lane = tid & 63;
    int quad = lane >> 4, nl = lane & 15;
    __shared__ __align__(16) char lds[4 * 4488];   // 4 slots x 33 pos x 136B
    const u64* in64 = (const u64*)in;

    bf16x8 wf[18];
#pragma unroll
    for (int ks = 0; ks < 18; ++ks)
        wf[ks] = *(const bf16x8*)(w3t + (wave * 16 + nl) * 576 + ks * 32 + quad * 8);
    float4 bv = *(const float4*)(bias + wave * 16 + quad * 4);

    int y0 = yh * 11;
    int rr = tid >> 7, li = tid & 127;   // 496 u64/row, 128 thr each

    {
        int y2 = 2 * y0 + rr;
        const u64* s = in64 + ((size_t)(b * 46 + y2) * 62 + 30 * xh) * 16;
        int slot = y2 & 3;
        u64 g0[4];
#pragma unroll
        for (int j = 0; j < 4; ++j) { int idx = li + j * 128; g0[j] = (idx < 496) ? s[idx] : 0ull; }
#pragma unroll
        for (int j = 0; j < 4; ++j) {
            int idx = li + j * 128;
            if (idx < 496) *(u64*)(lds + slot * 4488 + (idx >> 4) * 136 + (idx & 15) * 8) = g0[j];
        }
        int y2b = 2 * y0 + 2;
        const u64* s2 = in64 + ((size_t)(b * 46 + y2b) * 62 + 30 * xh) * 16;
        int slot2 = y2b & 3;
        u64 g1[2];
#pragma unroll
        for (int j = 0; j < 2; ++j) { int idx = tid + j * 256; g1[j] = (idx < 496) ? s2[idx] : 0ull; }
#pragma unroll
        for (int j = 0; j < 2; ++j) {
            int idx = tid + j * 256;
            if (idx < 496) *(u64*)(lds + slot2 * 4488 + (idx >> 4) * 136 + (idx & 15) * 8) = g1[j];
        }
    }
    u64 g[4];
    {
        int y2 = 2 * y0 + 3 + rr;
        const u64* s = in64 + ((size_t)(b * 46 + y2) * 62 + 30 * xh) * 16;
#pragma unroll
        for (int j = 0; j < 4; ++j) { int idx = li + j * 128; g[j] = (idx < 496) ? s[idx] : 0ull; }
    }
    __syncthreads();

    for (int yy = 0; yy < 11; ++yy) {
        int y = y0 + yy;
        f32x4 acc;
        acc[0] = bv.x; acc[1] = bv.y; acc[2] = bv.z; acc[3] = bv.w;
        int sb0 = ((2 * y) & 3) * 4488;
        int sb1 = ((2 * y + 1) & 3) * 4488;
        int sb2 = ((2 * y + 2) & 3) * 4488;
#pragma unroll
        for (int ks = 0; ks < 18; ++ks) {
            const int pos = ks >> 1, half = ks & 1;
            const int r = pos / 3, kx = pos - r * 3;
            int sb = (r == 0) ? sb0 : (r == 1) ? sb1 : sb2;
            union { u64 d[2]; bf16x8 v; } bb;
            const char* base = lds + sb + (2 * nl + kx) * 136 + half * 64 + quad * 16;
            bb.d[0] = *(const u64*)(base);
            bb.d[1] = *(const u64*)(base + 8);
            acc = __builtin_amdgcn_mfma_f32_16x16x32_bf16(wf[ks], bb.v, acc, 0, 0, 0);
        }
        if (nl < 15) {
            int xg = xh * 15 + nl;
#pragma unroll
            for (int r2 = 0; r2 < 4; ++r2)
                out[(size_t)b * 42240 + (wave * 16 + quad * 4 + r2) * 660 + y * 30 + xg] = f2bf(acc[r2]);
        }
        __syncthreads();
        {
            int row = 2 * y + 3 + rr;
            int slot = row & 3;
#pragma unroll
            for (int j = 0; j < 4; ++j) {
                int idx = li + j * 128;
                if (idx < 496) *(u64*)(lds + slot * 4488 + (idx >> 4) * 136 + (idx & 15) * 8) = g[j];
            }
        }
        if (yy < 10) {
            int y2 = 2 * y + 5 + rr;
            if (y2 > 45) y2 = 45;
            const u64* s = in64 + ((size_t)(b * 46 + y2) * 62 + 30 * xh) * 16;
#pragma unroll
            for (int j = 0; j < 4; ++j) { int idx = li + j * 128; g[j] = (idx < 496) ? s[idx] : 0ull; }
        }
        __syncthreads();
    }
}

// ---------------- fc1 v2: LDS-staged double-buffered bf16 MFMA GEMM.
__global__ __launch_bounds__(256) void k_fc1_mfma(const unsigned short* __restrict__ A,
                                                  const float* __restrict__ W,
                                                  float* __restrict__ part) {
    int kc = blockIdx.x;  // 0..59, 704 K each
    int nb = blockIdx.y;  // 0..3
    int tid = threadIdx.x;
    int wave = tid >> 6, lane = tid & 63;
    int m16 = lane & 15, quad = lane >> 4;
    __shared__ __align__(16) char lw[2][64 * 80];    // W: 64 rows x 32 bf16, stride 80
    __shared__ __align__(16) char la[2][128 * 80];   // A: 128 rows x 32 bf16, stride 80
    int k0 = kc * 704;
    int wrow = tid >> 2, wseg = tid & 3;   // 4 thr/row x 8 fp32
    const float* wsrc = W + (size_t)(nb * 64 + wrow) * 42240 + k0 + wseg * 8;
    int arow = tid >> 1, aseg = tid & 1;   // 2 thr/row x 16 bf16
    const uint4* asrc = (const uint4*)(A + (size_t)arow * 42240 + k0) + aseg * 2;
    float4 wr0 = ((const float4*)wsrc)[0];
    float4 wr1 = ((const float4*)wsrc)[1];
    uint4 ar0 = asrc[0];
    uint4 ar1 = asrc[1];
    f32x4 acc[8] = {};
    for (int ks = 0; ks < 22; ++ks) {
        int buf = ks & 1;
        uint4 wp;
        wp.x = pkbf2(wr0.x, wr0.y); wp.y = pkbf2(wr0.z, wr0.w);
        wp.z = pkbf2(wr1.x, wr1.y); wp.w = pkbf2(wr1.z, wr1.w);
        *(uint4*)(lw[buf] + wrow * 80 + wseg * 16) = wp;
        *(uint4*)(la[buf] + arow * 80 + aseg * 32) = ar0;
        *(uint4*)(la[buf] + arow * 80 + aseg * 32 + 16) = ar1;
        if (ks < 21) {
            wsrc += 32;
            asrc += 4;
            wr0 = ((const float4*)wsrc)[0];
            wr1 = ((const float4*)wsrc)[1];
            ar0 = asrc[0];
            ar1 = asrc[1];
        }
        __syncthreads();
        bf16x8 wf = *(const bf16x8*)(lw[buf] + (wave * 16 + m16) * 80 + quad * 16);
        const char* lab = la[buf] + m16 * 80 + quad * 16;
#pragma unroll
        for (int tm = 0; tm < 8; ++tm) {
            bf16x8 af = *(const bf16x8*)(lab + tm * 16 * 80);
            acc[tm] = __builtin_amdgcn_mfma_f32_16x16x32_bf16(af, wf, acc[tm], 0, 0, 0);
        }
    }
    int n = nb * 64 + wave * 16 + m16;
    float* pb = part + ((size_t)kc * 128) * 256 + n;
#pragma unroll
    for (int tm = 0; tm < 8; ++tm) {
        int row = tm * 16 + quad * 4;
#pragma unroll
        for (int r = 0; r < 4; ++r) pb[(size_t)(row + r) * 256] = acc[tm][r];
    }
}

// ---------------- fc1-combine + fc2 + lowd1 + lowd2 fused -> cnn_out2
__global__ __launch_bounds__(256) void k_head(const float* __restrict__ part,
                                              const float* __restrict__ f1b,
                                              const float* __restrict__ w2, const float* __restrict__ b2,
                                              const float* __restrict__ lw1, const float* __restrict__ lb1,
                                              const float* __restrict__ lw2, const float* __restrict__ lb2,
                                              float* __restrict__ cnn2) {
    int b = blockIdx.x, t = threadIdx.x;
    __shared__ float xa[256];
    __shared__ float xb[128];
    __shared__ float xc[128];
    __shared__ float pp[256];
    float s = f1b[t];
#pragma unroll
    for (int kc = 0; kc < 60; ++kc) s += part[((size_t)kc * 128 + b) * 256 + t];
    xa[t] = fmaxf(s, 0.f);
    __syncthreads();
    int n = t & 127, half = t >> 7;
    float acc = half ? 0.f : b2[n];
    {
        const float* w2r = w2 + n * 256 + half * 128;
        const float* xar = xa + half * 128;
#pragma unroll
        for (int k = 0; k < 128; ++k) acc = fmaf(xar[k], w2r[k], acc);
    }
    pp[t] = acc;
    __syncthreads();
    if (t < 128) xb[t] = pp[t] + pp[t + 128];
    __syncthreads();
    acc = half ? 0.f : lb1[n];
    {
        const float* l1r = lw1 + n * 128 + half * 64;
        const float* xbr = xb + half * 64;
#pragma unroll
        for (int k = 0; k < 64; ++k) acc = fmaf(xbr[k], l1r[k], acc);
    }
    pp[t] = acc;
    __syncthreads();
    if (t < 128) xc[t] = fmaxf(pp[t] + pp[t + 128], 0.f);
    __syncthreads();
    acc = half ? 0.f : lb2[n];
    {
        const float* l2r = lw2 + n * 128 + half * 64;
        const float* xcr = xc + half * 64;
#pragma unroll
        for (int k = 0; k < 64; ++k) acc = fmaf(xcr[k], l2r[k], acc);
    }
    pp[t] = acc;
    __syncthreads();
    if (t < 128) cnn2[b * 128 + t] = pp[t] + pp[t + 128];
}

// ---------------- action MLP
__global__ __launch_bounds__(256) void k_act(const float* __restrict__ ain,
                                             const float* __restrict__ w1, const float* __restrict__ b1,
                                             const float* __restrict__ w2, const float* __restrict__ b2,
                                             float* __restrict__ abuf) {
    int idx = blockIdx.x * 256 + threadIdx.x;
    float x0 = ain[idx * 2], x1 = ain[idx * 2 + 1];
    float h1[16];
#pragma unroll
    for (int i = 0; i < 16; ++i)
        h1[i] = fmaxf(fmaf(x0, w1[i * 2], fmaf(x1, w1[i * 2 + 1], b1[i])), 0.f);
#pragma unroll
    for (int i = 0; i < 16; ++i) {
        float a = b2[i];
#pragma unroll
        for (int j = 0; j < 16; ++j) a = fmaf(h1[j], w2[i * 16 + j], a);
        abuf[idx * 16 + i] = a;
    }
}

// ---------------- LSTM v3: layer-pipelined, weights k-SPLIT across wave pairs.
__global__ __launch_bounds__(512, 2) void k_lstm(const float* __restrict__ abuf,
                                                 const float* __restrict__ cnn2,
                                                 const uint32_t* __restrict__ wpk,
                                                 const float* __restrict__ bih,
                                                 const float* __restrict__ bhh,
                                                 float* __restrict__ lout) {
    int b = blockIdx.x;
    int tid = threadIdx.x;
    int w = tid >> 6, lane = tid & 63;
    int sl = w >> 1, pt = w & 1;
    __shared__ uint32_t hbuf[2][3][32];   // [step parity][producer slot][pair]
    __shared__ uint32_t h3pk[8][32];      // layer-3 h pairs (phase 0 -> 1)
    __shared__ float4 pex[8][64];         // gate-partial exchange

    uint32_t xq[8];
#pragma unroll
    for (int t = 0; t < 8; ++t) {
        float x0 = 0.f, x1 = 0.f;
        if (lane < 8) {
            const float* ap = abuf + (b * 8 + t) * 16 + 2 * lane;
            x0 = ap[0];
            x1 = ap[1];
        }
        xq[t] = pkh2(x0, x1);
    }
    float h0 = cnn2[b * 128 + 64 + lane];
    float c0 = cnn2[b * 128 + lane];
    const u32x4* wbase = (const u32x4*)wpk;

#pragma unroll
    for (int P = 0; P < 2; ++P) {
        const int L = P * 4 + sl;
        u32x4 wreg[4][8];   // [gate][quad-of-pairs] -- 128 VGPRs, static-indexed
#pragma unroll
        for (int g = 0; g < 4; ++g)
#pragma unroll
            for (int q = 0; q < 8; ++q)
                wreg[g][q] = wbase[(size_t)L * 4096 + (g * 16 + pt * 8 + q) * 64 + lane];
        float bias0 = 0.f, bias1 = 0.f, bias2 = 0.f, bias3 = 0.f;
        if (pt == 0) {
            bias0 = bih[L * 256 + lane] + bhh[L * 256 + lane];
            bias1 = bih[L * 256 + 64 + lane] + bhh[L * 256 + 64 + lane];
            bias2 = bih[L * 256 + 128 + lane] + bhh[L * 256 + 128 + lane];
            bias3 = bih[L * 256 + 192 + lane] + bhh[L * 256 + 192 + lane];
        }
        float h = h0, c = c0;
        uint32_t hpk = packpair(h0);

        for (int s = 0; s < 11; ++s) {
            bool act = (s >= sl && s < sl + 8);
            float a0 = bias0, a1 = bias1, a2 = bias2, a3 = bias3;
            if (act) {
                if (pt == 0) {
                    uint32_t xcur;
                    if (sl == 0)
                        xcur = (P == 0) ? xq[0] : h3pk[s][lane & 31];
                    else
                        xcur = hbuf[(s & 1) ^ 1][sl - 1][lane & 31];
#pragma unroll
                    for (int m = 0; m < 32; ++m) {
                        uint32_t bx = (uint32_t)__builtin_amdgcn_readlane((int)xcur, m);
                        int q = m >> 2, e = m & 3;
                        a0 = dot2(comp4v(wreg[0][q], e), bx, a0);
                        a1 = dot2(comp4v(wreg[1][q], e), bx, a1);
                        a2 = dot2(comp4v(wreg[2][q], e), bx, a2);
                        a3 = dot2(comp4v(wreg[3][q], e), bx, a3);
                    }
                } else {
#pragma unroll
                    for (int m = 0; m < 32; ++m) {
                        uint32_t bh2 = (uint32_t)__builtin_amdgcn_readlane((int)hpk, 2 * m);
                        int q = m >> 2, e = m & 3;
                        a0 = dot2(comp4v(wreg[0][q], e), bh2, a0);
                        a1 = dot2(comp4v(wreg[1][q], e), bh2, a1);
                        a2 = dot2(comp4v(wreg[2][q], e), bh2, a2);
                        a3 = dot2(comp4v(wreg[3][q], e), bh2, a3);
                    }
                }
                float4 pv;
                pv.x = a0; pv.y = a1; pv.z = a2; pv.w = a3;
                pex[w][lane] = pv;
            }
            __syncthreads();
            if (act) {
                float4 po = pex[w ^ 1][lane];
                float g0 = a0 + po.x, g1 = a1 + po.y, g2 = a2 + po.z, g3 = a3 + po.w;
                float gi = sigm(g0), gf = sigm(g1), gv = tanh_(g2), go = sigm(g3);
                c = gf * c + gi * gv;
                h = go * tanh_(c);
                hpk = packpair(h);
                if (pt == 0) {
                    if (sl < 3) {
                        if (!(lane & 1)) hbuf[s & 1][sl][lane >> 1] = hpk;
                    } else if (P == 0) {
                        if (!(lane & 1)) h3pk[s - 3][lane >> 1] = hpk;
                    } else {
                        lout[((size_t)b * 8 + (s - 3)) * 64 + lane] = h;
                    }
                }
            }
            if (P == 0 && w == 0) {  // shift x queue (static indices only)
#pragma unroll
                for (int k = 0; k < 7; ++k) xq[k] = xq[k + 1];
            }
            __syncthreads();
        }
    }
}

// ---------------- out MLP + rotation -> d_out (128,8,4)
__global__ __launch_bounds__(256) void k_out(const float* __restrict__ lout,
                                             const float* __restrict__ w1, const float* __restrict__ b1,
                                             const float* __restrict__ w2, const float* __restrict__ b2,
                                             const float* __restrict__ gt, float* __restrict__ out) {
    int idx = blockIdx.x * 256 + threadIdx.x;
    int b = idx >> 3;
    float x[64];
#pragma unroll
    for (int j = 0; j < 64; ++j) x[j] = lout[idx * 64 + j];
    float h[32];
#pragma unroll 8
    for (int i = 0; i < 32; ++i) {
        float a = b1[i];
#pragma unroll
        for (int j = 0; j < 64; ++j) a = fmaf(x[j], w1[i * 64 + j], a);
        h[i] = fmaxf(a, 0.f);
    }
    float mo[4];
#pragma unroll
    for (int i = 0; i < 4; ++i) {
        float a = b2[i];
#pragma unroll
        for (int j = 0; j < 32; ++j) a = fmaf(h[j], w2[i * 32 + j], a);
        mo[i] = a;
    }
    float yaw = gt[b * 48 + 5];
    float cy = cosf(yaw), sy = sinf(yaw);
    out[idx * 4 + 0] = fmaf(mo[0], cy, fmaf(mo[1], sy, gt[b * 48 + 1]));
    out[idx * 4 + 1] = fmaf(mo[0], -sy, fmaf(mo[1], cy, gt[b * 48 + 2]));
    out[idx * 4 + 2] = mo[2] + gt[b * 48 + 3];
    out[idx * 4 + 3] = mo[3];
}

extern "C" void kernel_launch(void* const* d_in, const int* in_sizes, int n_in,
                              void* d_out, int out_size, void* d_ws, size_t ws_size,
                              hipStream_t stream) {
    const float* img = (const float*)d_in[0];
    const float* ain = (const float*)d_in[1];
    const float* gt = (const float*)d_in[2];
    const float* c1w = (const float*)d_in[3];
    const float* c1b = (const float*)d_in[4];
    const float* c2w = (const float*)d_in[5];
    const float* c2b = (const float*)d_in[6];
    const float* c3w = (const float*)d_in[7];
    const float* c3b = (const float*)d_in[8];
    const float* f1w = (const float*)d_in[9];
    const float* f1b = (const float*)d_in[10];
    const float* f2w = (const float*)d_in[11];
    const float* f2b = (const float*)d_in[12];
    const float* l1w = (const float*)d_in[13];
    const float* l1b = (const float*)d_in[14];
    const float* l2w = (const float*)d_in[15];
    const float* l2b = (const float*)d_in[16];
    const float* a1w = (const float*)d_in[17];
    const float* a1b = (const float*)d_in[18];
    const float* a2w = (const float*)d_in[19];
    const float* a2b = (const float*)d_in[20];
    const float* wih0 = (const float*)d_in[21];
    const float* wih = (const float*)d_in[22];
    const float* whh = (const float*)d_in[23];
    const float* bihp = (const float*)d_in[24];
    const float* bhhp = (const float*)d_in[25];
    const float* o1w = (const float*)d_in[26];
    const float* o1b = (const float*)d_in[27];
    const float* o2w = (const float*)d_in[28];
    const float* o2b = (const float*)d_in[29];
    float* out = (float*)d_out;

    char* ws = (char*)d_ws;
    unsigned short* c2o = (unsigned short*)(ws + 97026048);      // 46,727,168 B
    unsigned short* c3o = (unsigned short*)(ws + 143753216);     // 10,813,440 B
    float* f1p = (float*)(ws + 154566656);                       // 60*128*256*4 = 7,864,320 B
    float* cnn2 = (float*)(ws + 163348480);
    float* abuf = (float*)(ws + 163414016);
    float* lo = (float*)(ws + 163479552);
    unsigned short* w1t = (unsigned short*)(ws + 163741696);     // 8,192 B
    unsigned short* w2t = (unsigned short*)(ws + 163749888);     // 36,864 B
    unsigned short* w3t = (unsigned short*)(ws + 163786752);     // 73,728 B
    uint32_t* wpk = (uint32_t*)(ws + 163860480);                 // 524,288 B

    k_wprep<<<232, 256, 0, stream>>>(c1w, c2w, c3w, w1t, w2t, w3t);
    k_wprep_lstm<<<128, 256, 0, stream>>>(wih0, wih, whh, wpk);
    k_conv12<<<dim3(128, 2, 2), 256, 0, stream>>>(img, w1t, c1b, w2t, c2b, c2o);
    k_conv3m<<<dim3(128, 2, 2), 256, 0, stream>>>(c2o, w3t, c3b, c3o);
    k_fc1_mfma<<<dim3(60, 4), 256, 0, stream>>>(c3o, f1w, f1p);
    k_head<<<128, 256, 0, stream>>>(f1p, f1b, f2w, f2b, l1w, l1b, l2w, l2b, cnn2);
    k_act<<<4, 256, 0, stream>>>(ain, a1w, a1b, a2w, a2b, abuf);
    k_lstm<<<128, 512, 0, stream>>>(abuf, cnn2, wpk, bihp, bhhp, lo);
    k_out<<<4, 256, 0, stream>>>(lo, o1w, o1b, o2w, o2b, gt, out);
}

// Round 8
// 326.998 us; speedup vs baseline: 1.4086x; 1.0146x over previous
//
#include <hip/hip_runtime.h>
#include <cstdint>

#define DEV __device__ __forceinline__

typedef __attribute__((ext_vector_type(8))) short bf16x8;
typedef __attribute__((ext_vector_type(4))) float f32x4;
typedef __attribute__((ext_vector_type(2))) __fp16 h2t;
typedef __attribute__((ext_vector_type(4))) unsigned int u32x4;
typedef unsigned long long u64;

DEV unsigned short f2bf(float f) {
    unsigned u = __float_as_uint(f);
    unsigned r = u + 0x7fffu + ((u >> 16) & 1u);
    return (unsigned short)(r >> 16);
}
DEV uint32_t pkbf2(float a, float b) {
    return (uint32_t)f2bf(a) | ((uint32_t)f2bf(b) << 16);
}
DEV uint32_t pkh2(float a, float b) {
    h2t p = __builtin_amdgcn_cvt_pkrtz(a, b);
    union { h2t h; uint32_t u; } c;
    c.h = p;
    return c.u;
}
DEV float dot2(uint32_t w, uint32_t x, float acc) {
    union { uint32_t u; h2t h; } a, b;
    a.u = w; b.u = x;
    return __builtin_amdgcn_fdot2(a.h, b.h, acc, false);
}
DEV float sigm(float x) { return __builtin_amdgcn_rcpf(1.f + __expf(-x)); }
DEV float tanh_(float x) { return fmaf(2.f, sigm(2.f * x), -1.f); }
DEV uint32_t packpair(float h) {
    float hs = __int_as_float(__builtin_amdgcn_ds_swizzle(__float_as_int(h), 0x041F));
    return pkh2(h, hs);
}
DEV uint32_t comp4v(u32x4 v, int e) {
    return (e == 0) ? v[0] : (e == 1) ? v[1] : (e == 2) ? v[2] : v[3];
}
DEV u64 pack4bf(float a, float b, float c, float d) {
    unsigned lo = (unsigned)f2bf(a) | ((unsigned)f2bf(b) << 16);
    unsigned hi = (unsigned)f2bf(c) | ((unsigned)f2bf(d) << 16);
    return (u64)lo | ((u64)hi << 32);
}

// ---------------- weight prep (bf16, K-chunk order)
__global__ __launch_bounds__(256) void k_wprep(const float* __restrict__ w1,
                                               const float* __restrict__ w2,
                                               const float* __restrict__ w3,
                                               unsigned short* __restrict__ w1t,
                                               unsigned short* __restrict__ w2t,
                                               unsigned short* __restrict__ w3t) {
    int i = blockIdx.x * 256 + threadIdx.x;
    if (i < 32 * 128) {
        int oc = i >> 7, k = i & 127;
        int cc = k >> 3, u = (k >> 2) & 1, c = k & 3;
        int r = cc / 3, kx = 2 * (cc - 3 * r) + u;
        w1t[i] = (cc < 15 && kx < 5 && c < 3) ? f2bf(w1[oc * 75 + c * 25 + r * 5 + kx])
                                              : (unsigned short)0;
    } else if (i < 32 * 128 + 64 * 288) {
        int j = i - 32 * 128;
        int oc = j / 288, k = j - oc * 288;
        int pos = k >> 5, c = k & 31;
        int ocr = ((c >> 2) & 1) * 16 + (c >> 3) * 4 + (c & 3);  // inverse of conv1 store perm
        w2t[j] = f2bf(w2[oc * 288 + ocr * 9 + pos]);
    } else if (i < 32 * 128 + 64 * 288 + 64 * 576) {
        int j = i - 32 * 128 - 64 * 288;
        int oc = j / 576, k = j - oc * 576;
        int pos = k >> 6, c = k & 63;
        w3t[j] = f2bf(w3[oc * 576 + c * 9 + pos]);
    }
}

// ---------------- LSTM weight prep: f16 pairs (see k_lstm)
__global__ __launch_bounds__(256) void k_wprep_lstm(const float* __restrict__ Wih0,
                                                    const float* __restrict__ Wih,
                                                    const float* __restrict__ Whh,
                                                    uint32_t* __restrict__ wpk) {
    int idx = blockIdx.x * 256 + threadIdx.x;  // 0..32767
    int lane = idx & 63;
    int j = (idx >> 6) & 63;
    int l = idx >> 12;
    int g = j >> 4, q = j & 15;
    int r = g * 64 + lane;
    uint32_t ov[4];
#pragma unroll
    for (int e = 0; e < 4; ++e) {
        int p = q * 4 + e;
        float w0, w1;
        if (p < 32) {
            int k0 = 2 * p;
            if (l == 0) {
                w0 = (k0 < 16) ? Wih0[r * 16 + k0] : 0.f;
                w1 = (k0 + 1 < 16) ? Wih0[r * 16 + k0 + 1] : 0.f;
            } else {
                const float* base = Wih + ((size_t)(l - 1) * 256 + r) * 64;
                w0 = base[k0];
                w1 = base[k0 + 1];
            }
        } else {
            int k0 = 2 * (p - 32);
            const float* base = Whh + ((size_t)l * 256 + r) * 64;
            w0 = base[k0];
            w1 = base[k0 + 1];
        }
        ov[e] = pkh2(w0, w1);
    }
    uint4 v;
    v.x = ov[0]; v.y = ov[1]; v.z = ov[2]; v.w = ov[3];
    ((uint4*)wpk)[idx] = v;
}

// ---------------- FUSED conv1+conv2 v2: single-barrier pipelined iteration.
// Grid (128 b, 2 xh, 4 ys) = 1024 blocks; strips of 12/12/12/10 conv2 rows.
// conv1 runs 2 rows AHEAD of conv2: iter t computes conv1 rows 2y+4,2y+5 while
// conv2 consumes rows 2y..2y+2 -> disjoint ring slots -> ONE barrier per iter,
// and conv1-MFMA + conv2-MFMA + img global loads share one scheduling region.
// img ring: 12 slots (live rows [4y+8,4y+19]); slot = row mod 12 (y0 % 12 == 0,
// so slot = (t3 + c) mod 12 with t3 = 4t mod 12 maintained incrementally).
// conv1-out ring: 6 slots (live rows 2y..2y+5), slot = row mod 6 via t3>>1.
// conv1 rows > 93 skipped (never consumed). Phantom tap (cc=15, r=5) reads a
// staged row with zero weight -> exact.
__global__ __launch_bounds__(256, 2) void k_conv12(const float* __restrict__ img,
                                                   const unsigned short* __restrict__ w1t,
                                                   const float* __restrict__ b1,
                                                   const unsigned short* __restrict__ w2t,
                                                   const float* __restrict__ b2,
                                                   unsigned short* __restrict__ out) {
    int b = blockIdx.x, xh = blockIdx.y, ys = blockIdx.z;
    int tid = threadIdx.x;
    int w = tid >> 6, lane = tid & 63;
    int quad = lane >> 4, nl = lane & 15;
    int nh = w >> 1, rw = w & 1;   // conv1: x-half, row-parity; conv2: x-half, oc-half
    __shared__ __align__(16) char ldsI[12 * 2080];
    __shared__ __align__(16) char ldsC[6 * 4536];
    const float* ib = img + (size_t)b * 3 * 192 * 256;
    int y0 = ys * 12;
    int NT = (ys == 3) ? 10 : 12;
    int imx = 124 * xh + tid;
    bool stg = tid < 132;

    bf16x8 wa1[4], wb1[4];
#pragma unroll
    for (int ks = 0; ks < 4; ++ks) {
        wa1[ks] = *(const bf16x8*)(w1t + nl * 128 + ks * 32 + quad * 8);
        wb1[ks] = *(const bf16x8*)(w1t + (16 + nl) * 128 + ks * 32 + quad * 8);
    }
    bf16x8 wa2[9], wb2[9];
#pragma unroll
    for (int ks = 0; ks < 9; ++ks) {
        wa2[ks] = *(const bf16x8*)(w2t + ((rw * 2 + 0) * 16 + nl) * 288 + ks * 32 + quad * 8);
        wb2[ks] = *(const bf16x8*)(w2t + ((rw * 2 + 1) * 16 + nl) * 288 + ks * 32 + quad * 8);
    }
    float4 c1b0 = *(const float4*)(b1 + quad * 4);
    float4 c1b1 = *(const float4*)(b1 + 16 + quad * 4);
    float4 c2b0 = *(const float4*)(b2 + (rw * 2 + 0) * 16 + quad * 4);
    float4 c2b1 = *(const float4*)(b2 + (rw * 2 + 1) * 16 + quad * 4);

    auto ldimg = [&](int row, float& f0, float& f1, float& f2) {
        if (row > 191) row = 191;
        const float* ip = ib + row * 256 + imx;
        f0 = ip[0];
        f1 = ip[192 * 256];
        f2 = ip[2 * 192 * 256];
    };
    auto stimgS = [&](int slot, float f0, float f1, float f2) {
        uint32_t lo = (uint32_t)f2bf(f0) | ((uint32_t)f2bf(f1) << 16);
        *(u64*)(ldsI + slot * 2080 + imx * 8) = (u64)lo | ((u64)f2bf(f2) << 32);
    };
    // compute one conv1 row; s0 = (2*R1) mod 12, cslot = R1 mod 6
    auto conv1row = [&](int s0, int cslot) {
        f32x4 a00, a01;
        a00[0] = c1b0.x; a00[1] = c1b0.y; a00[2] = c1b0.z; a00[3] = c1b0.w;
        a01[0] = c1b1.x; a01[1] = c1b1.y; a01[2] = c1b1.z; a01[3] = c1b1.w;
        f32x4 a10 = a00, a11 = a01;
#pragma unroll
        for (int ks = 0; ks < 4; ++ks) {
            int cc = ks * 4 + quad;
            int r = cc / 3, kxp = cc - 3 * r;
            int sl = s0 + r; if (sl >= 12) sl -= 12;
            int rb = sl * 2080 + 992 * xh + 512 * nh + kxp * 16 + nl * 16;
            bf16x8 v0 = *(const bf16x8*)(ldsI + rb);
            bf16x8 v1 = *(const bf16x8*)(ldsI + rb + 256);
            a00 = __builtin_amdgcn_mfma_f32_16x16x32_bf16(wa1[ks], v0, a00, 0, 0, 0);
            a01 = __builtin_amdgcn_mfma_f32_16x16x32_bf16(wb1[ks], v0, a01, 0, 0, 0);
            a10 = __builtin_amdgcn_mfma_f32_16x16x32_bf16(wa1[ks], v1, a10, 0, 0, 0);
            a11 = __builtin_amdgcn_mfma_f32_16x16x32_bf16(wb1[ks], v1, a11, 0, 0, 0);
        }
        int cs = cslot * 4536;
        int xl0 = nh * 32 + nl;
        {
            u64 lo = pack4bf(fmaxf(a00[0], 0.f), fmaxf(a00[1], 0.f),
                             fmaxf(a00[2], 0.f), fmaxf(a00[3], 0.f));
            u64 hi = pack4bf(fmaxf(a01[0], 0.f), fmaxf(a01[1], 0.f),
                             fmaxf(a01[2], 0.f), fmaxf(a01[3], 0.f));
            uint4 st;
            st.x = (uint32_t)lo; st.y = (uint32_t)(lo >> 32);
            st.z = (uint32_t)hi; st.w = (uint32_t)(hi >> 32);
            *(uint4*)(ldsC + cs + xl0 * 72 + quad * 16) = st;
        }
        int xl1 = xl0 + 16;
        if (xl1 < 63) {
            u64 lo = pack4bf(fmaxf(a10[0], 0.f), fmaxf(a10[1], 0.f),
                             fmaxf(a10[2], 0.f), fmaxf(a10[3], 0.f));
            u64 hi = pack4bf(fmaxf(a11[0], 0.f), fmaxf(a11[1], 0.f),
                             fmaxf(a11[2], 0.f), fmaxf(a11[3], 0.f));
            uint4 st;
            st.x = (uint32_t)lo; st.y = (uint32_t)(lo >> 32);
            st.z = (uint32_t)hi; st.w = (uint32_t)(hi >> 32);
            *(uint4*)(ldsC + cs + xl1 * 72 + quad * 16) = st;
        }
    };

    // ---- prologue ----
    // img rows 4y0..4y0+11 -> slots 0..11
    {
        float p0[12], p1[12], p2[12];
        if (stg) {
#pragma unroll
            for (int r = 0; r < 12; ++r) ldimg(4 * y0 + r, p0[r], p1[r], p2[r]);
        }
        __builtin_amdgcn_sched_barrier(0);
        if (stg) {
#pragma unroll
            for (int r = 0; r < 12; ++r) stimgS(r, p0[r], p1[r], p2[r]);
        }
    }
    __syncthreads();
    // conv1 rows 2y0+rw  (slots: img s0=2rw, conv1 cslot=rw)
    conv1row(2 * rw, rw);
    float g0[4], g1[4], g2[4];
    if (stg) {
#pragma unroll
        for (int j = 0; j < 4; ++j) ldimg(4 * y0 + 12 + j, g0[j], g1[j], g2[j]);
    }
    __syncthreads();
    // conv1 rows 2y0+2+rw (img s0=4+2rw, cslot=2+rw); stage img rows 12..15 -> slots 0..3
    conv1row(4 + 2 * rw, 2 + rw);
    if (stg) {
#pragma unroll
        for (int j = 0; j < 4; ++j) stimgS(j, g0[j], g1[j], g2[j]);
    }
    __syncthreads();

    // ---- main loop: one barrier per iteration ----
    int t3 = 0;   // (4t) mod 12
    for (int t = 0; t < NT; ++t) {
        int y = y0 + t;
        int t3h = t3 >> 1;   // (2t) mod 6
        // issue img loads rows 4y+16..19 (consumed next iters)
        if (stg) {
#pragma unroll
            for (int j = 0; j < 4; ++j) ldimg(4 * y + 16 + j, g0[j], g1[j], g2[j]);
        }
        // conv1 rows 2y+4+rw (2 ahead)
        int R1 = 2 * y + 4 + rw;
        if (R1 <= 93) {
            int s0 = t3 + 8 + 2 * rw; if (s0 >= 12) s0 -= 12;
            int cs = t3h + 4 + rw; if (cs >= 6) cs -= 6;
            conv1row(s0, cs);
        }
        // conv2 row y from conv1 ring rows 2y..2y+2
        {
            f32x4 acc0, acc1;
            acc0[0] = c2b0.x; acc0[1] = c2b0.y; acc0[2] = c2b0.z; acc0[3] = c2b0.w;
            acc1[0] = c2b1.x; acc1[1] = c2b1.y; acc1[2] = c2b1.z; acc1[3] = c2b1.w;
            int xl = nh * 16 + nl;
#pragma unroll
            for (int ks = 0; ks < 9; ++ks) {
                int r = ks / 3, kx = ks - r * 3;
                int cs = t3h + r; if (cs >= 6) cs -= 6;
                const char* base = ldsC + cs * 4536 + (2 * xl + kx) * 72 + quad * 16;
                union { u64 d[2]; bf16x8 v; } bb;
                bb.d[0] = *(const u64*)(base);
                bb.d[1] = *(const u64*)(base + 8);
                acc0 = __builtin_amdgcn_mfma_f32_16x16x32_bf16(wa2[ks], bb.v, acc0, 0, 0, 0);
                acc1 = __builtin_amdgcn_mfma_f32_16x16x32_bf16(wb2[ks], bb.v, acc1, 0, 0, 0);
            }
            if (xl < 31) {
                int xg = xh * 31 + xl;
                u64 q0 = pack4bf(fmaxf(acc0[0], 0.f), fmaxf(acc0[1], 0.f),
                                 fmaxf(acc0[2], 0.f), fmaxf(acc0[3], 0.f));
                u64 q1 = pack4bf(fmaxf(acc1[0], 0.f), fmaxf(acc1[1], 0.f),
                                 fmaxf(acc1[2], 0.f), fmaxf(acc1[3], 0.f));
                *(u64*)(out + (((size_t)b * 46 + y) * 62 + xg) * 64 + (rw * 2 + 0) * 16 + quad * 4) = q0;
                *(u64*)(out + (((size_t)b * 46 + y) * 62 + xg) * 64 + (rw * 2 + 1) * 16 + quad * 4) = q1;
            }
        }
        // write img rows 4y+16..19 -> slots (t3+4+j) mod 12
        if (stg) {
#pragma unroll
            for (int j = 0; j < 4; ++j) {
                int sl = t3 + 4 + j; if (sl >= 12) sl -= 12;
                stimgS(sl, g0[j], g1[j], g2[j]);
            }
        }
        __syncthreads();
        t3 += 4; if (t3 == 12) t3 = 0;
    }
}

// ---------------- conv3 v2: y-strip kernel. Grid (128 b, 2 xh, 2 yh), 4 waves.
__global__ __launch_bounds__(256, 1) void k_conv3m(const unsigned short* __restrict__ in,
                                                   const unsigned short* __restrict__ w3t,
                                                   const float* __restrict__ bias,
                                                   unsigned short* __restrict__ out) {
    int b = blockIdx.x, xh = blockIdx.y, yh = blockIdx.z;
    int tid = threadIdx.x;
    int wave = tid >> 6, lane = tid & 63;
    int quad = lane >> 4, nl = lane & 15;
    __shared__ __align__(16) char lds[4 * 4488];   // 4 slots x 33 pos x 136B
    const u64* in64 = (const u64*)in;

    bf16x8 wf[18];
#pragma unroll
    for (int ks = 0; ks < 18; ++ks)
        wf[ks] = *(const bf16x8*)(w3t + (wave * 16 + nl) * 576 + ks * 32 + quad * 8);
    float4 bv = *(const float4*)(bias + wave * 16 + quad * 4);

    int y0 = yh * 11;
    int rr = tid >> 7, li = tid & 127;   // 496 u64/row, 128 thr each

    {
        int y2 = 2 * y0 + rr;
        const u64* s = in64 + ((size_t)(b * 46 + y2) * 62 + 30 * xh) * 16;
        int slot = y2 & 3;
        u64 g0[4];
#pragma unroll
        for (int j = 0; j < 4; ++j) { int idx = li + j * 128; g0[j] = (idx < 496) ? s[idx] : 0ull; }
#pragma unroll
        for (int j = 0; j < 4; ++j) {
            int idx = li + j * 128;
            if (idx < 496) *(u64*)(lds + slot * 4488 + (idx >> 4) * 136 + (idx & 15) * 8) = g0[j];
        }
        int y2b = 2 * y0 + 2;
        const u64* s2 = in64 + ((size_t)(b * 46 + y2b) * 62 + 30 * xh) * 16;
        int slot2 = y2b & 3;
        u64 g1[2];
#pragma unroll
        for (int j = 0; j < 2; ++j) { int idx = tid + j * 256; g1[j] = (idx < 496) ? s2[idx] : 0ull; }
#pragma unroll
        for (int j = 0; j < 2; ++j) {
            int idx = tid + j * 256;
            if (idx < 496) *(u64*)(lds + slot2 * 4488 + (idx >> 4) * 136 + (idx & 15) * 8) = g1[j];
        }
    }
    u64 g[4];
    {
        int y2 = 2 * y0 + 3 + rr;
        const u64* s = in64 + ((size_t)(b * 46 + y2) * 62 + 30 * xh) * 16;
#pragma unroll
        for (int j = 0; j < 4; ++j) { int idx = li + j * 128; g[j] = (idx < 496) ? s[idx] : 0ull; }
    }
    __syncthreads();

    for (int yy = 0; yy < 11; ++yy) {
        int y = y0 + yy;
        f32x4 acc;
        acc[0] = bv.x; acc[1] = bv.y; acc[2] = bv.z; acc[3] = bv.w;
        int sb0 = ((2 * y) & 3) * 4488;
        int sb1 = ((2 * y + 1) & 3) * 4488;
        int sb2 = ((2 * y + 2) & 3) * 4488;
#pragma unroll
        for (int ks = 0; ks < 18; ++ks) {
            const int pos = ks >> 1, half = ks & 1;
            const int r = pos / 3, kx = pos - r * 3;
            int sb = (r == 0) ? sb0 : (r == 1) ? sb1 : sb2;
            union { u64 d[2]; bf16x8 v; } bb;
            const char* base = lds + sb + (2 * nl + kx) * 136 + half * 64 + quad * 16;
            bb.d[0] = *(const u64*)(base);
            bb.d[1] = *(const u64*)(base + 8);
            acc = __builtin_amdgcn_mfma_f32_16x16x32_bf16(wf[ks], bb.v, acc, 0, 0, 0);
        }
        if (nl < 15) {
            int xg = xh * 15 + nl;
#pragma unroll
            for (int r2 = 0; r2 < 4; ++r2)
                out[(size_t)b * 42240 + (wave * 16 + quad * 4 + r2) * 660 + y * 30 + xg] = f2bf(acc[r2]);
        }
        __syncthreads();
        {
            int row = 2 * y + 3 + rr;
            int slot = row & 3;
#pragma unroll
            for (int j = 0; j < 4; ++j) {
                int idx = li + j * 128;
                if (idx < 496) *(u64*)(lds + slot * 4488 + (idx >> 4) * 136 + (idx & 15) * 8) = g[j];
            }
        }
        if (yy < 10) {
            int y2 = 2 * y + 5 + rr;
            if (y2 > 45) y2 = 45;
            const u64* s = in64 + ((size_t)(b * 46 + y2) * 62 + 30 * xh) * 16;
#pragma unroll
            for (int j = 0; j < 4; ++j) { int idx = li + j * 128; g[j] = (idx < 496) ? s[idx] : 0ull; }
        }
        __syncthreads();
    }
}

// ---------------- fc1 v2: LDS-staged double-buffered bf16 MFMA GEMM.
__global__ __launch_bounds__(256) void k_fc1_mfma(const unsigned short* __restrict__ A,
                                                  const float* __restrict__ W,
                                                  float* __restrict__ part) {
    int kc = blockIdx.x;  // 0..59, 704 K each
    int nb = blockIdx.y;  // 0..3
    int tid = threadIdx.x;
    int wave = tid >> 6, lane = tid & 63;
    int m16 = lane & 15, quad = lane >> 4;
    __shared__ __align__(16) char lw[2][64 * 80];    // W: 64 rows x 32 bf16, stride 80
    __shared__ __align__(16) char la[2][128 * 80];   // A: 128 rows x 32 bf16, stride 80
    int k0 = kc * 704;
    int wrow = tid >> 2, wseg = tid & 3;   // 4 thr/row x 8 fp32
    const float* wsrc = W + (size_t)(nb * 64 + wrow) * 42240 + k0 + wseg * 8;
    int arow = tid >> 1, aseg = tid & 1;   // 2 thr/row x 16 bf16
    const uint4* asrc = (const uint4*)(A + (size_t)arow * 42240 + k0) + aseg * 2;
    float4 wr0 = ((const float4*)wsrc)[0];
    float4 wr1 = ((const float4*)wsrc)[1];
    uint4 ar0 = asrc[0];
    uint4 ar1 = asrc[1];
    f32x4 acc[8] = {};
    for (int ks = 0; ks < 22; ++ks) {
        int buf = ks & 1;
        uint4 wp;
        wp.x = pkbf2(wr0.x, wr0.y); wp.y = pkbf2(wr0.z, wr0.w);
        wp.z = pkbf2(wr1.x, wr1.y); wp.w = pkbf2(wr1.z, wr1.w);
        *(uint4*)(lw[buf] + wrow * 80 + wseg * 16) = wp;
        *(uint4*)(la[buf] + arow * 80 + aseg * 32) = ar0;
        *(uint4*)(la[buf] + arow * 80 + aseg * 32 + 16) = ar1;
        if (ks < 21) {
            wsrc += 32;
            asrc += 4;
            wr0 = ((const float4*)wsrc)[0];
            wr1 = ((const float4*)wsrc)[1];
            ar0 = asrc[0];
            ar1 = asrc[1];
        }
        __syncthreads();
        bf16x8 wf = *(const bf16x8*)(lw[buf] + (wave * 16 + m16) * 80 + quad * 16);
        const char* lab = la[buf] + m16 * 80 + quad * 16;
#pragma unroll
        for (int tm = 0; tm < 8; ++tm) {
            bf16x8 af = *(const bf16x8*)(lab + tm * 16 * 80);
            acc[tm] = __builtin_amdgcn_mfma_f32_16x16x32_bf16(af, wf, acc[tm], 0, 0, 0);
        }
    }
    int n = nb * 64 + wave * 16 + m16;
    float* pb = part + ((size_t)kc * 128) * 256 + n;
#pragma unroll
    for (int tm = 0; tm < 8; ++tm) {
        int row = tm * 16 + quad * 4;
#pragma unroll
        for (int r = 0; r < 4; ++r) pb[(size_t)(row + r) * 256] = acc[tm][r];
    }
}

// ---------------- fc1-combine + fc2 + lowd1 + lowd2 fused -> cnn_out2
__global__ __launch_bounds__(256) void k_head(const float* __restrict__ part,
                                              const float* __restrict__ f1b,
                                              const float* __restrict__ w2, const float* __restrict__ b2,
                                              const float* __restrict__ lw1, const float* __restrict__ lb1,
                                              const float* __restrict__ lw2, const float* __restrict__ lb2,
                                              float* __restrict__ cnn2) {
    int b = blockIdx.x, t = threadIdx.x;
    __shared__ float xa[256];
    __shared__ float xb[128];
    __shared__ float xc[128];
    __shared__ float pp[256];
    float s = f1b[t];
#pragma unroll
    for (int kc = 0; kc < 60; ++kc) s += part[((size_t)kc * 128 + b) * 256 + t];
    xa[t] = fmaxf(s, 0.f);
    __syncthreads();
    int n = t & 127, half = t >> 7;
    float acc = half ? 0.f : b2[n];
    {
        const float* w2r = w2 + n * 256 + half * 128;
        const float* xar = xa + half * 128;
#pragma unroll
        for (int k = 0; k < 128; ++k) acc = fmaf(xar[k], w2r[k], acc);
    }
    pp[t] = acc;
    __syncthreads();
    if (t < 128) xb[t] = pp[t] + pp[t + 128];
    __syncthreads();
    acc = half ? 0.f : lb1[n];
    {
        const float* l1r = lw1 + n * 128 + half * 64;
        const float* xbr = xb + half * 64;
#pragma unroll
        for (int k = 0; k < 64; ++k) acc = fmaf(xbr[k], l1r[k], acc);
    }
    pp[t] = acc;
    __syncthreads();
    if (t < 128) xc[t] = fmaxf(pp[t] + pp[t + 128], 0.f);
    __syncthreads();
    acc = half ? 0.f : lb2[n];
    {
        const float* l2r = lw2 + n * 128 + half * 64;
        const float* xcr = xc + half * 64;
#pragma unroll
        for (int k = 0; k < 64; ++k) acc = fmaf(xcr[k], l2r[k], acc);
    }
    pp[t] = acc;
    __syncthreads();
    if (t < 128) cnn2[b * 128 + t] = pp[t] + pp[t + 128];
}

// ---------------- action MLP
__global__ __launch_bounds__(256) void k_act(const float* __restrict__ ain,
                                             const float* __restrict__ w1, const float* __restrict__ b1,
                                             const float* __restrict__ w2, const float* __restrict__ b2,
                                             float* __restrict__ abuf) {
    int idx = blockIdx.x * 256 + threadIdx.x;
    float x0 = ain[idx * 2], x1 = ain[idx * 2 + 1];
    float h1[16];
#pragma unroll
    for (int i = 0; i < 16; ++i)
        h1[i] = fmaxf(fmaf(x0, w1[i * 2], fmaf(x1, w1[i * 2 + 1], b1[i])), 0.f);
#pragma unroll
    for (int i = 0; i < 16; ++i) {
        float a = b2[i];
#pragma unroll
        for (int j = 0; j < 16; ++j) a = fmaf(h1[j], w2[i * 16 + j], a);
        abuf[idx * 16 + i] = a;
    }
}

// ---------------- LSTM v3: layer-pipelined, weights k-SPLIT across wave pairs.
__global__ __launch_bounds__(512, 2) void k_lstm(const float* __restrict__ abuf,
                                                 const float* __restrict__ cnn2,
                                                 const uint32_t* __restrict__ wpk,
                                                 const float* __restrict__ bih,
                                                 const float* __restrict__ bhh,
                                                 float* __restrict__ lout) {
    int b = blockIdx.x;
    int tid = threadIdx.x;
    int w = tid >> 6, lane = tid & 63;
    int sl = w >> 1, pt = w & 1;
    __shared__ uint32_t hbuf[2][3][32];   // [step parity][producer slot][pair]
    __shared__ uint32_t h3pk[8][32];      // layer-3 h pairs (phase 0 -> 1)
    __shared__ float4 pex[8][64];         // gate-partial exchange

    uint32_t xq[8];
#pragma unroll
    for (int t = 0; t < 8; ++t) {
        float x0 = 0.f, x1 = 0.f;
        if (lane < 8) {
            const float* ap = abuf + (b * 8 + t) * 16 + 2 * lane;
            x0 = ap[0];
            x1 = ap[1];
        }
        xq[t] = pkh2(x0, x1);
    }
    float h0 = cnn2[b * 128 + 64 + lane];
    float c0 = cnn2[b * 128 + lane];
    const u32x4* wbase = (const u32x4*)wpk;

#pragma unroll
    for (int P = 0; P < 2; ++P) {
        const int L = P * 4 + sl;
        u32x4 wreg[4][8];   // [gate][quad-of-pairs] -- 128 VGPRs, static-indexed
#pragma unroll
        for (int g = 0; g < 4; ++g)
#pragma unroll
            for (int q = 0; q < 8; ++q)
                wreg[g][q] = wbase[(size_t)L * 4096 + (g * 16 + pt * 8 + q) * 64 + lane];
        float bias0 = 0.f, bias1 = 0.f, bias2 = 0.f, bias3 = 0.f;
        if (pt == 0) {
            bias0 = bih[L * 256 + lane] + bhh[L * 256 + lane];
            bias1 = bih[L * 256 + 64 + lane] + bhh[L * 256 + 64 + lane];
            bias2 = bih[L * 256 + 128 + lane] + bhh[L * 256 + 128 + lane];
            bias3 = bih[L * 256 + 192 + lane] + bhh[L * 256 + 192 + lane];
        }
        float h = h0, c = c0;
        uint32_t hpk = packpair(h0);

        for (int s = 0; s < 11; ++s) {
            bool act = (s >= sl && s < sl + 8);
            float a0 = bias0, a1 = bias1, a2 = bias2, a3 = bias3;
            if (act) {
                if (pt == 0) {
                    uint32_t xcur;
                    if (sl == 0)
                        xcur = (P == 0) ? xq[0] : h3pk[s][lane & 31];
                    else
                        xcur = hbuf[(s & 1) ^ 1][sl - 1][lane & 31];
#pragma unroll
                    for (int m = 0; m < 32; ++m) {
                        uint32_t bx = (uint32_t)__builtin_amdgcn_readlane((int)xcur, m);
                        int q = m >> 2, e = m & 3;
                        a0 = dot2(comp4v(wreg[0][q], e), bx, a0);
                        a1 = dot2(comp4v(wreg[1][q], e), bx, a1);
                        a2 = dot2(comp4v(wreg[2][q], e), bx, a2);
                        a3 = dot2(comp4v(wreg[3][q], e), bx, a3);
                    }
                } else {
#pragma unroll
                    for (int m = 0; m < 32; ++m) {
                        uint32_t bh2 = (uint32_t)__builtin_amdgcn_readlane((int)hpk, 2 * m);
                        int q = m >> 2, e = m & 3;
                        a0 = dot2(comp4v(wreg[0][q], e), bh2, a0);
                        a1 = dot2(comp4v(wreg[1][q], e), bh2, a1);
                        a2 = dot2(comp4v(wreg[2][q], e), bh2, a2);
                        a3 = dot2(comp4v(wreg[3][q], e), bh2, a3);
                    }
                }
                float4 pv;
                pv.x = a0; pv.y = a1; pv.z = a2; pv.w = a3;
                pex[w][lane] = pv;
            }
            __syncthreads();
            if (act) {
                float4 po = pex[w ^ 1][lane];
                float g0 = a0 + po.x, g1 = a1 + po.y, g2 = a2 + po.z, g3 = a3 + po.w;
                float gi = sigm(g0), gf = sigm(g1), gv = tanh_(g2), go = sigm(g3);
                c = gf * c + gi * gv;
                h = go * tanh_(c);
                hpk = packpair(h);
                if (pt == 0) {
                    if (sl < 3) {
                        if (!(lane & 1)) hbuf[s & 1][sl][lane >> 1] = hpk;
                    } else if (P == 0) {
                        if (!(lane & 1)) h3pk[s - 3][lane >> 1] = hpk;
                    } else {
                        lout[((size_t)b * 8 + (s - 3)) * 64 + lane] = h;
                    }
                }
            }
            if (P == 0 && w == 0) {  // shift x queue (static indices only)
#pragma unroll
                for (int k = 0; k < 7; ++k) xq[k] = xq[k + 1];
            }
            __syncthreads();
        }
    }
}

// ---------------- out MLP + rotation -> d_out (128,8,4)
__global__ __launch_bounds__(256) void k_out(const float* __restrict__ lout,
                                             const float* __restrict__ w1, const float* __restrict__ b1,
                                             const float* __restrict__ w2, const float* __restrict__ b2,
                                             const float* __restrict__ gt, float* __restrict__ out) {
    int idx = blockIdx.x * 256 + threadIdx.x;
    int b = idx >> 3;
    float x[64];
#pragma unroll
    for (int j = 0; j < 64; ++j) x[j] = lout[idx * 64 + j];
    float h[32];
#pragma unroll 8
    for (int i = 0; i < 32; ++i) {
        float a = b1[i];
#pragma unroll
        for (int j = 0; j < 64; ++j) a = fmaf(x[j], w1[i * 64 + j], a);
        h[i] = fmaxf(a, 0.f);
    }
    float mo[4];
#pragma unroll
    for (int i = 0; i < 4; ++i) {
        float a = b2[i];
#pragma unroll
        for (int j = 0; j < 32; ++j) a = fmaf(h[j], w2[i * 32 + j], a);
        mo[i] = a;
    }
    float yaw = gt[b * 48 + 5];
    float cy = cosf(yaw), sy = sinf(yaw);
    out[idx * 4 + 0] = fmaf(mo[0], cy, fmaf(mo[1], sy, gt[b * 48 + 1]));
    out[idx * 4 + 1] = fmaf(mo[0], -sy, fmaf(mo[1], cy, gt[b * 48 + 2]));
    out[idx * 4 + 2] = mo[2] + gt[b * 48 + 3];
    out[idx * 4 + 3] = mo[3];
}

extern "C" void kernel_launch(void* const* d_in, const int* in_sizes, int n_in,
                              void* d_out, int out_size, void* d_ws, size_t ws_size,
                              hipStream_t stream) {
    const float* img = (const float*)d_in[0];
    const float* ain = (const float*)d_in[1];
    const float* gt = (const float*)d_in[2];
    const float* c1w = (const float*)d_in[3];
    const float* c1b = (const float*)d_in[4];
    const float* c2w = (const float*)d_in[5];
    const float* c2b = (const float*)d_in[6];
    const float* c3w = (const float*)d_in[7];
    const float* c3b = (const float*)d_in[8];
    const float* f1w = (const float*)d_in[9];
    const float* f1b = (const float*)d_in[10];
    const float* f2w = (const float*)d_in[11];
    const float* f2b = (const float*)d_in[12];
    const float* l1w = (const float*)d_in[13];
    const float* l1b = (const float*)d_in[14];
    const float* l2w = (const float*)d_in[15];
    const float* l2b = (const float*)d_in[16];
    const float* a1w = (const float*)d_in[17];
    const float* a1b = (const float*)d_in[18];
    const float* a2w = (const float*)d_in[19];
    const float* a2b = (const float*)d_in[20];
    const float* wih0 = (const float*)d_in[21];
    const float* wih = (const float*)d_in[22];
    const float* whh = (const float*)d_in[23];
    const float* bihp = (const float*)d_in[24];
    const float* bhhp = (const float*)d_in[25];
    const float* o1w = (const float*)d_in[26];
    const float* o1b = (const float*)d_in[27];
    const float* o2w = (const float*)d_in[28];
    const float* o2b = (const float*)d_in[29];
    float* out = (float*)d_out;

    char* ws = (char*)d_ws;
    unsigned short* c2o = (unsigned short*)(ws + 97026048);      // 46,727,168 B
    unsigned short* c3o = (unsigned short*)(ws + 143753216);     // 10,813,440 B
    float* f1p = (float*)(ws + 154566656);                       // 60*128*256*4 = 7,864,320 B
    float* cnn2 = (float*)(ws + 163348480);
    float* abuf = (float*)(ws + 163414016);
    float* lo = (float*)(ws + 163479552);
    unsigned short* w1t = (unsigned short*)(ws + 163741696);     // 8,192 B
    unsigned short* w2t = (unsigned short*)(ws + 163749888);     // 36,864 B
    unsigned short* w3t = (unsigned short*)(ws + 163786752);     // 73,728 B
    uint32_t* wpk = (uint32_t*)(ws + 163860480);                 // 524,288 B

    k_wprep<<<232, 256, 0, stream>>>(c1w, c2w, c3w, w1t, w2t, w3t);
    k_wprep_lstm<<<128, 256, 0, stream>>>(wih0, wih, whh, wpk);
    k_conv12<<<dim3(128, 2, 4), 256, 0, stream>>>(img, w1t, c1b, w2t, c2b, c2o);
    k_conv3m<<<dim3(128, 2, 2), 256, 0, stream>>>(c2o, w3t, c3b, c3o);
    k_fc1_mfma<<<dim3(60, 4), 256, 0, stream>>>(c3o, f1w, f1p);
    k_head<<<128, 256, 0, stream>>>(f1p, f1b, f2w, f2b, l1w, l1b, l2w, l2b, cnn2);
    k_act<<<4, 256, 0, stream>>>(ain, a1w, a1b, a2w, a2b, abuf);
    k_lstm<<<128, 512, 0, stream>>>(abuf, cnn2, wpk, bihp, bhhp, lo);
    k_out<<<4, 256, 0, stream>>>(lo, o1w, o1b, o2w, o2b, gt, out);
}

// Round 9
// 319.034 us; speedup vs baseline: 1.4438x; 1.0250x over previous
//
#include <hip/hip_runtime.h>
#include <cstdint>

#define DEV __device__ __forceinline__

typedef __attribute__((ext_vector_type(8))) short bf16x8;
typedef __attribute__((ext_vector_type(4))) float f32x4;
typedef __attribute__((ext_vector_type(2))) __fp16 h2t;
typedef __attribute__((ext_vector_type(4))) unsigned int u32x4;
typedef unsigned long long u64;

DEV unsigned short f2bf(float f) {
    unsigned u = __float_as_uint(f);
    unsigned r = u + 0x7fffu + ((u >> 16) & 1u);
    return (unsigned short)(r >> 16);
}
DEV uint32_t pkbf2(float a, float b) {
    return (uint32_t)f2bf(a) | ((uint32_t)f2bf(b) << 16);
}
DEV uint32_t cvtpk(float lo, float hi) {
    uint32_t r;
    asm("v_cvt_pk_bf16_f32 %0, %1, %2" : "=v"(r) : "v"(lo), "v"(hi));
    return r;
}
DEV uint32_t pkh2(float a, float b) {
    h2t p = __builtin_amdgcn_cvt_pkrtz(a, b);
    union { h2t h; uint32_t u; } c;
    c.h = p;
    return c.u;
}
DEV float dot2(uint32_t w, uint32_t x, float acc) {
    union { uint32_t u; h2t h; } a, b;
    a.u = w; b.u = x;
    return __builtin_amdgcn_fdot2(a.h, b.h, acc, false);
}
DEV float sigm(float x) { return __builtin_amdgcn_rcpf(1.f + __expf(-x)); }
DEV float tanh_(float x) { return fmaf(2.f, sigm(2.f * x), -1.f); }
DEV uint32_t packpair(float h) {
    float hs = __int_as_float(__builtin_amdgcn_ds_swizzle(__float_as_int(h), 0x041F));
    return pkh2(h, hs);
}
DEV uint32_t comp4v(u32x4 v, int e) {
    return (e == 0) ? v[0] : (e == 1) ? v[1] : (e == 2) ? v[2] : v[3];
}
DEV u64 pack4bf(float a, float b, float c, float d) {
    unsigned lo = (unsigned)f2bf(a) | ((unsigned)f2bf(b) << 16);
    unsigned hi = (unsigned)f2bf(c) | ((unsigned)f2bf(d) << 16);
    return (u64)lo | ((u64)hi << 32);
}

// ---------------- weight prep (bf16, K-chunk order)
__global__ __launch_bounds__(256) void k_wprep(const float* __restrict__ w1,
                                               const float* __restrict__ w2,
                                               const float* __restrict__ w3,
                                               unsigned short* __restrict__ w1t,
                                               unsigned short* __restrict__ w2t,
                                               unsigned short* __restrict__ w3t) {
    int i = blockIdx.x * 256 + threadIdx.x;
    if (i < 32 * 128) {
        int oc = i >> 7, k = i & 127;
        int cc = k >> 3, u = (k >> 2) & 1, c = k & 3;
        int r = cc / 3, kx = 2 * (cc - 3 * r) + u;
        w1t[i] = (cc < 15 && kx < 5 && c < 3) ? f2bf(w1[oc * 75 + c * 25 + r * 5 + kx])
                                              : (unsigned short)0;
    } else if (i < 32 * 128 + 64 * 288) {
        int j = i - 32 * 128;
        int oc = j / 288, k = j - oc * 288;
        int pos = k >> 5, c = k & 31;
        int ocr = ((c >> 2) & 1) * 16 + (c >> 3) * 4 + (c & 3);  // inverse of conv1 store perm
        w2t[j] = f2bf(w2[oc * 288 + ocr * 9 + pos]);
    } else if (i < 32 * 128 + 64 * 288 + 64 * 576) {
        int j = i - 32 * 128 - 64 * 288;
        int oc = j / 576, k = j - oc * 576;
        int pos = k >> 6, c = k & 63;
        w3t[j] = f2bf(w3[oc * 576 + c * 9 + pos]);
    }
}

// ---------------- LSTM weight prep: f16 pairs (see k_lstm)
__global__ __launch_bounds__(256) void k_wprep_lstm(const float* __restrict__ Wih0,
                                                    const float* __restrict__ Wih,
                                                    const float* __restrict__ Whh,
                                                    uint32_t* __restrict__ wpk) {
    int idx = blockIdx.x * 256 + threadIdx.x;  // 0..32767
    int lane = idx & 63;
    int j = (idx >> 6) & 63;
    int l = idx >> 12;
    int g = j >> 4, q = j & 15;
    int r = g * 64 + lane;
    uint32_t ov[4];
#pragma unroll
    for (int e = 0; e < 4; ++e) {
        int p = q * 4 + e;
        float w0, w1;
        if (p < 32) {
            int k0 = 2 * p;
            if (l == 0) {
                w0 = (k0 < 16) ? Wih0[r * 16 + k0] : 0.f;
                w1 = (k0 + 1 < 16) ? Wih0[r * 16 + k0 + 1] : 0.f;
            } else {
                const float* base = Wih + ((size_t)(l - 1) * 256 + r) * 64;
                w0 = base[k0];
                w1 = base[k0 + 1];
            }
        } else {
            int k0 = 2 * (p - 32);
            const float* base = Whh + ((size_t)l * 256 + r) * 64;
            w0 = base[k0];
            w1 = base[k0 + 1];
        }
        ov[e] = pkh2(w0, w1);
    }
    uint4 v;
    v.x = ov[0]; v.y = ov[1]; v.z = ov[2]; v.w = ov[3];
    ((uint4*)wpk)[idx] = v;
}

// ---------------- FUSED conv1+conv2 v3: 2-deep prefetch, pow2 rings, cvt_pk packs.
// Grid (128 b, 2 xh, 2 ys) = 512 blocks; strips of 23 conv2 rows.
// img ring: 16 slots, slot = row & 15 (live window 4y+8..4y+19 = 12 rows).
// conv1 ring: 8 slots, slot = R1 & 7 (live rows 2y..2y+5).
// Pipeline per iter t (y = y0+t): write bufW (rows 4y+16..19, loaded at t-1) ->
// img ring; issue loads rows 4y+20..23 -> bufL; conv1 rows 2y+4,2y+5 (reads img
// 4y+8..15, written at t-2/t-1); conv2 row y (reads conv1 ring 2y..2y+2);
// ONE barrier. Load->LDS-write distance = 1 full iteration -> HBM latency hidden.
// All bf16 packing via v_cvt_pk_bf16_f32 (1 inst per pair, same RNE as f2bf).
__global__ __launch_bounds__(256, 2) void k_conv12(const float* __restrict__ img,
                                                   const unsigned short* __restrict__ w1t,
                                                   const float* __restrict__ b1,
                                                   const unsigned short* __restrict__ w2t,
                                                   const float* __restrict__ b2,
                                                   unsigned short* __restrict__ out) {
    int b = blockIdx.x, xh = blockIdx.y, ys = blockIdx.z;
    int tid = threadIdx.x;
    int w = tid >> 6, lane = tid & 63;
    int quad = lane >> 4, nl = lane & 15;
    int nh = w >> 1, rw = w & 1;   // conv1: x-half, row-parity; conv2: x-half, oc-half
    __shared__ __align__(16) char ldsI[16 * 2080];
    __shared__ __align__(16) char ldsC[8 * 4536];
    const float* ib = img + (size_t)b * 3 * 192 * 256;
    int y0 = ys * 23;
    int imx = 124 * xh + tid;
    bool stg = tid < 132;

    bf16x8 wa1[4], wb1[4];
#pragma unroll
    for (int ks = 0; ks < 4; ++ks) {
        wa1[ks] = *(const bf16x8*)(w1t + nl * 128 + ks * 32 + quad * 8);
        wb1[ks] = *(const bf16x8*)(w1t + (16 + nl) * 128 + ks * 32 + quad * 8);
    }
    bf16x8 wa2[9], wb2[9];
#pragma unroll
    for (int ks = 0; ks < 9; ++ks) {
        wa2[ks] = *(const bf16x8*)(w2t + ((rw * 2 + 0) * 16 + nl) * 288 + ks * 32 + quad * 8);
        wb2[ks] = *(const bf16x8*)(w2t + ((rw * 2 + 1) * 16 + nl) * 288 + ks * 32 + quad * 8);
    }
    float4 c1b0 = *(const float4*)(b1 + quad * 4);
    float4 c1b1 = *(const float4*)(b1 + 16 + quad * 4);
    float4 c2b0 = *(const float4*)(b2 + (rw * 2 + 0) * 16 + quad * 4);
    float4 c2b1 = *(const float4*)(b2 + (rw * 2 + 1) * 16 + quad * 4);

    auto ldimg = [&](int row, float& f0, float& f1, float& f2) {
        if (row > 191) row = 191;
        const float* ip = ib + row * 256 + imx;
        f0 = ip[0];
        f1 = ip[192 * 256];
        f2 = ip[2 * 192 * 256];
    };
    auto stimgS = [&](int row, float f0, float f1, float f2) {
        uint32_t lo = cvtpk(f0, f1);
        *(u64*)(ldsI + (row & 15) * 2080 + imx * 8) = (u64)lo | ((u64)cvtpk(f2, 0.f) << 32);
    };
    // compute one conv1 row R1; reads img rows 2R1..2R1+5 (slot = row & 15),
    // writes conv1 ring slot R1 & 7.
    auto conv1row = [&](int R1) {
        f32x4 a00, a01;
        a00[0] = c1b0.x; a00[1] = c1b0.y; a00[2] = c1b0.z; a00[3] = c1b0.w;
        a01[0] = c1b1.x; a01[1] = c1b1.y; a01[2] = c1b1.z; a01[3] = c1b1.w;
        f32x4 a10 = a00, a11 = a01;
        int base2 = 2 * R1;
#pragma unroll
        for (int ks = 0; ks < 4; ++ks) {
            int cc = ks * 4 + quad;
            int r = cc / 3, kxp = cc - 3 * r;
            int rb = ((base2 + r) & 15) * 2080 + 992 * xh + 512 * nh + kxp * 16 + nl * 16;
            bf16x8 v0 = *(const bf16x8*)(ldsI + rb);
            bf16x8 v1 = *(const bf16x8*)(ldsI + rb + 256);
            a00 = __builtin_amdgcn_mfma_f32_16x16x32_bf16(wa1[ks], v0, a00, 0, 0, 0);
            a01 = __builtin_amdgcn_mfma_f32_16x16x32_bf16(wb1[ks], v0, a01, 0, 0, 0);
            a10 = __builtin_amdgcn_mfma_f32_16x16x32_bf16(wa1[ks], v1, a10, 0, 0, 0);
            a11 = __builtin_amdgcn_mfma_f32_16x16x32_bf16(wb1[ks], v1, a11, 0, 0, 0);
        }
        int cs = (R1 & 7) * 4536;
        int xl0 = nh * 32 + nl;
        {
            uint4 st;
            st.x = cvtpk(fmaxf(a00[0], 0.f), fmaxf(a00[1], 0.f));
            st.y = cvtpk(fmaxf(a00[2], 0.f), fmaxf(a00[3], 0.f));
            st.z = cvtpk(fmaxf(a01[0], 0.f), fmaxf(a01[1], 0.f));
            st.w = cvtpk(fmaxf(a01[2], 0.f), fmaxf(a01[3], 0.f));
            *(uint4*)(ldsC + cs + xl0 * 72 + quad * 16) = st;
        }
        int xl1 = xl0 + 16;
        if (xl1 < 63) {
            uint4 st;
            st.x = cvtpk(fmaxf(a10[0], 0.f), fmaxf(a10[1], 0.f));
            st.y = cvtpk(fmaxf(a10[2], 0.f), fmaxf(a10[3], 0.f));
            st.z = cvtpk(fmaxf(a11[0], 0.f), fmaxf(a11[1], 0.f));
            st.w = cvtpk(fmaxf(a11[2], 0.f), fmaxf(a11[3], 0.f));
            *(uint4*)(ldsC + cs + xl1 * 72 + quad * 16) = st;
        }
    };

    float A0[4], A1[4], A2[4], B0[4], B1[4], B2[4];

    // ---- prologue: img rows 4y0..4y0+15 -> ring; bufA = rows 4y0+16..19 ----
    {
        float p0[8], p1[8], p2[8];
        if (stg) {
#pragma unroll
            for (int r = 0; r < 8; ++r) ldimg(4 * y0 + r, p0[r], p1[r], p2[r]);
        }
        __builtin_amdgcn_sched_barrier(0);
        if (stg) {
#pragma unroll
            for (int r = 0; r < 8; ++r) stimgS(4 * y0 + r, p0[r], p1[r], p2[r]);
#pragma unroll
            for (int r = 0; r < 8; ++r) ldimg(4 * y0 + 8 + r, p0[r], p1[r], p2[r]);
        }
        __builtin_amdgcn_sched_barrier(0);
        if (stg) {
#pragma unroll
            for (int r = 0; r < 8; ++r) stimgS(4 * y0 + 8 + r, p0[r], p1[r], p2[r]);
#pragma unroll
            for (int j = 0; j < 4; ++j) ldimg(4 * y0 + 16 + j, A0[j], A1[j], A2[j]);
        }
    }
    __syncthreads();
    // conv1 rows 2y0..2y0+3 into the conv1 ring
    conv1row(2 * y0 + rw);
    conv1row(2 * y0 + 2 + rw);
    __syncthreads();

    // one pipelined iteration: write bufW (rows 4y+16..19), load bufL (4y+20..23),
    // conv1 rows 2y+4/2y+5, conv2 row y, barrier.
    auto iter = [&](int y, float (&W0)[4], float (&W1)[4], float (&W2)[4],
                    float (&L0)[4], float (&L1)[4], float (&L2)[4]) {
        if (stg) {
#pragma unroll
            for (int j = 0; j < 4; ++j) stimgS(4 * y + 16 + j, W0[j], W1[j], W2[j]);
#pragma unroll
            for (int j = 0; j < 4; ++j) ldimg(4 * y + 20 + j, L0[j], L1[j], L2[j]);
        }
        int R1 = 2 * y + 4 + rw;
        if (R1 <= 93) conv1row(R1);
        {
            f32x4 acc0, acc1;
            acc0[0] = c2b0.x; acc0[1] = c2b0.y; acc0[2] = c2b0.z; acc0[3] = c2b0.w;
            acc1[0] = c2b1.x; acc1[1] = c2b1.y; acc1[2] = c2b1.z; acc1[3] = c2b1.w;
            int xl = nh * 16 + nl;
#pragma unroll
            for (int ks = 0; ks < 9; ++ks) {
                int r = ks / 3, kx = ks - r * 3;
                const char* base = ldsC + ((2 * y + r) & 7) * 4536 + (2 * xl + kx) * 72 + quad * 16;
                union { u64 d[2]; bf16x8 v; } bb;
                bb.d[0] = *(const u64*)(base);
                bb.d[1] = *(const u64*)(base + 8);
                acc0 = __builtin_amdgcn_mfma_f32_16x16x32_bf16(wa2[ks], bb.v, acc0, 0, 0, 0);
                acc1 = __builtin_amdgcn_mfma_f32_16x16x32_bf16(wb2[ks], bb.v, acc1, 0, 0, 0);
            }
            if (xl < 31) {
                int xg = xh * 31 + xl;
                u64 q0 = (u64)cvtpk(fmaxf(acc0[0], 0.f), fmaxf(acc0[1], 0.f)) |
                         ((u64)cvtpk(fmaxf(acc0[2], 0.f), fmaxf(acc0[3], 0.f)) << 32);
                u64 q1 = (u64)cvtpk(fmaxf(acc1[0], 0.f), fmaxf(acc1[1], 0.f)) |
                         ((u64)cvtpk(fmaxf(acc1[2], 0.f), fmaxf(acc1[3], 0.f)) << 32);
                *(u64*)(out + (((size_t)b * 46 + y) * 62 + xg) * 64 + (rw * 2 + 0) * 16 + quad * 4) = q0;
                *(u64*)(out + (((size_t)b * 46 + y) * 62 + xg) * 64 + (rw * 2 + 1) * 16 + quad * 4) = q1;
            }
        }
        __syncthreads();
    };

    for (int t = 0; t + 1 < 23; t += 2) {
        iter(y0 + t, A0, A1, A2, B0, B1, B2);
        iter(y0 + t + 1, B0, B1, B2, A0, A1, A2);
    }
    iter(y0 + 22, A0, A1, A2, B0, B1, B2);
}

// ---------------- conv3 v2: y-strip kernel. Grid (128 b, 2 xh, 2 yh), 4 waves.
__global__ __launch_bounds__(256, 1) void k_conv3m(const unsigned short* __restrict__ in,
                                                   const unsigned short* __restrict__ w3t,
                                                   const float* __restrict__ bias,
                                                   unsigned short* __restrict__ out) {
    int b = blockIdx.x, xh = blockIdx.y, yh = blockIdx.z;
    int tid = threadIdx.x;
    int wave = tid >> 6, lane = tid & 63;
    int quad = lane >> 4, nl = lane & 15;
    __shared__ __align__(16) char lds[4 * 4488];   // 4 slots x 33 pos x 136B
    const u64* in64 = (const u64*)in;

    bf16x8 wf[18];
#pragma unroll
    for (int ks = 0; ks < 18; ++ks)
        wf[ks] = *(const bf16x8*)(w3t + (wave * 16 + nl) * 576 + ks * 32 + quad * 8);
    float4 bv = *(const float4*)(bias + wave * 16 + quad * 4);

    int y0 = yh * 11;
    int rr = tid >> 7, li = tid & 127;   // 496 u64/row, 128 thr each

    {
        int y2 = 2 * y0 + rr;
        const u64* s = in64 + ((size_t)(b * 46 + y2) * 62 + 30 * xh) * 16;
        int slot = y2 & 3;
        u64 g0[4];
#pragma unroll
        for (int j = 0; j < 4; ++j) { int idx = li + j * 128; g0[j] = (idx < 496) ? s[idx] : 0ull; }
#pragma unroll
        for (int j = 0; j < 4; ++j) {
            int idx = li + j * 128;
            if (idx < 496) *(u64*)(lds + slot * 4488 + (idx >> 4) * 136 + (idx & 15) * 8) = g0[j];
        }
        int y2b = 2 * y0 + 2;
        const u64* s2 = in64 + ((size_t)(b * 46 + y2b) * 62 + 30 * xh) * 16;
        int slot2 = y2b & 3;
        u64 g1[2];
#pragma unroll
        for (int j = 0; j < 2; ++j) { int idx = tid + j * 256; g1[j] = (idx < 496) ? s2[idx] : 0ull; }
#pragma unroll
        for (int j = 0; j < 2; ++j) {
            int idx = tid + j * 256;
            if (idx < 496) *(u64*)(lds + slot2 * 4488 + (idx >> 4) * 136 + (idx & 15) * 8) = g1[j];
        }
    }
    u64 g[4];
    {
        int y2 = 2 * y0 + 3 + rr;
        const u64* s = in64 + ((size_t)(b * 46 + y2) * 62 + 30 * xh) * 16;
#pragma unroll
        for (int j = 0; j < 4; ++j) { int idx = li + j * 128; g[j] = (idx < 496) ? s[idx] : 0ull; }
    }
    __syncthreads();

    for (int yy = 0; yy < 11; ++yy) {
        int y = y0 + yy;
        f32x4 acc;
        acc[0] = bv.x; acc[1] = bv.y; acc[2] = bv.z; acc[3] = bv.w;
        int sb0 = ((2 * y) & 3) * 4488;
        int sb1 = ((2 * y + 1) & 3) * 4488;
        int sb2 = ((2 * y + 2) & 3) * 4488;
#pragma unroll
        for (int ks = 0; ks < 18; ++ks) {
            const int pos = ks >> 1, half = ks & 1;
            const int r = pos / 3, kx = pos - r * 3;
            int sb = (r == 0) ? sb0 : (r == 1) ? sb1 : sb2;
            union { u64 d[2]; bf16x8 v; } bb;
            const char* base = lds + sb + (2 * nl + kx) * 136 + half * 64 + quad * 16;
            bb.d[0] = *(const u64*)(base);
            bb.d[1] = *(const u64*)(base + 8);
            acc = __builtin_amdgcn_mfma_f32_16x16x32_bf16(wf[ks], bb.v, acc, 0, 0, 0);
        }
        if (nl < 15) {
            int xg = xh * 15 + nl;
#pragma unroll
            for (int r2 = 0; r2 < 4; ++r2)
                out[(size_t)b * 42240 + (wave * 16 + quad * 4 + r2) * 660 + y * 30 + xg] = f2bf(acc[r2]);
        }
        __syncthreads();
        {
            int row = 2 * y + 3 + rr;
            int slot = row & 3;
#pragma unroll
            for (int j = 0; j < 4; ++j) {
                int idx = li + j * 128;
                if (idx < 496) *(u64*)(lds + slot * 4488 + (idx >> 4) * 136 + (idx & 15) * 8) = g[j];
            }
        }
        if (yy < 10) {
            int y2 = 2 * y + 5 + rr;
            if (y2 > 45) y2 = 45;
            const u64* s = in64 + ((size_t)(b * 46 + y2) * 62 + 30 * xh) * 16;
#pragma unroll
            for (int j = 0; j < 4; ++j) { int idx = li + j * 128; g[j] = (idx < 496) ? s[idx] : 0ull; }
        }
        __syncthreads();
    }
}

// ---------------- fc1 v2: LDS-staged double-buffered bf16 MFMA GEMM.
__global__ __launch_bounds__(256) void k_fc1_mfma(const unsigned short* __restrict__ A,
                                                  const float* __restrict__ W,
                                                  float* __restrict__ part) {
    int kc = blockIdx.x;  // 0..59, 704 K each
    int nb = blockIdx.y;  // 0..3
    int tid = threadIdx.x;
    int wave = tid >> 6, lane = tid & 63;
    int m16 = lane & 15, quad = lane >> 4;
    __shared__ __align__(16) char lw[2][64 * 80];    // W: 64 rows x 32 bf16, stride 80
    __shared__ __align__(16) char la[2][128 * 80];   // A: 128 rows x 32 bf16, stride 80
    int k0 = kc * 704;
    int wrow = tid >> 2, wseg = tid & 3;   // 4 thr/row x 8 fp32
    const float* wsrc = W + (size_t)(nb * 64 + wrow) * 42240 + k0 + wseg * 8;
    int arow = tid >> 1, aseg = tid & 1;   // 2 thr/row x 16 bf16
    const uint4* asrc = (const uint4*)(A + (size_t)arow * 42240 + k0) + aseg * 2;
    float4 wr0 = ((const float4*)wsrc)[0];
    float4 wr1 = ((const float4*)wsrc)[1];
    uint4 ar0 = asrc[0];
    uint4 ar1 = asrc[1];
    f32x4 acc[8] = {};
    for (int ks = 0; ks < 22; ++ks) {
        int buf = ks & 1;
        uint4 wp;
        wp.x = pkbf2(wr0.x, wr0.y); wp.y = pkbf2(wr0.z, wr0.w);
        wp.z = pkbf2(wr1.x, wr1.y); wp.w = pkbf2(wr1.z, wr1.w);
        *(uint4*)(lw[buf] + wrow * 80 + wseg * 16) = wp;
        *(uint4*)(la[buf] + arow * 80 + aseg * 32) = ar0;
        *(uint4*)(la[buf] + arow * 80 + aseg * 32 + 16) = ar1;
        if (ks < 21) {
            wsrc += 32;
            asrc += 4;
            wr0 = ((const float4*)wsrc)[0];
            wr1 = ((const float4*)wsrc)[1];
            ar0 = asrc[0];
            ar1 = asrc[1];
        }
        __syncthreads();
        bf16x8 wf = *(const bf16x8*)(lw[buf] + (wave * 16 + m16) * 80 + quad * 16);
        const char* lab = la[buf] + m16 * 80 + quad * 16;
#pragma unroll
        for (int tm = 0; tm < 8; ++tm) {
            bf16x8 af = *(const bf16x8*)(lab + tm * 16 * 80);
            acc[tm] = __builtin_amdgcn_mfma_f32_16x16x32_bf16(af, wf, acc[tm], 0, 0, 0);
        }
    }
    int n = nb * 64 + wave * 16 + m16;
    float* pb = part + ((size_t)kc * 128) * 256 + n;
#pragma unroll
    for (int tm = 0; tm < 8; ++tm) {
        int row = tm * 16 + quad * 4;
#pragma unroll
        for (int r = 0; r < 4; ++r) pb[(size_t)(row + r) * 256] = acc[tm][r];
    }
}

// ---------------- fc1-combine + fc2 + lowd1 + lowd2 fused -> cnn_out2
__global__ __launch_bounds__(256) void k_head(const float* __restrict__ part,
                                              const float* __restrict__ f1b,
                                              const float* __restrict__ w2, const float* __restrict__ b2,
                                              const float* __restrict__ lw1, const float* __restrict__ lb1,
                                              const float* __restrict__ lw2, const float* __restrict__ lb2,
                                              float* __restrict__ cnn2) {
    int b = blockIdx.x, t = threadIdx.x;
    __shared__ float xa[256];
    __shared__ float xb[128];
    __shared__ float xc[128];
    __shared__ float pp[256];
    float s = f1b[t];
#pragma unroll
    for (int kc = 0; kc < 60; ++kc) s += part[((size_t)kc * 128 + b) * 256 + t];
    xa[t] = fmaxf(s, 0.f);
    __syncthreads();
    int n = t & 127, half = t >> 7;
    float acc = half ? 0.f : b2[n];
    {
        const float* w2r = w2 + n * 256 + half * 128;
        const float* xar = xa + half * 128;
#pragma unroll
        for (int k = 0; k < 128; ++k) acc = fmaf(xar[k], w2r[k], acc);
    }
    pp[t] = acc;
    __syncthreads();
    if (t < 128) xb[t] = pp[t] + pp[t + 128];
    __syncthreads();
    acc = half ? 0.f : lb1[n];
    {
        const float* l1r = lw1 + n * 128 + half * 64;
        const float* xbr = xb + half * 64;
#pragma unroll
        for (int k = 0; k < 64; ++k) acc = fmaf(xbr[k], l1r[k], acc);
    }
    pp[t] = acc;
    __syncthreads();
    if (t < 128) xc[t] = fmaxf(pp[t] + pp[t + 128], 0.f);
    __syncthreads();
    acc = half ? 0.f : lb2[n];
    {
        const float* l2r = lw2 + n * 128 + half * 64;
        const float* xcr = xc + half * 64;
#pragma unroll
        for (int k = 0; k < 64; ++k) acc = fmaf(xcr[k], l2r[k], acc);
    }
    pp[t] = acc;
    __syncthreads();
    if (t < 128) cnn2[b * 128 + t] = pp[t] + pp[t + 128];
}

// ---------------- action MLP
__global__ __launch_bounds__(256) void k_act(const float* __restrict__ ain,
                                             const float* __restrict__ w1, const float* __restrict__ b1,
                                             const float* __restrict__ w2, const float* __restrict__ b2,
                                             float* __restrict__ abuf) {
    int idx = blockIdx.x * 256 + threadIdx.x;
    float x0 = ain[idx * 2], x1 = ain[idx * 2 + 1];
    float h1[16];
#pragma unroll
    for (int i = 0; i < 16; ++i)
        h1[i] = fmaxf(fmaf(x0, w1[i * 2], fmaf(x1, w1[i * 2 + 1], b1[i])), 0.f);
#pragma unroll
    for (int i = 0; i < 16; ++i) {
        float a = b2[i];
#pragma unroll
        for (int j = 0; j < 16; ++j) a = fmaf(h1[j], w2[i * 16 + j], a);
        abuf[idx * 16 + i] = a;
    }
}

// ---------------- LSTM v3: layer-pipelined, weights k-SPLIT across wave pairs.
__global__ __launch_bounds__(512, 2) void k_lstm(const float* __restrict__ abuf,
                                                 const float* __restrict__ cnn2,
                                                 const uint32_t* __restrict__ wpk,
                                                 const float* __restrict__ bih,
                                                 const float* __restrict__ bhh,
                                                 float* __restrict__ lout) {
    int b = blockIdx.x;
    int tid = threadIdx.x;
    int w = tid >> 6, lane = tid & 63;
    int sl = w >> 1, pt = w & 1;
    __shared__ uint32_t hbuf[2][3][32];   // [step parity][producer slot][pair]
    __shared__ uint32_t h3pk[8][32];      // layer-3 h pairs (phase 0 -> 1)
    __shared__ float4 pex[8][64];         // gate-partial exchange

    uint32_t xq[8];
#pragma unroll
    for (int t = 0; t < 8; ++t) {
        float x0 = 0.f, x1 = 0.f;
        if (lane < 8) {
            const float* ap = abuf + (b * 8 + t) * 16 + 2 * lane;
            x0 = ap[0];
            x1 = ap[1];
        }
        xq[t] = pkh2(x0, x1);
    }
    float h0 = cnn2[b * 128 + 64 + lane];
    float c0 = cnn2[b * 128 + lane];
    const u32x4* wbase = (const u32x4*)wpk;

#pragma unroll
    for (int P = 0; P < 2; ++P) {
        const int L = P * 4 + sl;
        u32x4 wreg[4][8];   // [gate][quad-of-pairs] -- 128 VGPRs, static-indexed
#pragma unroll
        for (int g = 0; g < 4; ++g)
#pragma unroll
            for (int q = 0; q < 8; ++q)
                wreg[g][q] = wbase[(size_t)L * 4096 + (g * 16 + pt * 8 + q) * 64 + lane];
        float bias0 = 0.f, bias1 = 0.f, bias2 = 0.f, bias3 = 0.f;
        if (pt == 0) {
            bias0 = bih[L * 256 + lane] + bhh[L * 256 + lane];
            bias1 = bih[L * 256 + 64 + lane] + bhh[L * 256 + 64 + lane];
            bias2 = bih[L * 256 + 128 + lane] + bhh[L * 256 + 128 + lane];
            bias3 = bih[L * 256 + 192 + lane] + bhh[L * 256 + 192 + lane];
        }
        float h = h0, c = c0;
        uint32_t hpk = packpair(h0);

        for (int s = 0; s < 11; ++s) {
            bool act = (s >= sl && s < sl + 8);
            float a0 = bias0, a1 = bias1, a2 = bias2, a3 = bias3;
            if (act) {
                if (pt == 0) {
                    uint32_t xcur;
                    if (sl == 0)
                        xcur = (P == 0) ? xq[0] : h3pk[s][lane & 31];
                    else
                        xcur = hbuf[(s & 1) ^ 1][sl - 1][lane & 31];
#pragma unroll
                    for (int m = 0; m < 32; ++m) {
                        uint32_t bx = (uint32_t)__builtin_amdgcn_readlane((int)xcur, m);
                        int q = m >> 2, e = m & 3;
                        a0 = dot2(comp4v(wreg[0][q], e), bx, a0);
                        a1 = dot2(comp4v(wreg[1][q], e), bx, a1);
                        a2 = dot2(comp4v(wreg[2][q], e), bx, a2);
                        a3 = dot2(comp4v(wreg[3][q], e), bx, a3);
                    }
                } else {
#pragma unroll
                    for (int m = 0; m < 32; ++m) {
                        uint32_t bh2 = (uint32_t)__builtin_amdgcn_readlane((int)hpk, 2 * m);
                        int q = m >> 2, e = m & 3;
                        a0 = dot2(comp4v(wreg[0][q], e), bh2, a0);
                        a1 = dot2(comp4v(wreg[1][q], e), bh2, a1);
                        a2 = dot2(comp4v(wreg[2][q], e), bh2, a2);
                        a3 = dot2(comp4v(wreg[3][q], e), bh2, a3);
                    }
                }
                float4 pv;
                pv.x = a0; pv.y = a1; pv.z = a2; pv.w = a3;
                pex[w][lane] = pv;
            }
            __syncthreads();
            if (act) {
                float4 po = pex[w ^ 1][lane];
                float g0 = a0 + po.x, g1 = a1 + po.y, g2 = a2 + po.z, g3 = a3 + po.w;
                float gi = sigm(g0), gf = sigm(g1), gv = tanh_(g2), go = sigm(g3);
                c = gf * c + gi * gv;
                h = go * tanh_(c);
                hpk = packpair(h);
                if (pt == 0) {
                    if (sl < 3) {
                        if (!(lane & 1)) hbuf[s & 1][sl][lane >> 1] = hpk;
                    } else if (P == 0) {
                        if (!(lane & 1)) h3pk[s - 3][lane >> 1] = hpk;
                    } else {
                        lout[((size_t)b * 8 + (s - 3)) * 64 + lane] = h;
                    }
                }
            }
            if (P == 0 && w == 0) {  // shift x queue (static indices only)
#pragma unroll
                for (int k = 0; k < 7; ++k) xq[k] = xq[k + 1];
            }
            __syncthreads();
        }
    }
}

// ---------------- out MLP + rotation -> d_out (128,8,4)
__global__ __launch_bounds__(256) void k_out(const float* __restrict__ lout,
                                             const float* __restrict__ w1, const float* __restrict__ b1,
                                             const float* __restrict__ w2, const float* __restrict__ b2,
                                             const float* __restrict__ gt, float* __restrict__ out) {
    int idx = blockIdx.x * 256 + threadIdx.x;
    int b = idx >> 3;
    float x[64];
#pragma unroll
    for (int j = 0; j < 64; ++j) x[j] = lout[idx * 64 + j];
    float h[32];
#pragma unroll 8
    for (int i = 0; i < 32; ++i) {
        float a = b1[i];
#pragma unroll
        for (int j = 0; j < 64; ++j) a = fmaf(x[j], w1[i * 64 + j], a);
        h[i] = fmaxf(a, 0.f);
    }
    float mo[4];
#pragma unroll
    for (int i = 0; i < 4; ++i) {
        float a = b2[i];
#pragma unroll
        for (int j = 0; j < 32; ++j) a = fmaf(h[j], w2[i * 32 + j], a);
        mo[i] = a;
    }
    float yaw = gt[b * 48 + 5];
    float cy = cosf(yaw), sy = sinf(yaw);
    out[idx * 4 + 0] = fmaf(mo[0], cy, fmaf(mo[1], sy, gt[b * 48 + 1]));
    out[idx * 4 + 1] = fmaf(mo[0], -sy, fmaf(mo[1], cy, gt[b * 48 + 2]));
    out[idx * 4 + 2] = mo[2] + gt[b * 48 + 3];
    out[idx * 4 + 3] = mo[3];
}

extern "C" void kernel_launch(void* const* d_in, const int* in_sizes, int n_in,
                              void* d_out, int out_size, void* d_ws, size_t ws_size,
                              hipStream_t stream) {
    const float* img = (const float*)d_in[0];
    const float* ain = (const float*)d_in[1];
    const float* gt = (const float*)d_in[2];
    const float* c1w = (const float*)d_in[3];
    const float* c1b = (const float*)d_in[4];
    const float* c2w = (const float*)d_in[5];
    const float* c2b = (const float*)d_in[6];
    const float* c3w = (const float*)d_in[7];
    const float* c3b = (const float*)d_in[8];
    const float* f1w = (const float*)d_in[9];
    const float* f1b = (const float*)d_in[10];
    const float* f2w = (const float*)d_in[11];
    const float* f2b = (const float*)d_in[12];
    const float* l1w = (const float*)d_in[13];
    const float* l1b = (const float*)d_in[14];
    const float* l2w = (const float*)d_in[15];
    const float* l2b = (const float*)d_in[16];
    const float* a1w = (const float*)d_in[17];
    const float* a1b = (const float*)d_in[18];
    const float* a2w = (const float*)d_in[19];
    const float* a2b = (const float*)d_in[20];
    const float* wih0 = (const float*)d_in[21];
    const float* wih = (const float*)d_in[22];
    const float* whh = (const float*)d_in[23];
    const float* bihp = (const float*)d_in[24];
    const float* bhhp = (const float*)d_in[25];
    const float* o1w = (const float*)d_in[26];
    const float* o1b = (const float*)d_in[27];
    const float* o2w = (const float*)d_in[28];
    const float* o2b = (const float*)d_in[29];
    float* out = (float*)d_out;

    char* ws = (char*)d_ws;
    unsigned short* c2o = (unsigned short*)(ws + 97026048);      // 46,727,168 B
    unsigned short* c3o = (unsigned short*)(ws + 143753216);     // 10,813,440 B
    float* f1p = (float*)(ws + 154566656);                       // 60*128*256*4 = 7,864,320 B
    float* cnn2 = (float*)(ws + 163348480);
    float* abuf = (float*)(ws + 163414016);
    float* lo = (float*)(ws + 163479552);
    unsigned short* w1t = (unsigned short*)(ws + 163741696);     // 8,192 B
    unsigned short* w2t = (unsigned short*)(ws + 163749888);     // 36,864 B
    unsigned short* w3t = (unsigned short*)(ws + 163786752);     // 73,728 B
    uint32_t* wpk = (uint32_t*)(ws + 163860480);                 // 524,288 B

    k_wprep<<<232, 256, 0, stream>>>(c1w, c2w, c3w, w1t, w2t, w3t);
    k_wprep_lstm<<<128, 256, 0, stream>>>(wih0, wih, whh, wpk);
    k_conv12<<<dim3(128, 2, 2), 256, 0, stream>>>(img, w1t, c1b, w2t, c2b, c2o);
    k_conv3m<<<dim3(128, 2, 2), 256, 0, stream>>>(c2o, w3t, c3b, c3o);
    k_fc1_mfma<<<dim3(60, 4), 256, 0, stream>>>(c3o, f1w, f1p);
    k_head<<<128, 256, 0, stream>>>(f1p, f1b, f2w, f2b, l1w, l1b, l2w, l2b, cnn2);
    k_act<<<4, 256, 0, stream>>>(ain, a1w, a1b, a2w, a2b, abuf);
    k_lstm<<<128, 512, 0, stream>>>(abuf, cnn2, wpk, bihp, bhhp, lo);
    k_out<<<4, 256, 0, stream>>>(lo, o1w, o1b, o2w, o2b, gt, out);
}